// Round 5
// baseline (235.082 us; speedup 1.0000x reference)
//
#include <hip/hip_runtime.h>
#include <math.h>

// Problem constants
static constexpr int NB   = 16;    // batch
static constexpr int DIM  = 256;   // total channels
static constexpr int CG   = 64;    // global-branch channels
static constexpr int HH   = 64;
static constexpr int WW   = 64;
static constexpr int HW   = HH * WW;   // 4096

// mish(x) = x*tanh(softplus(x)) = x*(t^2+2t)/(t^2+2t+2), t=e^x.
// Clamp at 20: for x>=20 the ratio is 1.0 in fp32 exactly.
__device__ __forceinline__ float mish_fast(float x) {
    float t = __expf(fminf(x, 20.f));
    float p = __builtin_fmaf(t, t, t + t);         // t^2 + 2t
    return x * p * __builtin_amdgcn_rcpf(p + 2.f);
}
__device__ __forceinline__ float silu_f(float x) {
    return x * __builtin_amdgcn_rcpf(1.f + __expf(-x));
}
// softplus via hw exp/log: max(x,0) + log(1 + e^-|x|). Error vs log1pf < 2 ulp.
__device__ __forceinline__ float softplus_fast(float x) {
    return fmaxf(x, 0.f) + __logf(1.f + __expf(-fabsf(x)));
}

// ---------------------------------------------------------------------------
// Passthrough: out[:,128:256] = x[:,128:256]   (identical flat indices)
// ---------------------------------------------------------------------------
__global__ __launch_bounds__(256) void k_copy_xi(const float4* __restrict__ x,
                                                 float4* __restrict__ out) {
    int i = blockIdx.x * 256 + threadIdx.x;            // 16*128*1024 float4
    const int per_b = 128 * HW / 4;                    // 131072
    int b = i / per_b, r = i % per_b;
    int idx = b * (DIM * HW / 4) + per_b + r;
    out[idx] = x[idx];
}

// ---------------------------------------------------------------------------
// Local branch: per-(b,c) channel mean of xl
// ---------------------------------------------------------------------------
__global__ __launch_bounds__(256) void k_mean(const float* __restrict__ x,
                                              float* __restrict__ mean) {
    int bc = blockIdx.x;                 // b*64 + c
    int b = bc >> 6, c = bc & 63;
    const float* p = x + ((size_t)b * DIM + 64 + c) * HW;
    float s = 0.f;
    for (int i = threadIdx.x; i < HW; i += 256) s += p[i];
    __shared__ float red[256];
    red[threadIdx.x] = s;
    __syncthreads();
    for (int o = 128; o > 0; o >>= 1) {
        if (threadIdx.x < o) red[threadIdx.x] += red[threadIdx.x + o];
        __syncthreads();
    }
    if (threadIdx.x == 0) mean[bc] = red[0] * (1.f / HW);
}

// ---------------------------------------------------------------------------
// gates = softmax(mean @ gw.T); weff[b,c,:] = (sum_e g_e * ew[e,c]) * bn1scale
// ---------------------------------------------------------------------------
__global__ void k_weff(const float* __restrict__ mean,
                       const float* __restrict__ ew,
                       const float* __restrict__ gw,
                       const float* __restrict__ bn1g,
                       float* __restrict__ weff, int k2) {
    int b = blockIdx.x;
    int c = threadIdx.x;                 // 64 threads
    __shared__ float m[64];
    __shared__ float g[4];
    m[c] = mean[b * 64 + c];
    __syncthreads();
    if (c < 4) {
        float l = 0.f;
        for (int cc = 0; cc < 64; ++cc) l += m[cc] * gw[c * 64 + cc];
        g[c] = l;
    }
    __syncthreads();
    if (c == 0) {
        float mx = fmaxf(fmaxf(g[0], g[1]), fmaxf(g[2], g[3]));
        float e0 = expf(g[0] - mx), e1 = expf(g[1] - mx);
        float e2 = expf(g[2] - mx), e3 = expf(g[3] - mx);
        float inv = 1.f / (e0 + e1 + e2 + e3);
        g[0] = e0 * inv; g[1] = e1 * inv; g[2] = e2 * inv; g[3] = e3 * inv;
    }
    __syncthreads();
    float g1s = bn1g[c] * rsqrtf(1.f + 1e-5f);
    for (int kk = 0; kk < k2; ++kk) {
        float w = 0.f;
        for (int e = 0; e < 4; ++e) w += g[e] * ew[(e * 64 + c) * k2 + kk];
        weff[(b * 64 + c) * k2 + kk] = w * g1s;
    }
}

// ---------------------------------------------------------------------------
// Local branch conv v2: register-blocked. Each lane owns a 4-wide x strip.
// Per dy: 3x ds_read_b128 row load (12 floats) shared by the 3x3/5x5/7x7 taps.
// Weights via block-uniform global reads -> SGPRs.
// ---------------------------------------------------------------------------
__global__ __launch_bounds__(256) void k_local(
    const float* __restrict__ x,
    const float* __restrict__ w3, const float* __restrict__ w5, const float* __restrict__ w7,
    const float* __restrict__ b1_0, const float* __restrict__ pw0,
    const float* __restrict__ g2_0, const float* __restrict__ b2_0,
    const float* __restrict__ b1_1, const float* __restrict__ pw1,
    const float* __restrict__ g2_1, const float* __restrict__ b2_1,
    const float* __restrict__ b1_2, const float* __restrict__ pw2,
    const float* __restrict__ g2_2, const float* __restrict__ b2_2,
    float* __restrict__ out) {
    int tile = blockIdx.x;               // 0..3
    int c = blockIdx.y, b = blockIdx.z;
    int oy = (tile >> 1) * 32, ox = (tile & 1) * 32;
    __shared__ float t[38 * 40];         // row stride 40 floats = 160B (16B-aligned)
    const float* xp = x + ((size_t)b * DIM + 64 + c) * HW;
    for (int i = threadIdx.x; i < 38 * 38; i += 256) {
        int r = i / 38, cc = i % 38;
        int yy = r - 3 + oy, xx = cc - 3 + ox;
        t[r * 40 + cc] = (yy >= 0 && yy < 64 && xx >= 0 && xx < 64) ? xp[yy * 64 + xx] : 0.f;
    }
    // Block-uniform weight loads -> scalar registers
    const float* w3p = w3 + (b * 64 + c) * 9;
    const float* w5p = w5 + (b * 64 + c) * 25;
    const float* w7p = w7 + (b * 64 + c) * 49;
    float W3r[9], W5r[25], W7r[49];
#pragma unroll
    for (int j = 0; j < 9; ++j)  W3r[j] = w3p[j];
#pragma unroll
    for (int j = 0; j < 25; ++j) W5r[j] = w5p[j];
#pragma unroll
    for (int j = 0; j < 49; ++j) W7r[j] = w7p[j];
    __syncthreads();

    const float rs = rsqrtf(1.f + 1e-5f);
    float bb1a = b1_0[c], bb1b = b1_1[c], bb1c = b1_2[c];
    float ssa = pw0[c] * g2_0[c] * rs, ssb = pw1[c] * g2_1[c] * rs, ssc = pw2[c] * g2_2[c] * rs;
    float bb2a = b2_0[c], bb2b = b2_1[c], bb2c = b2_2[c];

    int y  = threadIdx.x >> 3;           // 0..31
    int x0 = (threadIdx.x & 7) * 4;      // 0,4,...,28

    float a3[4] = {0.f, 0.f, 0.f, 0.f};
    float a5[4] = {0.f, 0.f, 0.f, 0.f};
    float a7[4] = {0.f, 0.f, 0.f, 0.f};

#pragma unroll
    for (int dy = 0; dy < 7; ++dy) {
        const float4* rp = (const float4*)(t + (y + dy) * 40 + x0);
        float4 q0 = rp[0], q1 = rp[1], q2 = rp[2];
        float r[12] = {q0.x, q0.y, q0.z, q0.w, q1.x, q1.y, q1.z, q1.w,
                       q2.x, q2.y, q2.z, q2.w};
#pragma unroll
        for (int k = 0; k < 4; ++k)
#pragma unroll
            for (int dx = 0; dx < 7; ++dx)
                a7[k] = fmaf(r[k + dx], W7r[dy * 7 + dx], a7[k]);
        if (dy >= 1 && dy <= 5) {
            int ey = dy - 1;
#pragma unroll
            for (int k = 0; k < 4; ++k)
#pragma unroll
                for (int dx = 0; dx < 5; ++dx)
                    a5[k] = fmaf(r[k + 1 + dx], W5r[ey * 5 + dx], a5[k]);
        }
        if (dy >= 2 && dy <= 4) {
            int ey = dy - 2;
#pragma unroll
            for (int k = 0; k < 4; ++k)
#pragma unroll
                for (int dx = 0; dx < 3; ++dx)
                    a3[k] = fmaf(r[k + 2 + dx], W3r[ey * 3 + dx], a3[k]);
        }
    }

    float4 res;
    float* rr = (float*)&res;
#pragma unroll
    for (int k = 0; k < 4; ++k) {
        rr[k] = mish_fast(a3[k] + bb1a) * ssa + bb2a
              + mish_fast(a5[k] + bb1b) * ssb + bb2b
              + mish_fast(a7[k] + bb1c) * ssc + bb2c;
    }
    float* op = out + ((size_t)b * DIM + 64 + c) * HW;
    *(float4*)(op + (oy + y) * 64 + ox + x0) = res;
}

// ---------------------------------------------------------------------------
// Fused wavelet: Haar decompose -> depthwise 3x3 conv + bias, *scale -> Haar rec.
// One block per (b, c): full 64x64 plane in LDS.
// ---------------------------------------------------------------------------
__global__ __launch_bounds__(256) void k_up(const float* __restrict__ x,
                                            const float* __restrict__ wav_w,
                                            const float* __restrict__ wav_b,
                                            const float* __restrict__ wav_scale,
                                            float* __restrict__ up) {
    int c = blockIdx.x, b = blockIdx.y;
    __shared__ float xs[64 * 65];
    __shared__ float wt[4][32 * 33];
    const float* xp = x + ((size_t)b * DIM + c) * HW;
    for (int i = threadIdx.x; i < HW; i += 256) xs[(i >> 6) * 65 + (i & 63)] = xp[i];
    __syncthreads();
    for (int i = threadIdx.x; i < 1024; i += 256) {
        int h = i >> 5, w = i & 31;
        float a  = xs[(2 * h) * 65 + 2 * w],     bb = xs[(2 * h) * 65 + 2 * w + 1];
        float cc = xs[(2 * h + 1) * 65 + 2 * w], dd = xs[(2 * h + 1) * 65 + 2 * w + 1];
        wt[0][h * 33 + w] = 0.5f * (a + bb + cc + dd);
        wt[1][h * 33 + w] = 0.5f * (a + bb - cc - dd);
        wt[2][h * 33 + w] = 0.5f * (a - bb + cc - dd);
        wt[3][h * 33 + w] = 0.5f * (a - bb - cc + dd);
    }
    __syncthreads();
    float wk[4][9], tb[4];
#pragma unroll
    for (int k = 0; k < 4; ++k) {
        int ch = c * 4 + k;
        float sc = wav_scale[ch];
#pragma unroll
        for (int j = 0; j < 9; ++j) wk[k][j] = wav_w[ch * 9 + j] * sc;
        tb[k] = wav_b[ch] * sc;
    }
    float* upp = up + ((size_t)b * CG + c) * HW;
    for (int i = threadIdx.x; i < 1024; i += 256) {
        int h = i >> 5, w = i & 31;
        float tg[4];
#pragma unroll
    for (int k = 0; k < 4; ++k) {
            float s = tb[k];
#pragma unroll
            for (int dy = -1; dy <= 1; ++dy) {
                int hh = h + dy;
                if (hh < 0 || hh >= 32) continue;
#pragma unroll
                for (int dx = -1; dx <= 1; ++dx) {
                    int wx = w + dx;
                    if (wx < 0 || wx >= 32) continue;
                    s = fmaf(wt[k][hh * 33 + wx], wk[k][(dy + 1) * 3 + (dx + 1)], s);
                }
            }
            tg[k] = s;
        }
        float u00 = 0.5f * (tg[0] - tg[1] - tg[2] + tg[3]);
        float u01 = 0.5f * (tg[0] - tg[1] + tg[2] - tg[3]);
        float u10 = 0.5f * (tg[0] + tg[1] - tg[2] - tg[3]);
        float u11 = 0.5f * (tg[0] + tg[1] + tg[2] + tg[3]);
        upp[(2 * h) * 64 + 2 * w]         = u00;
        upp[(2 * h) * 64 + 2 * w + 1]     = u01;
        upp[(2 * h + 1) * 64 + 2 * w]     = u10;
        upp[(2 * h + 1) * 64 + 2 * w + 1] = u11;
    }
}

// ---------------------------------------------------------------------------
// SS2D input projection: xz = in_w(128x64) @ xg per pixel. Block per (b, h row).
// ---------------------------------------------------------------------------
__global__ __launch_bounds__(256) void k_inproj(const float* __restrict__ x,
                                                const float* __restrict__ in_w,
                                                float* __restrict__ xi,
                                                float* __restrict__ z) {
    int h = blockIdx.x, b = blockIdx.y;
    __shared__ float xs[64 * 65];        // [c][w]
    __shared__ float wl[128 * 64];
    for (int i = threadIdx.x; i < 64 * 64; i += 256) {
        int c = i >> 6, w = i & 63;
        xs[c * 65 + w] = x[((size_t)b * DIM + c) * HW + h * 64 + w];
    }
    for (int i = threadIdx.x; i < 128 * 64; i += 256) wl[i] = in_w[i];
    __syncthreads();
    int lane = threadIdx.x & 63;
    int wave = threadIdx.x >> 6;
    float acc[32];
#pragma unroll
    for (int oi = 0; oi < 32; ++oi) acc[oi] = 0.f;
    for (int c = 0; c < 64; ++c) {
        float xv = xs[c * 65 + lane];
#pragma unroll
        for (int oi = 0; oi < 32; ++oi)
            acc[oi] = fmaf(wl[(wave * 32 + oi) * 64 + c], xv, acc[oi]);
    }
#pragma unroll
    for (int oi = 0; oi < 32; ++oi) {
        int o = wave * 32 + oi;
        float* dst = (o < 64) ? (xi + ((size_t)b * 64 + o) * HW + h * 64)
                              : (z + ((size_t)b * 64 + (o - 64)) * HW + h * 64);
        dst[lane] = acc[oi];
    }
}

// ---------------------------------------------------------------------------
// xc = silu(depthwise3x3(xi) + cb). Block per (b, c) plane.
// ---------------------------------------------------------------------------
__global__ __launch_bounds__(256) void k_dwss(const float* __restrict__ xi,
                                              const float* __restrict__ cw,
                                              const float* __restrict__ cb,
                                              float* __restrict__ xc) {
    int c = blockIdx.x, b = blockIdx.y;
    __shared__ float t[66 * 66];
    const float* p = xi + ((size_t)b * 64 + c) * HW;
    for (int i = threadIdx.x; i < 66 * 66; i += 256) {
        int y = i / 66 - 1, xq = i % 66 - 1;
        t[i] = (y >= 0 && y < 64 && xq >= 0 && xq < 64) ? p[y * 64 + xq] : 0.f;
    }
    __syncthreads();
    float wk[9];
#pragma unroll
    for (int j = 0; j < 9; ++j) wk[j] = cw[c * 9 + j];
    float bias = cb[c];
    float* q = xc + ((size_t)b * 64 + c) * HW;
    for (int i = threadIdx.x; i < HW; i += 256) {
        int y = i >> 6, xq = i & 63;
        float s = bias;
#pragma unroll
        for (int dy = 0; dy < 3; ++dy)
#pragma unroll
            for (int dx = 0; dx < 3; ++dx)
                s = fmaf(t[(y + dy) * 66 + xq + dx], wk[dy * 3 + dx], s);
        q[i] = silu_f(s);
    }
}

// ---------------------------------------------------------------------------
// Per-pixel 6-way projections for both scan directions (dt[4], B, C).
// proj layout: [dir][b][l][8]
// ---------------------------------------------------------------------------
__global__ __launch_bounds__(256) void k_ssproj(const float* __restrict__ xc,
                                                const float* __restrict__ xpw,
                                                float* __restrict__ proj) {
    int h = blockIdx.x, b = blockIdx.y;
    __shared__ float xs[64 * 65];
    for (int i = threadIdx.x; i < 64 * 64; i += 256) {
        int c = i >> 6, w = i & 63;
        xs[c * 65 + w] = xc[((size_t)b * 64 + c) * HW + h * 64 + w];
    }
    __syncthreads();
    int w = threadIdx.x & 63;
    int j = threadIdx.x >> 6;
    for (int m = 0; m < 3; ++m) {
        int pidx = j * 3 + m;
        int dir = pidx / 6, e = pidx % 6;
        float s = 0.f;
        for (int c = 0; c < 64; ++c)
            s = fmaf(xs[c * 65 + w], xpw[(dir * 6 + e) * 64 + c], s);
        int l = (dir == 0) ? (h * 64 + w) : (w * 64 + h);
        proj[(((size_t)dir * NB + b) * HW + l) * 8 + e] = s;
    }
}

// ---------------------------------------------------------------------------
// Selective scan (N=1), chunk-parallel: one BLOCK (4 waves) per (b,dir,d)
// plane. Wave w owns chunk w (1024 elems, lane segment = 16 contiguous).
// Chunk aggregates composed through LDS; carry chain math is bit-identical
// to the previous serial version. Fast hw transcendentals.
// ---------------------------------------------------------------------------
__global__ __launch_bounds__(256) void k_scan(const float* __restrict__ xc,
                                              const float* __restrict__ proj,
                                              const float* __restrict__ dt_w,
                                              const float* __restrict__ dt_b,
                                              const float* __restrict__ A_log,
                                              const float* __restrict__ Dp,
                                              float* __restrict__ y0,
                                              float* __restrict__ y1) {
    int wave = threadIdx.x >> 6;         // chunk index 0..3
    int lane = threadIdx.x & 63;
    int wid = blockIdx.x;                // plane id
    int b = wid >> 7;
    int rem = wid & 127;
    int dir = rem >> 6;                  // uniform per block
    int d = rem & 63;
    int pd = dir * 64 + d;

    float4 wv = *(const float4*)(dt_w + pd * 4);
    float db = dt_b[pd];
    float A = -__expf(A_log[pd]);
    float Dv = Dp[pd];
    const float* pr = proj + ((size_t)dir * NB + b) * HW * 8;
    const float* uplane = xc + ((size_t)b * 64 + d) * HW;
    float* yp = ((dir == 0) ? y0 : y1) + ((size_t)b * 64 + d) * HW;

    __shared__ float lt[4][64 * 17];     // dir=1 transpose tile, per wave
    __shared__ float aggA[4], aggB[4];   // chunk aggregates
    float* myl = lt[wave];

    int ch = wave;
    int e0 = ch * 1024 + lane * 16;      // first scan index of my segment
    float a[16], bv[16], cm[16], du[16];

    float uv[16];
    if (dir == 0) {
#pragma unroll
        for (int q = 0; q < 4; ++q) {
            float4 u4 = *(const float4*)(uplane + e0 + q * 4);
            uv[q * 4 + 0] = u4.x; uv[q * 4 + 1] = u4.y;
            uv[q * 4 + 2] = u4.z; uv[q * 4 + 3] = u4.w;
        }
    } else {
        int w_sp = e0 >> 6;              // fixed for all 16 elems of segment
        int h_sp0 = e0 & 63;
#pragma unroll
        for (int j = 0; j < 16; ++j) uv[j] = uplane[(h_sp0 + j) * 64 + w_sp];
    }

    float As = 1.f, Bs = 0.f;
#pragma unroll
    for (int j = 0; j < 16; ++j) {
        const float* pp = pr + (size_t)(e0 + j) * 8;
        float4 p4 = *(const float4*)pp;        // dt[0..3]
        float4 p5 = *(const float4*)(pp + 4);  // Bm, Cm, (pad)
        float pre = fmaf(p4.x, wv.x, fmaf(p4.y, wv.y,
                    fmaf(p4.z, wv.z, fmaf(p4.w, wv.w, db))));
        float delta = softplus_fast(pre);
        float aj = __expf(delta * A);
        float bj = delta * p5.x * uv[j];
        a[j] = aj; bv[j] = bj; cm[j] = p5.y; du[j] = Dv * uv[j];
        Bs = fmaf(aj, Bs, bj);           // compose segment map
        As *= aj;
    }

    // inclusive cross-lane scan of (As, Bs) within the chunk
    float Ai = As, Bi = Bs;
#pragma unroll
    for (int off = 1; off < 64; off <<= 1) {
        float ap = __shfl_up(Ai, (unsigned)off, 64);
        float bp = __shfl_up(Bi, (unsigned)off, 64);
        if (lane >= off) { Bi = fmaf(Ai, bp, Bi); Ai *= ap; }
    }

    // publish chunk aggregate; compose carries across chunks
    if (lane == 63) { aggA[wave] = Ai; aggB[wave] = Bi; }
    __syncthreads();
    float carry = 0.f;
    for (int k = 0; k < wave; ++k) carry = fmaf(aggA[k], carry, aggB[k]);

    float ap1 = __shfl_up(Ai, 1, 64);
    float bp1 = __shfl_up(Bi, 1, 64);
    float h = (lane == 0) ? carry : fmaf(ap1, carry, bp1);

    float y[16];
#pragma unroll
    for (int j = 0; j < 16; ++j) {
        h = fmaf(a[j], h, bv[j]);
        y[j] = fmaf(h, cm[j], du[j]);
    }

    if (dir == 0) {
        float4* dst = (float4*)(yp + e0);
#pragma unroll
        for (int q = 0; q < 4; ++q)
            dst[q] = make_float4(y[q * 4], y[q * 4 + 1], y[q * 4 + 2], y[q * 4 + 3]);
    } else {
        // scan elem e = ch*1024 + lane*16 + j -> spatial (h=(lane&3)*16+j, w=ch*16+lane>>2)
        int wl = lane >> 2;
        int hs0 = (lane & 3) * 16;
#pragma unroll
        for (int j = 0; j < 16; ++j) myl[(hs0 + j) * 17 + wl] = y[j];
        __builtin_amdgcn_wave_barrier();     // order LDS writes before reads (same wave)
        int w0 = ch * 16;
        float4* dst = (float4*)(yp + lane * 64 + w0);
#pragma unroll
        for (int q = 0; q < 4; ++q)
            dst[q] = make_float4(myl[lane * 17 + q * 4 + 0],
                                 myl[lane * 17 + q * 4 + 1],
                                 myl[lane * 17 + q * 4 + 2],
                                 myl[lane * 17 + q * 4 + 3]);
    }
}

// ---------------------------------------------------------------------------
// Final: y=(y0+y1)*silu(z); g = ow @ y (1x1 conv); out_g = base_scale*g + up
// ---------------------------------------------------------------------------
__global__ __launch_bounds__(256) void k_final(const float* __restrict__ y0,
                                               const float* __restrict__ y1,
                                               const float* __restrict__ z,
                                               const float* __restrict__ ow,
                                               const float* __restrict__ base_scale,
                                               const float* __restrict__ up,
                                               float* __restrict__ out) {
    int h = blockIdx.x, b = blockIdx.y;
    __shared__ float yv[64 * 65];
    __shared__ float wl[64 * 64];
    for (int i = threadIdx.x; i < 64 * 64; i += 256) {
        int c = i >> 6, w = i & 63;
        size_t idx = ((size_t)b * 64 + c) * HW + h * 64 + w;
        float zz = z[idx];
        yv[c * 65 + w] = (y0[idx] + y1[idx]) * silu_f(zz);
        wl[i] = ow[i];
    }
    __syncthreads();
    for (int i = threadIdx.x; i < 64 * 64; i += 256) {
        int o = i >> 6, w = i & 63;
        float s = 0.f;
        for (int c = 0; c < 64; ++c)
            s = fmaf(wl[o * 64 + c], yv[c * 65 + w], s);
        out[((size_t)b * DIM + o) * HW + h * 64 + w] =
            fmaf(base_scale[o], s, up[((size_t)b * CG + o) * HW + h * 64 + w]);
    }
}

// ---------------------------------------------------------------------------
extern "C" void kernel_launch(void* const* d_in, const int* in_sizes, int n_in,
                              void* d_out, int out_size, void* d_ws, size_t ws_size,
                              hipStream_t stream) {
    (void)in_sizes; (void)n_in; (void)out_size; (void)ws_size;
    const float* x = (const float*)d_in[0];
    float* out = (float*)d_out;
    float* ws = (float*)d_ws;

    const size_t IMG = (size_t)NB * 64 * HW;   // 4,194,304 floats
    float* buf_xi   = ws;                      // reused as y0 after consumption
    float* buf_z    = ws + IMG;
    float* buf_xc   = ws + 2 * IMG;
    float* buf_up   = ws + 3 * IMG;
    float* buf_y1   = ws + 4 * IMG;
    float* buf_proj = ws + 5 * IMG;            // 2*16*4096*8 = 1,048,576 floats
    float* buf_mean = buf_proj + (size_t)2 * NB * HW * 8;  // 1024
    float* buf_w3   = buf_mean + 1024;         // 16*64*9
    float* buf_w5   = buf_w3 + 16 * 64 * 9;    // 16*64*25
    float* buf_w7   = buf_w5 + 16 * 64 * 25;   // 16*64*49

    // ---- local branch ----
    k_mean<<<1024, 256, 0, stream>>>(x, buf_mean);
    k_weff<<<16, 64, 0, stream>>>(buf_mean, (const float*)d_in[1],
                                  (const float*)d_in[2], (const float*)d_in[3], buf_w3, 9);
    k_weff<<<16, 64, 0, stream>>>(buf_mean, (const float*)d_in[8],
                                  (const float*)d_in[9], (const float*)d_in[10], buf_w5, 25);
    k_weff<<<16, 64, 0, stream>>>(buf_mean, (const float*)d_in[15],
                                  (const float*)d_in[16], (const float*)d_in[17], buf_w7, 49);
    k_local<<<dim3(4, 64, 16), 256, 0, stream>>>(x, buf_w3, buf_w5, buf_w7,
        (const float*)d_in[4],  (const float*)d_in[5],  (const float*)d_in[6],  (const float*)d_in[7],
        (const float*)d_in[11], (const float*)d_in[12], (const float*)d_in[13], (const float*)d_in[14],
        (const float*)d_in[18], (const float*)d_in[19], (const float*)d_in[20], (const float*)d_in[21],
        out);

    // ---- wavelet branch (fused dec->conv->rec) ----
    k_up<<<dim3(64, 16), 256, 0, stream>>>(x, (const float*)d_in[22],
        (const float*)d_in[23], (const float*)d_in[24], buf_up);

    // ---- ss2d ----
    k_inproj<<<dim3(64, 16), 256, 0, stream>>>(x, (const float*)d_in[26], buf_xi, buf_z);
    k_dwss<<<dim3(64, 16), 256, 0, stream>>>(buf_xi, (const float*)d_in[27],
        (const float*)d_in[28], buf_xc);
    k_ssproj<<<dim3(64, 16), 256, 0, stream>>>(buf_xc, (const float*)d_in[29], buf_proj);
    k_scan<<<2048, 256, 0, stream>>>(buf_xc, buf_proj,
        (const float*)d_in[30], (const float*)d_in[31],
        (const float*)d_in[32], (const float*)d_in[33],
        buf_xi /* y0 (xi is dead now) */, buf_y1);
    k_final<<<dim3(64, 16), 256, 0, stream>>>(buf_xi, buf_y1, buf_z,
        (const float*)d_in[34], (const float*)d_in[25], buf_up, out);

    // ---- passthrough ----
    k_copy_xi<<<(16 * 128 * HW / 4) / 256, 256, 0, stream>>>((const float4*)x, (float4*)out);
}

// Round 6
// 214.625 us; speedup vs baseline: 1.0953x; 1.0953x over previous
//
#include <hip/hip_runtime.h>
#include <math.h>

// Problem constants
static constexpr int NB   = 16;    // batch
static constexpr int DIM  = 256;   // total channels
static constexpr int CG   = 64;    // global-branch channels
static constexpr int HH   = 64;
static constexpr int WW   = 64;
static constexpr int HW   = HH * WW;   // 4096

// mish(x) = x*tanh(softplus(x)) = x*(t^2+2t)/(t^2+2t+2), t=e^x.
__device__ __forceinline__ float mish_fast(float x) {
    float t = __expf(fminf(x, 20.f));
    float p = __builtin_fmaf(t, t, t + t);         // t^2 + 2t
    return x * p * __builtin_amdgcn_rcpf(p + 2.f);
}
__device__ __forceinline__ float silu_f(float x) {
    return x * __builtin_amdgcn_rcpf(1.f + __expf(-x));
}
// softplus via hw exp/log: max(x,0) + log(1 + e^-|x|). Error vs log1pf < 2 ulp.
__device__ __forceinline__ float softplus_fast(float x) {
    return fmaxf(x, 0.f) + __logf(1.f + __expf(-fabsf(x)));
}

// ---------------------------------------------------------------------------
// Passthrough: out[:,128:256] = x[:,128:256]
// ---------------------------------------------------------------------------
__global__ __launch_bounds__(256) void k_copy_xi(const float4* __restrict__ x,
                                                 float4* __restrict__ out) {
    int i = blockIdx.x * 256 + threadIdx.x;
    const int per_b = 128 * HW / 4;
    int b = i / per_b, r = i % per_b;
    int idx = b * (DIM * HW / 4) + per_b + r;
    out[idx] = x[idx];
}

// ---------------------------------------------------------------------------
// Local branch: per-(b,c) channel mean of xl
// ---------------------------------------------------------------------------
__global__ __launch_bounds__(256) void k_mean(const float* __restrict__ x,
                                              float* __restrict__ mean) {
    int bc = blockIdx.x;
    int b = bc >> 6, c = bc & 63;
    const float* p = x + ((size_t)b * DIM + 64 + c) * HW;
    float s = 0.f;
    for (int i = threadIdx.x; i < HW; i += 256) s += p[i];
    __shared__ float red[256];
    red[threadIdx.x] = s;
    __syncthreads();
    for (int o = 128; o > 0; o >>= 1) {
        if (threadIdx.x < o) red[threadIdx.x] += red[threadIdx.x + o];
        __syncthreads();
    }
    if (threadIdx.x == 0) mean[bc] = red[0] * (1.f / HW);
}

// ---------------------------------------------------------------------------
// gates = softmax(mean @ gw.T); weff[b,c,:] = (sum_e g_e * ew[e,c]) * bn1scale
// ---------------------------------------------------------------------------
__global__ void k_weff(const float* __restrict__ mean,
                       const float* __restrict__ ew,
                       const float* __restrict__ gw,
                       const float* __restrict__ bn1g,
                       float* __restrict__ weff, int k2) {
    int b = blockIdx.x;
    int c = threadIdx.x;
    __shared__ float m[64];
    __shared__ float g[4];
    m[c] = mean[b * 64 + c];
    __syncthreads();
    if (c < 4) {
        float l = 0.f;
        for (int cc = 0; cc < 64; ++cc) l += m[cc] * gw[c * 64 + cc];
        g[c] = l;
    }
    __syncthreads();
    if (c == 0) {
        float mx = fmaxf(fmaxf(g[0], g[1]), fmaxf(g[2], g[3]));
        float e0 = expf(g[0] - mx), e1 = expf(g[1] - mx);
        float e2 = expf(g[2] - mx), e3 = expf(g[3] - mx);
        float inv = 1.f / (e0 + e1 + e2 + e3);
        g[0] = e0 * inv; g[1] = e1 * inv; g[2] = e2 * inv; g[3] = e3 * inv;
    }
    __syncthreads();
    float g1s = bn1g[c] * rsqrtf(1.f + 1e-5f);
    for (int kk = 0; kk < k2; ++kk) {
        float w = 0.f;
        for (int e = 0; e < 4; ++e) w += g[e] * ew[(e * 64 + c) * k2 + kk];
        weff[(b * 64 + c) * k2 + kk] = w * g1s;
    }
}

// ---------------------------------------------------------------------------
// Local branch conv: register-blocked, 4-wide strips, b128 row loads.
// ---------------------------------------------------------------------------
__global__ __launch_bounds__(256) void k_local(
    const float* __restrict__ x,
    const float* __restrict__ w3, const float* __restrict__ w5, const float* __restrict__ w7,
    const float* __restrict__ b1_0, const float* __restrict__ pw0,
    const float* __restrict__ g2_0, const float* __restrict__ b2_0,
    const float* __restrict__ b1_1, const float* __restrict__ pw1,
    const float* __restrict__ g2_1, const float* __restrict__ b2_1,
    const float* __restrict__ b1_2, const float* __restrict__ pw2,
    const float* __restrict__ g2_2, const float* __restrict__ b2_2,
    float* __restrict__ out) {
    int tile = blockIdx.x;
    int c = blockIdx.y, b = blockIdx.z;
    int oy = (tile >> 1) * 32, ox = (tile & 1) * 32;
    __shared__ float t[38 * 40];
    const float* xp = x + ((size_t)b * DIM + 64 + c) * HW;
    for (int i = threadIdx.x; i < 38 * 38; i += 256) {
        int r = i / 38, cc = i % 38;
        int yy = r - 3 + oy, xx = cc - 3 + ox;
        t[r * 40 + cc] = (yy >= 0 && yy < 64 && xx >= 0 && xx < 64) ? xp[yy * 64 + xx] : 0.f;
    }
    const float* w3p = w3 + (b * 64 + c) * 9;
    const float* w5p = w5 + (b * 64 + c) * 25;
    const float* w7p = w7 + (b * 64 + c) * 49;
    float W3r[9], W5r[25], W7r[49];
#pragma unroll
    for (int j = 0; j < 9; ++j)  W3r[j] = w3p[j];
#pragma unroll
    for (int j = 0; j < 25; ++j) W5r[j] = w5p[j];
#pragma unroll
    for (int j = 0; j < 49; ++j) W7r[j] = w7p[j];
    __syncthreads();

    const float rs = rsqrtf(1.f + 1e-5f);
    float bb1a = b1_0[c], bb1b = b1_1[c], bb1c = b1_2[c];
    float ssa = pw0[c] * g2_0[c] * rs, ssb = pw1[c] * g2_1[c] * rs, ssc = pw2[c] * g2_2[c] * rs;
    float bb2a = b2_0[c], bb2b = b2_1[c], bb2c = b2_2[c];

    int y  = threadIdx.x >> 3;
    int x0 = (threadIdx.x & 7) * 4;

    float a3[4] = {0.f, 0.f, 0.f, 0.f};
    float a5[4] = {0.f, 0.f, 0.f, 0.f};
    float a7[4] = {0.f, 0.f, 0.f, 0.f};

#pragma unroll
    for (int dy = 0; dy < 7; ++dy) {
        const float4* rp = (const float4*)(t + (y + dy) * 40 + x0);
        float4 q0 = rp[0], q1 = rp[1], q2 = rp[2];
        float r[12] = {q0.x, q0.y, q0.z, q0.w, q1.x, q1.y, q1.z, q1.w,
                       q2.x, q2.y, q2.z, q2.w};
#pragma unroll
        for (int k = 0; k < 4; ++k)
#pragma unroll
            for (int dx = 0; dx < 7; ++dx)
                a7[k] = fmaf(r[k + dx], W7r[dy * 7 + dx], a7[k]);
        if (dy >= 1 && dy <= 5) {
            int ey = dy - 1;
#pragma unroll
            for (int k = 0; k < 4; ++k)
#pragma unroll
                for (int dx = 0; dx < 5; ++dx)
                    a5[k] = fmaf(r[k + 1 + dx], W5r[ey * 5 + dx], a5[k]);
        }
        if (dy >= 2 && dy <= 4) {
            int ey = dy - 2;
#pragma unroll
            for (int k = 0; k < 4; ++k)
#pragma unroll
                for (int dx = 0; dx < 3; ++dx)
                    a3[k] = fmaf(r[k + 2 + dx], W3r[ey * 3 + dx], a3[k]);
        }
    }

    float4 res;
    float* rr = (float*)&res;
#pragma unroll
    for (int k = 0; k < 4; ++k) {
        rr[k] = mish_fast(a3[k] + bb1a) * ssa + bb2a
              + mish_fast(a5[k] + bb1b) * ssb + bb2b
              + mish_fast(a7[k] + bb1c) * ssc + bb2c;
    }
    float* op = out + ((size_t)b * DIM + 64 + c) * HW;
    *(float4*)(op + (oy + y) * 64 + ox + x0) = res;
}

// ---------------------------------------------------------------------------
// Fused wavelet: Haar dec -> dw3x3 conv -> Haar rec. One block per (b,c).
// ---------------------------------------------------------------------------
__global__ __launch_bounds__(256) void k_up(const float* __restrict__ x,
                                            const float* __restrict__ wav_w,
                                            const float* __restrict__ wav_b,
                                            const float* __restrict__ wav_scale,
                                            float* __restrict__ up) {
    int c = blockIdx.x, b = blockIdx.y;
    __shared__ float xs[64 * 65];
    __shared__ float wt[4][32 * 33];
    const float* xp = x + ((size_t)b * DIM + c) * HW;
    for (int i = threadIdx.x; i < HW; i += 256) xs[(i >> 6) * 65 + (i & 63)] = xp[i];
    __syncthreads();
    for (int i = threadIdx.x; i < 1024; i += 256) {
        int h = i >> 5, w = i & 31;
        float a  = xs[(2 * h) * 65 + 2 * w],     bb = xs[(2 * h) * 65 + 2 * w + 1];
        float cc = xs[(2 * h + 1) * 65 + 2 * w], dd = xs[(2 * h + 1) * 65 + 2 * w + 1];
        wt[0][h * 33 + w] = 0.5f * (a + bb + cc + dd);
        wt[1][h * 33 + w] = 0.5f * (a + bb - cc - dd);
        wt[2][h * 33 + w] = 0.5f * (a - bb + cc - dd);
        wt[3][h * 33 + w] = 0.5f * (a - bb - cc + dd);
    }
    __syncthreads();
    float wk[4][9], tb[4];
#pragma unroll
    for (int k = 0; k < 4; ++k) {
        int ch = c * 4 + k;
        float sc = wav_scale[ch];
#pragma unroll
        for (int j = 0; j < 9; ++j) wk[k][j] = wav_w[ch * 9 + j] * sc;
        tb[k] = wav_b[ch] * sc;
    }
    float* upp = up + ((size_t)b * CG + c) * HW;
    for (int i = threadIdx.x; i < 1024; i += 256) {
        int h = i >> 5, w = i & 31;
        float tg[4];
#pragma unroll
        for (int k = 0; k < 4; ++k) {
            float s = tb[k];
#pragma unroll
            for (int dy = -1; dy <= 1; ++dy) {
                int hh = h + dy;
                if (hh < 0 || hh >= 32) continue;
#pragma unroll
                for (int dx = -1; dx <= 1; ++dx) {
                    int wx = w + dx;
                    if (wx < 0 || wx >= 32) continue;
                    s = fmaf(wt[k][hh * 33 + wx], wk[k][(dy + 1) * 3 + (dx + 1)], s);
                }
            }
            tg[k] = s;
        }
        float u00 = 0.5f * (tg[0] - tg[1] - tg[2] + tg[3]);
        float u01 = 0.5f * (tg[0] - tg[1] + tg[2] - tg[3]);
        float u10 = 0.5f * (tg[0] + tg[1] - tg[2] - tg[3]);
        float u11 = 0.5f * (tg[0] + tg[1] + tg[2] + tg[3]);
        upp[(2 * h) * 64 + 2 * w]         = u00;
        upp[(2 * h) * 64 + 2 * w + 1]     = u01;
        upp[(2 * h + 1) * 64 + 2 * w]     = u10;
        upp[(2 * h + 1) * 64 + 2 * w + 1] = u11;
    }
}

// ---------------------------------------------------------------------------
// SS2D input projection. Block per (b, h row).
// ---------------------------------------------------------------------------
__global__ __launch_bounds__(256) void k_inproj(const float* __restrict__ x,
                                                const float* __restrict__ in_w,
                                                float* __restrict__ xi,
                                                float* __restrict__ z) {
    int h = blockIdx.x, b = blockIdx.y;
    __shared__ float xs[64 * 65];
    __shared__ float wl[128 * 64];
    for (int i = threadIdx.x; i < 64 * 64; i += 256) {
        int c = i >> 6, w = i & 63;
        xs[c * 65 + w] = x[((size_t)b * DIM + c) * HW + h * 64 + w];
    }
    for (int i = threadIdx.x; i < 128 * 64; i += 256) wl[i] = in_w[i];
    __syncthreads();
    int lane = threadIdx.x & 63;
    int wave = threadIdx.x >> 6;
    float acc[32];
#pragma unroll
    for (int oi = 0; oi < 32; ++oi) acc[oi] = 0.f;
    for (int c = 0; c < 64; ++c) {
        float xv = xs[c * 65 + lane];
#pragma unroll
        for (int oi = 0; oi < 32; ++oi)
            acc[oi] = fmaf(wl[(wave * 32 + oi) * 64 + c], xv, acc[oi]);
    }
#pragma unroll
    for (int oi = 0; oi < 32; ++oi) {
        int o = wave * 32 + oi;
        float* dst = (o < 64) ? (xi + ((size_t)b * 64 + o) * HW + h * 64)
                              : (z + ((size_t)b * 64 + (o - 64)) * HW + h * 64);
        dst[lane] = acc[oi];
    }
}

// ---------------------------------------------------------------------------
// xc = silu(depthwise3x3(xi) + cb). Block per (b, c) plane.
// ---------------------------------------------------------------------------
__global__ __launch_bounds__(256) void k_dwss(const float* __restrict__ xi,
                                              const float* __restrict__ cw,
                                              const float* __restrict__ cb,
                                              float* __restrict__ xc) {
    int c = blockIdx.x, b = blockIdx.y;
    __shared__ float t[66 * 66];
    const float* p = xi + ((size_t)b * 64 + c) * HW;
    for (int i = threadIdx.x; i < 66 * 66; i += 256) {
        int y = i / 66 - 1, xq = i % 66 - 1;
        t[i] = (y >= 0 && y < 64 && xq >= 0 && xq < 64) ? p[y * 64 + xq] : 0.f;
    }
    __syncthreads();
    float wk[9];
#pragma unroll
    for (int j = 0; j < 9; ++j) wk[j] = cw[c * 9 + j];
    float bias = cb[c];
    float* q = xc + ((size_t)b * 64 + c) * HW;
    for (int i = threadIdx.x; i < HW; i += 256) {
        int y = i >> 6, xq = i & 63;
        float s = bias;
#pragma unroll
        for (int dy = 0; dy < 3; ++dy)
#pragma unroll
            for (int dx = 0; dx < 3; ++dx)
                s = fmaf(t[(y + dy) * 66 + xq + dx], wk[dy * 3 + dx], s);
        q[i] = silu_f(s);
    }
}

// ---------------------------------------------------------------------------
// Per-pixel projections, SoA output: proj4 = (dt0..dt3) float4 plane,
// projBC = (Bm, Cm) float2 plane, per (dir, b). Block per (b, h row).
// Groups: g0/g1 -> dir0 (dt4 / BC), g2/g3 -> dir1.
// ---------------------------------------------------------------------------
__global__ __launch_bounds__(256) void k_ssproj(const float* __restrict__ xc,
                                                const float* __restrict__ xpw,
                                                float4* __restrict__ proj4,
                                                float2* __restrict__ projBC) {
    int h = blockIdx.x, b = blockIdx.y;
    __shared__ float xs[64 * 65];
    for (int i = threadIdx.x; i < 64 * 64; i += 256) {
        int c = i >> 6, w = i & 63;
        xs[c * 65 + w] = xc[((size_t)b * 64 + c) * HW + h * 64 + w];
    }
    __syncthreads();
    int w = threadIdx.x & 63;
    int g = threadIdx.x >> 6;
    int dir = g >> 1;
    int l = (dir == 0) ? (h * 64 + w) : (w * 64 + h);
    size_t base = ((size_t)dir * NB + b) * HW + l;
    const float* wp = xpw + dir * 6 * 64;
    if ((g & 1) == 0) {
        float s0 = 0.f, s1 = 0.f, s2 = 0.f, s3 = 0.f;
        for (int c = 0; c < 64; ++c) {
            float xv = xs[c * 65 + w];
            s0 = fmaf(xv, wp[0 * 64 + c], s0);
            s1 = fmaf(xv, wp[1 * 64 + c], s1);
            s2 = fmaf(xv, wp[2 * 64 + c], s2);
            s3 = fmaf(xv, wp[3 * 64 + c], s3);
        }
        proj4[base] = make_float4(s0, s1, s2, s3);
    } else {
        float s4 = 0.f, s5 = 0.f;
        for (int c = 0; c < 64; ++c) {
            float xv = xs[c * 65 + w];
            s4 = fmaf(xv, wp[4 * 64 + c], s4);
            s5 = fmaf(xv, wp[5 * 64 + c], s5);
        }
        projBC[base] = make_float2(s4, s5);
    }
}

// ---------------------------------------------------------------------------
// Selective scan (N=1), chunk-parallel + LDS ownership transpose.
// Block per (b,dir,d) plane; wave = chunk of 1024. Phase A: coalesced global
// loads (e = j*64+lane), compute (a,b), write padded LDS. Phase B: per-lane
// 16-segments, compose + 6-step shfl scan (bit-identical to serial math),
// h back to LDS. Phase C: coalesced apply + store. dir=1 u/y via plane tile.
// ---------------------------------------------------------------------------
__global__ __launch_bounds__(256) void k_scan(const float* __restrict__ xc,
                                              const float4* __restrict__ proj4,
                                              const float2* __restrict__ projBC,
                                              const float* __restrict__ dt_w,
                                              const float* __restrict__ dt_b,
                                              const float* __restrict__ A_log,
                                              const float* __restrict__ Dp,
                                              float* __restrict__ y0,
                                              float* __restrict__ y1) {
    int wave = threadIdx.x >> 6;
    int lane = threadIdx.x & 63;
    int wid = blockIdx.x;
    int b = wid >> 7;
    int rem = wid & 127;
    int dir = rem >> 6;                  // uniform per block
    int d = rem & 63;
    int pd = dir * 64 + d;

    float4 wv = *(const float4*)(dt_w + pd * 4);
    float db = dt_b[pd];
    float A = -__expf(A_log[pd]);
    float Dv = Dp[pd];
    const float4* p4 = proj4 + ((size_t)dir * NB + b) * HW;
    const float2* pBC = projBC + ((size_t)dir * NB + b) * HW;
    const float* uplane = xc + ((size_t)b * 64 + d) * HW;
    float* yp = ((dir == 0) ? y0 : y1) + ((size_t)b * 64 + d) * HW;

    __shared__ float ut[64 * 65];        // u plane tile (later y tile for dir1)
    __shared__ float al[4][1088];        // (a) then (h), padded seg*17+pos
    __shared__ float bl[4][1088];        // (b)
    __shared__ float aggA[4], aggB[4];

    // stage u plane, coalesced float4 loads
    const float4* up4 = (const float4*)uplane;
#pragma unroll
    for (int q = 0; q < 4; ++q) {
        int s = q * 256 + threadIdx.x;
        float4 v = up4[s];
        int r = s >> 4, c0 = (s & 15) * 4;
        float* p = ut + r * 65 + c0;
        p[0] = v.x; p[1] = v.y; p[2] = v.z; p[3] = v.w;
    }
    __syncthreads();

    int ch = wave;
    float* a_my = al[wave];
    float* b_my = bl[wave];

    // ---- phase A: coalesced loads, compute (a,b), scatter to padded LDS ----
#pragma unroll
    for (int j = 0; j < 16; ++j) {
        int el = j * 64 + lane;
        int e  = ch * 1024 + el;
        float4 t4 = p4[e];
        float2 t2 = pBC[e];
        float u = (dir == 0) ? ut[(ch * 16 + j) * 65 + lane]
                             : ut[lane * 65 + (ch * 16 + j)];
        float pre = fmaf(t4.x, wv.x, fmaf(t4.y, wv.y,
                    fmaf(t4.z, wv.z, fmaf(t4.w, wv.w, db))));
        float delta = softplus_fast(pre);
        float aj = __expf(delta * A);
        float bj = delta * t2.x * u;
        int idx = (el >> 4) * 17 + (el & 15);
        a_my[idx] = aj;
        b_my[idx] = bj;
    }
    __builtin_amdgcn_wave_barrier();     // cross-lane LDS within wave: pin order

    // ---- phase B: per-lane segment compose + cross-lane scan ----
    float a[16], bb[16];
#pragma unroll
    for (int j = 0; j < 16; ++j) {
        a[j]  = a_my[lane * 17 + j];
        bb[j] = b_my[lane * 17 + j];
    }
    float As = 1.f, Bs = 0.f;
#pragma unroll
    for (int j = 0; j < 16; ++j) { Bs = fmaf(a[j], Bs, bb[j]); As *= a[j]; }
    float Ai = As, Bi = Bs;
#pragma unroll
    for (int off = 1; off < 64; off <<= 1) {
        float ap = __shfl_up(Ai, (unsigned)off, 64);
        float bp = __shfl_up(Bi, (unsigned)off, 64);
        if (lane >= off) { Bi = fmaf(Ai, bp, Bi); Ai *= ap; }
    }
    if (lane == 63) { aggA[wave] = Ai; aggB[wave] = Bi; }
    __syncthreads();
    float carry = 0.f;
    for (int k = 0; k < wave; ++k) carry = fmaf(aggA[k], carry, aggB[k]);
    float ap1 = __shfl_up(Ai, 1, 64);
    float bp1 = __shfl_up(Bi, 1, 64);
    float h = (lane == 0) ? carry : fmaf(ap1, carry, bp1);
#pragma unroll
    for (int j = 0; j < 16; ++j) {
        h = fmaf(a[j], h, bb[j]);
        a_my[lane * 17 + j] = h;         // h overwrites a slot
    }
    __builtin_amdgcn_wave_barrier();

    // ---- phase C: coalesced apply + store ----
    if (dir == 0) {
#pragma unroll
        for (int j = 0; j < 16; ++j) {
            int el = j * 64 + lane;
            int e  = ch * 1024 + el;
            float hv = a_my[(el >> 4) * 17 + (el & 15)];
            float cmv = pBC[e].y;
            float u = ut[(ch * 16 + j) * 65 + lane];
            yp[e] = fmaf(hv, cmv, Dv * u);
        }
    } else {
#pragma unroll
        for (int j = 0; j < 16; ++j) {
            int el = j * 64 + lane;
            int e  = ch * 1024 + el;
            float hv = a_my[(el >> 4) * 17 + (el & 15)];
            float cmv = pBC[e].y;
            int w = ch * 16 + j;
            float u = ut[lane * 65 + w];
            ut[lane * 65 + w] = fmaf(hv, cmv, Dv * u);   // y in place
        }
        __syncthreads();
        // block-cooperative contiguous store of the whole y plane
#pragma unroll
        for (int q = 0; q < 4; ++q) {
            int s = q * 256 + threadIdx.x;
            int r = s >> 4, c0 = (s & 15) * 4;
            const float* p = ut + r * 65 + c0;
            ((float4*)yp)[s] = make_float4(p[0], p[1], p[2], p[3]);
        }
    }
}

// ---------------------------------------------------------------------------
// Final: y=(y0+y1)*silu(z); g = ow @ y; out_g = base_scale*g + up
// ---------------------------------------------------------------------------
__global__ __launch_bounds__(256) void k_final(const float* __restrict__ y0,
                                               const float* __restrict__ y1,
                                               const float* __restrict__ z,
                                               const float* __restrict__ ow,
                                               const float* __restrict__ base_scale,
                                               const float* __restrict__ up,
                                               float* __restrict__ out) {
    int h = blockIdx.x, b = blockIdx.y;
    __shared__ float yv[64 * 65];
    __shared__ float wl[64 * 64];
    for (int i = threadIdx.x; i < 64 * 64; i += 256) {
        int c = i >> 6, w = i & 63;
        size_t idx = ((size_t)b * 64 + c) * HW + h * 64 + w;
        float zz = z[idx];
        yv[c * 65 + w] = (y0[idx] + y1[idx]) * silu_f(zz);
        wl[i] = ow[i];
    }
    __syncthreads();
    for (int i = threadIdx.x; i < 64 * 64; i += 256) {
        int o = i >> 6, w = i & 63;
        float s = 0.f;
        for (int c = 0; c < 64; ++c)
            s = fmaf(wl[o * 64 + c], yv[c * 65 + w], s);
        out[((size_t)b * DIM + o) * HW + h * 64 + w] =
            fmaf(base_scale[o], s, up[((size_t)b * CG + o) * HW + h * 64 + w]);
    }
}

// ---------------------------------------------------------------------------
extern "C" void kernel_launch(void* const* d_in, const int* in_sizes, int n_in,
                              void* d_out, int out_size, void* d_ws, size_t ws_size,
                              hipStream_t stream) {
    (void)in_sizes; (void)n_in; (void)out_size; (void)ws_size;
    const float* x = (const float*)d_in[0];
    float* out = (float*)d_out;
    float* ws = (float*)d_ws;

    const size_t IMG = (size_t)NB * 64 * HW;   // 4,194,304 floats
    float* buf_xi   = ws;                      // reused as y0 after consumption
    float* buf_z    = ws + IMG;
    float* buf_xc   = ws + 2 * IMG;
    float* buf_up   = ws + 3 * IMG;
    float* buf_y1   = ws + 4 * IMG;
    float* buf_p4   = ws + 5 * IMG;            // float4[2*16*4096] = 524288 floats
    float* buf_pBC  = buf_p4 + (size_t)4 * 2 * NB * HW;   // float2 = 262144 floats
    float* buf_mean = buf_pBC + (size_t)2 * 2 * NB * HW;
    float* buf_w3   = buf_mean + 1024;
    float* buf_w5   = buf_w3 + 16 * 64 * 9;
    float* buf_w7   = buf_w5 + 16 * 64 * 25;

    // ---- local branch ----
    k_mean<<<1024, 256, 0, stream>>>(x, buf_mean);
    k_weff<<<16, 64, 0, stream>>>(buf_mean, (const float*)d_in[1],
                                  (const float*)d_in[2], (const float*)d_in[3], buf_w3, 9);
    k_weff<<<16, 64, 0, stream>>>(buf_mean, (const float*)d_in[8],
                                  (const float*)d_in[9], (const float*)d_in[10], buf_w5, 25);
    k_weff<<<16, 64, 0, stream>>>(buf_mean, (const float*)d_in[15],
                                  (const float*)d_in[16], (const float*)d_in[17], buf_w7, 49);
    k_local<<<dim3(4, 64, 16), 256, 0, stream>>>(x, buf_w3, buf_w5, buf_w7,
        (const float*)d_in[4],  (const float*)d_in[5],  (const float*)d_in[6],  (const float*)d_in[7],
        (const float*)d_in[11], (const float*)d_in[12], (const float*)d_in[13], (const float*)d_in[14],
        (const float*)d_in[18], (const float*)d_in[19], (const float*)d_in[20], (const float*)d_in[21],
        out);

    // ---- wavelet branch ----
    k_up<<<dim3(64, 16), 256, 0, stream>>>(x, (const float*)d_in[22],
        (const float*)d_in[23], (const float*)d_in[24], buf_up);

    // ---- ss2d ----
    k_inproj<<<dim3(64, 16), 256, 0, stream>>>(x, (const float*)d_in[26], buf_xi, buf_z);
    k_dwss<<<dim3(64, 16), 256, 0, stream>>>(buf_xi, (const float*)d_in[27],
        (const float*)d_in[28], buf_xc);
    k_ssproj<<<dim3(64, 16), 256, 0, stream>>>(buf_xc, (const float*)d_in[29],
        (float4*)buf_p4, (float2*)buf_pBC);
    k_scan<<<2048, 256, 0, stream>>>(buf_xc, (const float4*)buf_p4, (const float2*)buf_pBC,
        (const float*)d_in[30], (const float*)d_in[31],
        (const float*)d_in[32], (const float*)d_in[33],
        buf_xi /* y0 (xi is dead now) */, buf_y1);
    k_final<<<dim3(64, 16), 256, 0, stream>>>(buf_xi, buf_y1, buf_z,
        (const float*)d_in[34], (const float*)d_in[25], buf_up, out);

    // ---- passthrough ----
    k_copy_xi<<<(16 * 128 * HW / 4) / 256, 256, 0, stream>>>((const float4*)x, (float4*)out);
}

// Round 7
// 179.328 us; speedup vs baseline: 1.3109x; 1.1968x over previous
//
#include <hip/hip_runtime.h>
#include <math.h>

// Problem constants
static constexpr int NB   = 16;    // batch
static constexpr int DIM  = 256;   // total channels
static constexpr int CG   = 64;    // global-branch channels
static constexpr int HH   = 64;
static constexpr int WW   = 64;
static constexpr int HW   = HH * WW;   // 4096

// mish(x) = x*tanh(softplus(x)) = x*(t^2+2t)/(t^2+2t+2), t=e^x.
__device__ __forceinline__ float mish_fast(float x) {
    float t = __expf(fminf(x, 20.f));
    float p = __builtin_fmaf(t, t, t + t);         // t^2 + 2t
    return x * p * __builtin_amdgcn_rcpf(p + 2.f);
}
__device__ __forceinline__ float silu_f(float x) {
    return x * __builtin_amdgcn_rcpf(1.f + __expf(-x));
}
// softplus via hw exp/log: max(x,0) + log(1 + e^-|x|). Error vs log1pf < 2 ulp.
__device__ __forceinline__ float softplus_fast(float x) {
    return fmaxf(x, 0.f) + __logf(1.f + __expf(-fabsf(x)));
}

// ---------------------------------------------------------------------------
// Passthrough: out[:,128:256] = x[:,128:256]
// ---------------------------------------------------------------------------
__global__ __launch_bounds__(256) void k_copy_xi(const float4* __restrict__ x,
                                                 float4* __restrict__ out) {
    int i = blockIdx.x * 256 + threadIdx.x;
    const int per_b = 128 * HW / 4;
    int b = i / per_b, r = i % per_b;
    int idx = b * (DIM * HW / 4) + per_b + r;
    out[idx] = x[idx];
}

// ---------------------------------------------------------------------------
// Local branch: per-(b,c) channel mean of xl
// ---------------------------------------------------------------------------
__global__ __launch_bounds__(256) void k_mean(const float* __restrict__ x,
                                              float* __restrict__ mean) {
    int bc = blockIdx.x;
    int b = bc >> 6, c = bc & 63;
    const float* p = x + ((size_t)b * DIM + 64 + c) * HW;
    float s = 0.f;
    for (int i = threadIdx.x; i < HW; i += 256) s += p[i];
    __shared__ float red[256];
    red[threadIdx.x] = s;
    __syncthreads();
    for (int o = 128; o > 0; o >>= 1) {
        if (threadIdx.x < o) red[threadIdx.x] += red[threadIdx.x + o];
        __syncthreads();
    }
    if (threadIdx.x == 0) mean[bc] = red[0] * (1.f / HW);
}

// ---------------------------------------------------------------------------
// gates = softmax(mean @ gw.T); weff[b,c,:] = (sum_e g_e * ew[e,c]) * bn1scale
// ---------------------------------------------------------------------------
__global__ void k_weff(const float* __restrict__ mean,
                       const float* __restrict__ ew,
                       const float* __restrict__ gw,
                       const float* __restrict__ bn1g,
                       float* __restrict__ weff, int k2) {
    int b = blockIdx.x;
    int c = threadIdx.x;
    __shared__ float m[64];
    __shared__ float g[4];
    m[c] = mean[b * 64 + c];
    __syncthreads();
    if (c < 4) {
        float l = 0.f;
        for (int cc = 0; cc < 64; ++cc) l += m[cc] * gw[c * 64 + cc];
        g[c] = l;
    }
    __syncthreads();
    if (c == 0) {
        float mx = fmaxf(fmaxf(g[0], g[1]), fmaxf(g[2], g[3]));
        float e0 = expf(g[0] - mx), e1 = expf(g[1] - mx);
        float e2 = expf(g[2] - mx), e3 = expf(g[3] - mx);
        float inv = 1.f / (e0 + e1 + e2 + e3);
        g[0] = e0 * inv; g[1] = e1 * inv; g[2] = e2 * inv; g[3] = e3 * inv;
    }
    __syncthreads();
    float g1s = bn1g[c] * rsqrtf(1.f + 1e-5f);
    for (int kk = 0; kk < k2; ++kk) {
        float w = 0.f;
        for (int e = 0; e < 4; ++e) w += g[e] * ew[(e * 64 + c) * k2 + kk];
        weff[(b * 64 + c) * k2 + kk] = w * g1s;
    }
}

// ---------------------------------------------------------------------------
// Local branch conv: register-blocked, 4-wide strips, b128 row loads.
// ---------------------------------------------------------------------------
__global__ __launch_bounds__(256) void k_local(
    const float* __restrict__ x,
    const float* __restrict__ w3, const float* __restrict__ w5, const float* __restrict__ w7,
    const float* __restrict__ b1_0, const float* __restrict__ pw0,
    const float* __restrict__ g2_0, const float* __restrict__ b2_0,
    const float* __restrict__ b1_1, const float* __restrict__ pw1,
    const float* __restrict__ g2_1, const float* __restrict__ b2_1,
    const float* __restrict__ b1_2, const float* __restrict__ pw2,
    const float* __restrict__ g2_2, const float* __restrict__ b2_2,
    float* __restrict__ out) {
    int tile = blockIdx.x;
    int c = blockIdx.y, b = blockIdx.z;
    int oy = (tile >> 1) * 32, ox = (tile & 1) * 32;
    __shared__ float t[38 * 40];
    const float* xp = x + ((size_t)b * DIM + 64 + c) * HW;
    for (int i = threadIdx.x; i < 38 * 38; i += 256) {
        int r = i / 38, cc = i % 38;
        int yy = r - 3 + oy, xx = cc - 3 + ox;
        t[r * 40 + cc] = (yy >= 0 && yy < 64 && xx >= 0 && xx < 64) ? xp[yy * 64 + xx] : 0.f;
    }
    const float* w3p = w3 + (b * 64 + c) * 9;
    const float* w5p = w5 + (b * 64 + c) * 25;
    const float* w7p = w7 + (b * 64 + c) * 49;
    float W3r[9], W5r[25], W7r[49];
#pragma unroll
    for (int j = 0; j < 9; ++j)  W3r[j] = w3p[j];
#pragma unroll
    for (int j = 0; j < 25; ++j) W5r[j] = w5p[j];
#pragma unroll
    for (int j = 0; j < 49; ++j) W7r[j] = w7p[j];
    __syncthreads();

    const float rs = rsqrtf(1.f + 1e-5f);
    float bb1a = b1_0[c], bb1b = b1_1[c], bb1c = b1_2[c];
    float ssa = pw0[c] * g2_0[c] * rs, ssb = pw1[c] * g2_1[c] * rs, ssc = pw2[c] * g2_2[c] * rs;
    float bb2a = b2_0[c], bb2b = b2_1[c], bb2c = b2_2[c];

    int y  = threadIdx.x >> 3;
    int x0 = (threadIdx.x & 7) * 4;

    float a3[4] = {0.f, 0.f, 0.f, 0.f};
    float a5[4] = {0.f, 0.f, 0.f, 0.f};
    float a7[4] = {0.f, 0.f, 0.f, 0.f};

#pragma unroll
    for (int dy = 0; dy < 7; ++dy) {
        const float4* rp = (const float4*)(t + (y + dy) * 40 + x0);
        float4 q0 = rp[0], q1 = rp[1], q2 = rp[2];
        float r[12] = {q0.x, q0.y, q0.z, q0.w, q1.x, q1.y, q1.z, q1.w,
                       q2.x, q2.y, q2.z, q2.w};
#pragma unroll
        for (int k = 0; k < 4; ++k)
#pragma unroll
            for (int dx = 0; dx < 7; ++dx)
                a7[k] = fmaf(r[k + dx], W7r[dy * 7 + dx], a7[k]);
        if (dy >= 1 && dy <= 5) {
            int ey = dy - 1;
#pragma unroll
            for (int k = 0; k < 4; ++k)
#pragma unroll
                for (int dx = 0; dx < 5; ++dx)
                    a5[k] = fmaf(r[k + 1 + dx], W5r[ey * 5 + dx], a5[k]);
        }
        if (dy >= 2 && dy <= 4) {
            int ey = dy - 2;
#pragma unroll
            for (int k = 0; k < 4; ++k)
#pragma unroll
                for (int dx = 0; dx < 3; ++dx)
                    a3[k] = fmaf(r[k + 2 + dx], W3r[ey * 3 + dx], a3[k]);
        }
    }

    float4 res;
    float* rr = (float*)&res;
#pragma unroll
    for (int k = 0; k < 4; ++k) {
        rr[k] = mish_fast(a3[k] + bb1a) * ssa + bb2a
              + mish_fast(a5[k] + bb1b) * ssb + bb2b
              + mish_fast(a7[k] + bb1c) * ssc + bb2c;
    }
    float* op = out + ((size_t)b * DIM + 64 + c) * HW;
    *(float4*)(op + (oy + y) * 64 + ox + x0) = res;
}

// ---------------------------------------------------------------------------
// Fused wavelet: Haar dec -> dw3x3 conv -> Haar rec. One block per (b,c).
// ---------------------------------------------------------------------------
__global__ __launch_bounds__(256) void k_up(const float* __restrict__ x,
                                            const float* __restrict__ wav_w,
                                            const float* __restrict__ wav_b,
                                            const float* __restrict__ wav_scale,
                                            float* __restrict__ up) {
    int c = blockIdx.x, b = blockIdx.y;
    __shared__ float xs[64 * 65];
    __shared__ float wt[4][32 * 33];
    const float* xp = x + ((size_t)b * DIM + c) * HW;
    for (int i = threadIdx.x; i < HW; i += 256) xs[(i >> 6) * 65 + (i & 63)] = xp[i];
    __syncthreads();
    for (int i = threadIdx.x; i < 1024; i += 256) {
        int h = i >> 5, w = i & 31;
        float a  = xs[(2 * h) * 65 + 2 * w],     bb = xs[(2 * h) * 65 + 2 * w + 1];
        float cc = xs[(2 * h + 1) * 65 + 2 * w], dd = xs[(2 * h + 1) * 65 + 2 * w + 1];
        wt[0][h * 33 + w] = 0.5f * (a + bb + cc + dd);
        wt[1][h * 33 + w] = 0.5f * (a + bb - cc - dd);
        wt[2][h * 33 + w] = 0.5f * (a - bb + cc - dd);
        wt[3][h * 33 + w] = 0.5f * (a - bb - cc + dd);
    }
    __syncthreads();
    float wk[4][9], tb[4];
#pragma unroll
    for (int k = 0; k < 4; ++k) {
        int ch = c * 4 + k;
        float sc = wav_scale[ch];
#pragma unroll
        for (int j = 0; j < 9; ++j) wk[k][j] = wav_w[ch * 9 + j] * sc;
        tb[k] = wav_b[ch] * sc;
    }
    float* upp = up + ((size_t)b * CG + c) * HW;
    for (int i = threadIdx.x; i < 1024; i += 256) {
        int h = i >> 5, w = i & 31;
        float tg[4];
#pragma unroll
        for (int k = 0; k < 4; ++k) {
            float s = tb[k];
#pragma unroll
            for (int dy = -1; dy <= 1; ++dy) {
                int hh = h + dy;
                if (hh < 0 || hh >= 32) continue;
#pragma unroll
                for (int dx = -1; dx <= 1; ++dx) {
                    int wx = w + dx;
                    if (wx < 0 || wx >= 32) continue;
                    s = fmaf(wt[k][hh * 33 + wx], wk[k][(dy + 1) * 3 + (dx + 1)], s);
                }
            }
            tg[k] = s;
        }
        float u00 = 0.5f * (tg[0] - tg[1] - tg[2] + tg[3]);
        float u01 = 0.5f * (tg[0] - tg[1] + tg[2] - tg[3]);
        float u10 = 0.5f * (tg[0] + tg[1] - tg[2] - tg[3]);
        float u11 = 0.5f * (tg[0] + tg[1] + tg[2] + tg[3]);
        upp[(2 * h) * 64 + 2 * w]         = u00;
        upp[(2 * h) * 64 + 2 * w + 1]     = u01;
        upp[(2 * h + 1) * 64 + 2 * w]     = u10;
        upp[(2 * h + 1) * 64 + 2 * w + 1] = u11;
    }
}

// ---------------------------------------------------------------------------
// SS2D input projection v3: register-blocked GEMM. Block = (b, 2 h-rows).
// Thread tile: 8 outputs x 8 pixels. K split in two 32-wide stages.
// Per K-step: 2 b128 (weights, LDS-transposed) + 2 b128 (pixels) -> 64 FMA.
// Accumulation order over c ascending 0..63 (identical to previous version).
// ---------------------------------------------------------------------------
__global__ __launch_bounds__(256) void k_inproj(const float* __restrict__ x,
                                                const float* __restrict__ in_w,
                                                float* __restrict__ xi,
                                                float* __restrict__ z) {
    int h0 = blockIdx.x * 2;             // two spatial rows
    int b  = blockIdx.y;
    __shared__ float xs[32 * 128];       // [c_loc][px]
    __shared__ float wt[32 * 128];       // [c_loc][o]
    int tid = threadIdx.x;

    float acc[8][8];
#pragma unroll
    for (int i = 0; i < 8; ++i)
#pragma unroll
        for (int j = 0; j < 8; ++j) acc[i][j] = 0.f;

    int o0 = (tid >> 4) * 8;             // 16 output groups of 8
    int p0 = (tid & 15) * 8;             // 16 pixel groups of 8

    for (int ko = 0; ko < 64; ko += 32) {
        if (ko) __syncthreads();
        // stage xs: 32c x 128px (coalesced float4)
        {
            int s = tid;
#pragma unroll
            for (int it = 0; it < 4; ++it, s += 256) {
                int c = s >> 5, p4 = (s & 31) * 4;
                float4 v = *(const float4*)(x + ((size_t)b * DIM + ko + c) * HW + h0 * 64 + p4);
                *(float4*)(xs + c * 128 + p4) = v;
            }
        }
        // stage wt: transpose of in_w[o][ko+c]
        {
            int s = tid;
#pragma unroll
            for (int it = 0; it < 4; ++it, s += 256) {
                int o = s >> 3, c0 = (s & 7) * 4;
                float4 v = *(const float4*)(in_w + o * 64 + ko + c0);
                wt[(c0 + 0) * 128 + o] = v.x;
                wt[(c0 + 1) * 128 + o] = v.y;
                wt[(c0 + 2) * 128 + o] = v.z;
                wt[(c0 + 3) * 128 + o] = v.w;
            }
        }
        __syncthreads();
#pragma unroll 4
        for (int c = 0; c < 32; ++c) {
            float xv[8], wv[8];
            *(float4*)(xv)     = *(const float4*)(xs + c * 128 + p0);
            *(float4*)(xv + 4) = *(const float4*)(xs + c * 128 + p0 + 4);
            *(float4*)(wv)     = *(const float4*)(wt + c * 128 + o0);
            *(float4*)(wv + 4) = *(const float4*)(wt + c * 128 + o0 + 4);
#pragma unroll
            for (int i = 0; i < 8; ++i)
#pragma unroll
                for (int j = 0; j < 8; ++j)
                    acc[i][j] = fmaf(wv[i], xv[j], acc[i][j]);
        }
    }

#pragma unroll
    for (int i = 0; i < 8; ++i) {
        int o = o0 + i;
        float* dst = (o < 64) ? (xi + ((size_t)b * 64 + o) * HW + h0 * 64)
                              : (z + ((size_t)b * 64 + (o - 64)) * HW + h0 * 64);
        *(float4*)(dst + p0)     = make_float4(acc[i][0], acc[i][1], acc[i][2], acc[i][3]);
        *(float4*)(dst + p0 + 4) = make_float4(acc[i][4], acc[i][5], acc[i][6], acc[i][7]);
    }
}

// ---------------------------------------------------------------------------
// xc = silu(depthwise3x3(xi) + cb). Block per (b, c) plane.
// ---------------------------------------------------------------------------
__global__ __launch_bounds__(256) void k_dwss(const float* __restrict__ xi,
                                              const float* __restrict__ cw,
                                              const float* __restrict__ cb,
                                              float* __restrict__ xc) {
    int c = blockIdx.x, b = blockIdx.y;
    __shared__ float t[66 * 66];
    const float* p = xi + ((size_t)b * 64 + c) * HW;
    for (int i = threadIdx.x; i < 66 * 66; i += 256) {
        int y = i / 66 - 1, xq = i % 66 - 1;
        t[i] = (y >= 0 && y < 64 && xq >= 0 && xq < 64) ? p[y * 64 + xq] : 0.f;
    }
    __syncthreads();
    float wk[9];
#pragma unroll
    for (int j = 0; j < 9; ++j) wk[j] = cw[c * 9 + j];
    float bias = cb[c];
    float* q = xc + ((size_t)b * 64 + c) * HW;
    for (int i = threadIdx.x; i < HW; i += 256) {
        int y = i >> 6, xq = i & 63;
        float s = bias;
#pragma unroll
        for (int dy = 0; dy < 3; ++dy)
#pragma unroll
            for (int dx = 0; dx < 3; ++dx)
                s = fmaf(t[(y + dy) * 66 + xq + dx], wk[dy * 3 + dx], s);
        q[i] = silu_f(s);
    }
}

// ---------------------------------------------------------------------------
// Per-pixel projections, SoA output: proj4 = (dt0..dt3) float4 plane,
// projBC = (Bm, Cm) float2 plane, per (dir, b). Block per (b, h row).
// ---------------------------------------------------------------------------
__global__ __launch_bounds__(256) void k_ssproj(const float* __restrict__ xc,
                                                const float* __restrict__ xpw,
                                                float4* __restrict__ proj4,
                                                float2* __restrict__ projBC) {
    int h = blockIdx.x, b = blockIdx.y;
    __shared__ float xs[64 * 65];
    for (int i = threadIdx.x; i < 64 * 64; i += 256) {
        int c = i >> 6, w = i & 63;
        xs[c * 65 + w] = xc[((size_t)b * 64 + c) * HW + h * 64 + w];
    }
    __syncthreads();
    int w = threadIdx.x & 63;
    int g = threadIdx.x >> 6;
    int dir = g >> 1;
    int l = (dir == 0) ? (h * 64 + w) : (w * 64 + h);
    size_t base = ((size_t)dir * NB + b) * HW + l;
    const float* wp = xpw + dir * 6 * 64;
    if ((g & 1) == 0) {
        float s0 = 0.f, s1 = 0.f, s2 = 0.f, s3 = 0.f;
        for (int c = 0; c < 64; ++c) {
            float xv = xs[c * 65 + w];
            s0 = fmaf(xv, wp[0 * 64 + c], s0);
            s1 = fmaf(xv, wp[1 * 64 + c], s1);
            s2 = fmaf(xv, wp[2 * 64 + c], s2);
            s3 = fmaf(xv, wp[3 * 64 + c], s3);
        }
        proj4[base] = make_float4(s0, s1, s2, s3);
    } else {
        float s4 = 0.f, s5 = 0.f;
        for (int c = 0; c < 64; ++c) {
            float xv = xs[c * 65 + w];
            s4 = fmaf(xv, wp[4 * 64 + c], s4);
            s5 = fmaf(xv, wp[5 * 64 + c], s5);
        }
        projBC[base] = make_float2(s4, s5);
    }
}

// ---------------------------------------------------------------------------
// Selective scan (N=1), chunk-parallel + LDS ownership transpose.
// ---------------------------------------------------------------------------
__global__ __launch_bounds__(256) void k_scan(const float* __restrict__ xc,
                                              const float4* __restrict__ proj4,
                                              const float2* __restrict__ projBC,
                                              const float* __restrict__ dt_w,
                                              const float* __restrict__ dt_b,
                                              const float* __restrict__ A_log,
                                              const float* __restrict__ Dp,
                                              float* __restrict__ y0,
                                              float* __restrict__ y1) {
    int wave = threadIdx.x >> 6;
    int lane = threadIdx.x & 63;
    int wid = blockIdx.x;
    int b = wid >> 7;
    int rem = wid & 127;
    int dir = rem >> 6;                  // uniform per block
    int d = rem & 63;
    int pd = dir * 64 + d;

    float4 wv = *(const float4*)(dt_w + pd * 4);
    float db = dt_b[pd];
    float A = -__expf(A_log[pd]);
    float Dv = Dp[pd];
    const float4* p4 = proj4 + ((size_t)dir * NB + b) * HW;
    const float2* pBC = projBC + ((size_t)dir * NB + b) * HW;
    const float* uplane = xc + ((size_t)b * 64 + d) * HW;
    float* yp = ((dir == 0) ? y0 : y1) + ((size_t)b * 64 + d) * HW;

    __shared__ float ut[64 * 65];        // u plane tile (later y tile for dir1)
    __shared__ float al[4][1088];        // (a) then (h), padded seg*17+pos
    __shared__ float bl[4][1088];        // (b)
    __shared__ float aggA[4], aggB[4];

    const float4* up4 = (const float4*)uplane;
#pragma unroll
    for (int q = 0; q < 4; ++q) {
        int s = q * 256 + threadIdx.x;
        float4 v = up4[s];
        int r = s >> 4, c0 = (s & 15) * 4;
        float* p = ut + r * 65 + c0;
        p[0] = v.x; p[1] = v.y; p[2] = v.z; p[3] = v.w;
    }
    __syncthreads();

    int ch = wave;
    float* a_my = al[wave];
    float* b_my = bl[wave];

    // ---- phase A: coalesced loads, compute (a,b), scatter to padded LDS ----
#pragma unroll
    for (int j = 0; j < 16; ++j) {
        int el = j * 64 + lane;
        int e  = ch * 1024 + el;
        float4 t4 = p4[e];
        float2 t2 = pBC[e];
        float u = (dir == 0) ? ut[(ch * 16 + j) * 65 + lane]
                             : ut[lane * 65 + (ch * 16 + j)];
        float pre = fmaf(t4.x, wv.x, fmaf(t4.y, wv.y,
                    fmaf(t4.z, wv.z, fmaf(t4.w, wv.w, db))));
        float delta = softplus_fast(pre);
        float aj = __expf(delta * A);
        float bj = delta * t2.x * u;
        int idx = (el >> 4) * 17 + (el & 15);
        a_my[idx] = aj;
        b_my[idx] = bj;
    }
    __builtin_amdgcn_wave_barrier();

    // ---- phase B: per-lane segment compose + cross-lane scan ----
    float a[16], bb[16];
#pragma unroll
    for (int j = 0; j < 16; ++j) {
        a[j]  = a_my[lane * 17 + j];
        bb[j] = b_my[lane * 17 + j];
    }
    float As = 1.f, Bs = 0.f;
#pragma unroll
    for (int j = 0; j < 16; ++j) { Bs = fmaf(a[j], Bs, bb[j]); As *= a[j]; }
    float Ai = As, Bi = Bs;
#pragma unroll
    for (int off = 1; off < 64; off <<= 1) {
        float ap = __shfl_up(Ai, (unsigned)off, 64);
        float bp = __shfl_up(Bi, (unsigned)off, 64);
        if (lane >= off) { Bi = fmaf(Ai, bp, Bi); Ai *= ap; }
    }
    if (lane == 63) { aggA[wave] = Ai; aggB[wave] = Bi; }
    __syncthreads();
    float carry = 0.f;
    for (int k = 0; k < wave; ++k) carry = fmaf(aggA[k], carry, aggB[k]);
    float ap1 = __shfl_up(Ai, 1, 64);
    float bp1 = __shfl_up(Bi, 1, 64);
    float h = (lane == 0) ? carry : fmaf(ap1, carry, bp1);
#pragma unroll
    for (int j = 0; j < 16; ++j) {
        h = fmaf(a[j], h, bb[j]);
        a_my[lane * 17 + j] = h;         // h overwrites a slot
    }
    __builtin_amdgcn_wave_barrier();

    // ---- phase C: coalesced apply + store ----
    if (dir == 0) {
#pragma unroll
        for (int j = 0; j < 16; ++j) {
            int el = j * 64 + lane;
            int e  = ch * 1024 + el;
            float hv = a_my[(el >> 4) * 17 + (el & 15)];
            float cmv = pBC[e].y;
            float u = ut[(ch * 16 + j) * 65 + lane];
            yp[e] = fmaf(hv, cmv, Dv * u);
        }
    } else {
#pragma unroll
        for (int j = 0; j < 16; ++j) {
            int el = j * 64 + lane;
            int e  = ch * 1024 + el;
            float hv = a_my[(el >> 4) * 17 + (el & 15)];
            float cmv = pBC[e].y;
            int w = ch * 16 + j;
            float u = ut[lane * 65 + w];
            ut[lane * 65 + w] = fmaf(hv, cmv, Dv * u);   // y in place
        }
        __syncthreads();
#pragma unroll
        for (int q = 0; q < 4; ++q) {
            int s = q * 256 + threadIdx.x;
            int r = s >> 4, c0 = (s & 15) * 4;
            const float* p = ut + r * 65 + c0;
            ((float4*)yp)[s] = make_float4(p[0], p[1], p[2], p[3]);
        }
    }
}

// ---------------------------------------------------------------------------
// Final v3: register-blocked. Block = (b, 2 h-rows). Thread tile 8o x 4px.
// yv = (y0+y1)*silu(z) staged per 32-c half; weights LDS-transposed.
// Accumulation order over c ascending 0..63 (identical to previous version).
// ---------------------------------------------------------------------------
__global__ __launch_bounds__(256) void k_final(const float* __restrict__ y0,
                                               const float* __restrict__ y1,
                                               const float* __restrict__ z,
                                               const float* __restrict__ ow,
                                               const float* __restrict__ base_scale,
                                               const float* __restrict__ up,
                                               float* __restrict__ out) {
    int h0 = blockIdx.x * 2;
    int b  = blockIdx.y;
    __shared__ float yv[32 * 128];       // [c_loc][px]
    __shared__ float wt[32 * 64];        // [c_loc][o]
    int tid = threadIdx.x;

    float acc[8][4];
#pragma unroll
    for (int i = 0; i < 8; ++i)
#pragma unroll
        for (int j = 0; j < 4; ++j) acc[i][j] = 0.f;

    int o0 = (tid >> 5) * 8;             // 8 output groups of 8
    int p0 = (tid & 31) * 4;             // 32 pixel groups of 4

    for (int ko = 0; ko < 64; ko += 32) {
        if (ko) __syncthreads();
        // stage yv
        {
            int s = tid;
#pragma unroll
            for (int it = 0; it < 4; ++it, s += 256) {
                int c = s >> 5, p4 = (s & 31) * 4;
                size_t idx = ((size_t)b * 64 + ko + c) * HW + h0 * 64 + p4;
                float4 a  = *(const float4*)(y0 + idx);
                float4 bb = *(const float4*)(y1 + idx);
                float4 zz = *(const float4*)(z + idx);
                float4 r;
                r.x = (a.x + bb.x) * silu_f(zz.x);
                r.y = (a.y + bb.y) * silu_f(zz.y);
                r.z = (a.z + bb.z) * silu_f(zz.z);
                r.w = (a.w + bb.w) * silu_f(zz.w);
                *(float4*)(yv + c * 128 + p4) = r;
            }
        }
        // stage wt: transpose of ow[o][ko+c] (64o x 32c = 512 float4)
        {
            int s = tid;
#pragma unroll
            for (int it = 0; it < 2; ++it, s += 256) {
                int o = s >> 3, c0 = (s & 7) * 4;
                float4 v = *(const float4*)(ow + o * 64 + ko + c0);
                wt[(c0 + 0) * 64 + o] = v.x;
                wt[(c0 + 1) * 64 + o] = v.y;
                wt[(c0 + 2) * 64 + o] = v.z;
                wt[(c0 + 3) * 64 + o] = v.w;
            }
        }
        __syncthreads();
#pragma unroll 4
        for (int c = 0; c < 32; ++c) {
            float wv[8], xv[4];
            *(float4*)(wv)     = *(const float4*)(wt + c * 64 + o0);
            *(float4*)(wv + 4) = *(const float4*)(wt + c * 64 + o0 + 4);
            *(float4*)(xv)     = *(const float4*)(yv + c * 128 + p0);
#pragma unroll
            for (int i = 0; i < 8; ++i)
#pragma unroll
                for (int j = 0; j < 4; ++j)
                    acc[i][j] = fmaf(wv[i], xv[j], acc[i][j]);
        }
    }

#pragma unroll
    for (int i = 0; i < 8; ++i) {
        int o = o0 + i;
        float bs = base_scale[o];
        float4 u = *(const float4*)(up + ((size_t)b * 64 + o) * HW + h0 * 64 + p0);
        float4 r = make_float4(fmaf(bs, acc[i][0], u.x),
                               fmaf(bs, acc[i][1], u.y),
                               fmaf(bs, acc[i][2], u.z),
                               fmaf(bs, acc[i][3], u.w));
        *(float4*)(out + ((size_t)b * DIM + o) * HW + h0 * 64 + p0) = r;
    }
}

// ---------------------------------------------------------------------------
extern "C" void kernel_launch(void* const* d_in, const int* in_sizes, int n_in,
                              void* d_out, int out_size, void* d_ws, size_t ws_size,
                              hipStream_t stream) {
    (void)in_sizes; (void)n_in; (void)out_size; (void)ws_size;
    const float* x = (const float*)d_in[0];
    float* out = (float*)d_out;
    float* ws = (float*)d_ws;

    const size_t IMG = (size_t)NB * 64 * HW;   // 4,194,304 floats
    float* buf_xi   = ws;                      // reused as y0 after consumption
    float* buf_z    = ws + IMG;
    float* buf_xc   = ws + 2 * IMG;
    float* buf_up   = ws + 3 * IMG;
    float* buf_y1   = ws + 4 * IMG;
    float* buf_p4   = ws + 5 * IMG;            // float4[2*16*4096]
    float* buf_pBC  = buf_p4 + (size_t)4 * 2 * NB * HW;
    float* buf_mean = buf_pBC + (size_t)2 * 2 * NB * HW;
    float* buf_w3   = buf_mean + 1024;
    float* buf_w5   = buf_w3 + 16 * 64 * 9;
    float* buf_w7   = buf_w5 + 16 * 64 * 25;

    // ---- local branch ----
    k_mean<<<1024, 256, 0, stream>>>(x, buf_mean);
    k_weff<<<16, 64, 0, stream>>>(buf_mean, (const float*)d_in[1],
                                  (const float*)d_in[2], (const float*)d_in[3], buf_w3, 9);
    k_weff<<<16, 64, 0, stream>>>(buf_mean, (const float*)d_in[8],
                                  (const float*)d_in[9], (const float*)d_in[10], buf_w5, 25);
    k_weff<<<16, 64, 0, stream>>>(buf_mean, (const float*)d_in[15],
                                  (const float*)d_in[16], (const float*)d_in[17], buf_w7, 49);
    k_local<<<dim3(4, 64, 16), 256, 0, stream>>>(x, buf_w3, buf_w5, buf_w7,
        (const float*)d_in[4],  (const float*)d_in[5],  (const float*)d_in[6],  (const float*)d_in[7],
        (const float*)d_in[11], (const float*)d_in[12], (const float*)d_in[13], (const float*)d_in[14],
        (const float*)d_in[18], (const float*)d_in[19], (const float*)d_in[20], (const float*)d_in[21],
        out);

    // ---- wavelet branch ----
    k_up<<<dim3(64, 16), 256, 0, stream>>>(x, (const float*)d_in[22],
        (const float*)d_in[23], (const float*)d_in[24], buf_up);

    // ---- ss2d ----
    k_inproj<<<dim3(32, 16), 256, 0, stream>>>(x, (const float*)d_in[26], buf_xi, buf_z);
    k_dwss<<<dim3(64, 16), 256, 0, stream>>>(buf_xi, (const float*)d_in[27],
        (const float*)d_in[28], buf_xc);
    k_ssproj<<<dim3(64, 16), 256, 0, stream>>>(buf_xc, (const float*)d_in[29],
        (float4*)buf_p4, (float2*)buf_pBC);
    k_scan<<<2048, 256, 0, stream>>>(buf_xc, (const float4*)buf_p4, (const float2*)buf_pBC,
        (const float*)d_in[30], (const float*)d_in[31],
        (const float*)d_in[32], (const float*)d_in[33],
        buf_xi /* y0 (xi is dead now) */, buf_y1);
    k_final<<<dim3(32, 16), 256, 0, stream>>>(buf_xi, buf_y1, buf_z,
        (const float*)d_in[34], (const float*)d_in[25], buf_up, out);

    // ---- passthrough ----
    k_copy_xi<<<(16 * 128 * HW / 4) / 256, 256, 0, stream>>>((const float4*)x, (float4*)out);
}

// Round 8
// 147.073 us; speedup vs baseline: 1.5984x; 1.2193x over previous
//
#include <hip/hip_runtime.h>
#include <math.h>

// Problem constants
static constexpr int NB   = 16;    // batch
static constexpr int DIM  = 256;   // total channels
static constexpr int CG   = 64;    // global-branch channels
static constexpr int HH   = 64;
static constexpr int WW   = 64;
static constexpr int HW   = HH * WW;   // 4096

// mish(x) = x*tanh(softplus(x)) = x*(t^2+2t)/(t^2+2t+2), t=e^x.
__device__ __forceinline__ float mish_fast(float x) {
    float t = __expf(fminf(x, 20.f));
    float p = __builtin_fmaf(t, t, t + t);         // t^2 + 2t
    return x * p * __builtin_amdgcn_rcpf(p + 2.f);
}
__device__ __forceinline__ float silu_f(float x) {
    return x * __builtin_amdgcn_rcpf(1.f + __expf(-x));
}
// softplus via hw exp/log: max(x,0) + log(1 + e^-|x|). Error vs log1pf < 2 ulp.
__device__ __forceinline__ float softplus_fast(float x) {
    return fmaxf(x, 0.f) + __logf(1.f + __expf(-fabsf(x)));
}

// ---------------------------------------------------------------------------
// Local branch: per-(b,c) channel mean of xl
// ---------------------------------------------------------------------------
__global__ __launch_bounds__(256) void k_mean(const float* __restrict__ x,
                                              float* __restrict__ mean) {
    int bc = blockIdx.x;
    int b = bc >> 6, c = bc & 63;
    const float* p = x + ((size_t)b * DIM + 64 + c) * HW;
    float s = 0.f;
    for (int i = threadIdx.x; i < HW; i += 256) s += p[i];
    __shared__ float red[256];
    red[threadIdx.x] = s;
    __syncthreads();
    for (int o = 128; o > 0; o >>= 1) {
        if (threadIdx.x < o) red[threadIdx.x] += red[threadIdx.x + o];
        __syncthreads();
    }
    if (threadIdx.x == 0) mean[bc] = red[0] * (1.f / HW);
}

// ---------------------------------------------------------------------------
// All three expert-mixes in one launch. Block per b, 64 threads.
// ---------------------------------------------------------------------------
__global__ void k_weff_all(const float* __restrict__ mean,
                           const float* __restrict__ ew3, const float* __restrict__ gw3,
                           const float* __restrict__ g13,
                           const float* __restrict__ ew5, const float* __restrict__ gw5,
                           const float* __restrict__ g15,
                           const float* __restrict__ ew7, const float* __restrict__ gw7,
                           const float* __restrict__ g17,
                           float* __restrict__ w3o, float* __restrict__ w5o,
                           float* __restrict__ w7o) {
    int b = blockIdx.x;
    int c = threadIdx.x;                 // 64 threads
    __shared__ float m[64];
    __shared__ float g[4];
    m[c] = mean[b * 64 + c];
    __syncthreads();
    const float rs = rsqrtf(1.f + 1e-5f);

#define WEFF_SECT(GW, EW, G1, OUT, K2)                                        \
    {                                                                         \
        if (c < 4) {                                                          \
            float l = 0.f;                                                    \
            for (int cc = 0; cc < 64; ++cc) l += m[cc] * GW[c * 64 + cc];     \
            g[c] = l;                                                         \
        }                                                                     \
        __syncthreads();                                                      \
        if (c == 0) {                                                         \
            float mx = fmaxf(fmaxf(g[0], g[1]), fmaxf(g[2], g[3]));           \
            float e0 = expf(g[0] - mx), e1 = expf(g[1] - mx);                 \
            float e2 = expf(g[2] - mx), e3 = expf(g[3] - mx);                 \
            float inv = 1.f / (e0 + e1 + e2 + e3);                            \
            g[0] = e0 * inv; g[1] = e1 * inv; g[2] = e2 * inv; g[3] = e3 * inv;\
        }                                                                     \
        __syncthreads();                                                      \
        float g1s = G1[c] * rs;                                               \
        for (int kk = 0; kk < K2; ++kk) {                                     \
            float w = 0.f;                                                    \
            for (int e = 0; e < 4; ++e) w += g[e] * EW[(e * 64 + c) * K2 + kk];\
            OUT[(b * 64 + c) * K2 + kk] = w * g1s;                            \
        }                                                                     \
        __syncthreads();                                                      \
    }

    WEFF_SECT(gw3, ew3, g13, w3o, 9)
    WEFF_SECT(gw5, ew5, g15, w5o, 25)
    WEFF_SECT(gw7, ew7, g17, w7o, 49)
#undef WEFF_SECT
}

// ---------------------------------------------------------------------------
// Local branch conv: register-blocked, 4-wide strips, b128 row loads.
// Fused: each block also copies 512 float4 of the x[:,128:256] passthrough
// (HBM-bound copy hides under the VALU-bound conv).
// ---------------------------------------------------------------------------
__global__ __launch_bounds__(256) void k_local(
    const float* __restrict__ x,
    const float* __restrict__ w3, const float* __restrict__ w5, const float* __restrict__ w7,
    const float* __restrict__ b1_0, const float* __restrict__ pw0,
    const float* __restrict__ g2_0, const float* __restrict__ b2_0,
    const float* __restrict__ b1_1, const float* __restrict__ pw1,
    const float* __restrict__ g2_1, const float* __restrict__ b2_1,
    const float* __restrict__ b1_2, const float* __restrict__ pw2,
    const float* __restrict__ g2_2, const float* __restrict__ b2_2,
    float* __restrict__ out) {
    int tile = blockIdx.x;
    int c = blockIdx.y, b = blockIdx.z;
    int oy = (tile >> 1) * 32, ox = (tile & 1) * 32;
    __shared__ float t[38 * 40];
    const float* xp = x + ((size_t)b * DIM + 64 + c) * HW;
    for (int i = threadIdx.x; i < 38 * 38; i += 256) {
        int r = i / 38, cc = i % 38;
        int yy = r - 3 + oy, xx = cc - 3 + ox;
        t[r * 40 + cc] = (yy >= 0 && yy < 64 && xx >= 0 && xx < 64) ? xp[yy * 64 + xx] : 0.f;
    }
    // fused passthrough copy (independent of LDS/barrier)
    {
        int bl = tile + 4 * c + 256 * b;             // 0..4095
        const float4* x4 = (const float4*)x;
        float4* o4 = (float4*)out;
        int base = bl * 512;
#pragma unroll
        for (int it = 0; it < 2; ++it) {
            int idx = base + it * 256 + threadIdx.x;
            int bb = idx >> 17;                      // /131072
            int r  = idx & 131071;
            int gi = bb * 262144 + 131072 + r;       // 262144 = DIM*HW/4
            o4[gi] = x4[gi];
        }
    }
    const float* w3p = w3 + (b * 64 + c) * 9;
    const float* w5p = w5 + (b * 64 + c) * 25;
    const float* w7p = w7 + (b * 64 + c) * 49;
    float W3r[9], W5r[25], W7r[49];
#pragma unroll
    for (int j = 0; j < 9; ++j)  W3r[j] = w3p[j];
#pragma unroll
    for (int j = 0; j < 25; ++j) W5r[j] = w5p[j];
#pragma unroll
    for (int j = 0; j < 49; ++j) W7r[j] = w7p[j];
    __syncthreads();

    const float rs = rsqrtf(1.f + 1e-5f);
    float bb1a = b1_0[c], bb1b = b1_1[c], bb1c = b1_2[c];
    float ssa = pw0[c] * g2_0[c] * rs, ssb = pw1[c] * g2_1[c] * rs, ssc = pw2[c] * g2_2[c] * rs;
    float bb2a = b2_0[c], bb2b = b2_1[c], bb2c = b2_2[c];

    int y  = threadIdx.x >> 3;
    int x0 = (threadIdx.x & 7) * 4;

    float a3[4] = {0.f, 0.f, 0.f, 0.f};
    float a5[4] = {0.f, 0.f, 0.f, 0.f};
    float a7[4] = {0.f, 0.f, 0.f, 0.f};

#pragma unroll
    for (int dy = 0; dy < 7; ++dy) {
        const float4* rp = (const float4*)(t + (y + dy) * 40 + x0);
        float4 q0 = rp[0], q1 = rp[1], q2 = rp[2];
        float r[12] = {q0.x, q0.y, q0.z, q0.w, q1.x, q1.y, q1.z, q1.w,
                       q2.x, q2.y, q2.z, q2.w};
#pragma unroll
        for (int k = 0; k < 4; ++k)
#pragma unroll
            for (int dx = 0; dx < 7; ++dx)
                a7[k] = fmaf(r[k + dx], W7r[dy * 7 + dx], a7[k]);
        if (dy >= 1 && dy <= 5) {
            int ey = dy - 1;
#pragma unroll
            for (int k = 0; k < 4; ++k)
#pragma unroll
                for (int dx = 0; dx < 5; ++dx)
                    a5[k] = fmaf(r[k + 1 + dx], W5r[ey * 5 + dx], a5[k]);
        }
        if (dy >= 2 && dy <= 4) {
            int ey = dy - 2;
#pragma unroll
            for (int k = 0; k < 4; ++k)
#pragma unroll
                for (int dx = 0; dx < 3; ++dx)
                    a3[k] = fmaf(r[k + 2 + dx], W3r[ey * 3 + dx], a3[k]);
        }
    }

    float4 res;
    float* rr = (float*)&res;
#pragma unroll
    for (int k = 0; k < 4; ++k) {
        rr[k] = mish_fast(a3[k] + bb1a) * ssa + bb2a
              + mish_fast(a5[k] + bb1b) * ssb + bb2b
              + mish_fast(a7[k] + bb1c) * ssc + bb2c;
    }
    float* op = out + ((size_t)b * DIM + 64 + c) * HW;
    *(float4*)(op + (oy + y) * 64 + ox + x0) = res;
}

// ---------------------------------------------------------------------------
// Fused wavelet: Haar dec -> dw3x3 conv -> Haar rec. One block per (b,c).
// ---------------------------------------------------------------------------
__global__ __launch_bounds__(256) void k_up(const float* __restrict__ x,
                                            const float* __restrict__ wav_w,
                                            const float* __restrict__ wav_b,
                                            const float* __restrict__ wav_scale,
                                            float* __restrict__ up) {
    int c = blockIdx.x, b = blockIdx.y;
    __shared__ float xs[64 * 65];
    __shared__ float wt[4][32 * 33];
    const float* xp = x + ((size_t)b * DIM + c) * HW;
    for (int i = threadIdx.x; i < HW; i += 256) xs[(i >> 6) * 65 + (i & 63)] = xp[i];
    __syncthreads();
    for (int i = threadIdx.x; i < 1024; i += 256) {
        int h = i >> 5, w = i & 31;
        float a  = xs[(2 * h) * 65 + 2 * w],     bb = xs[(2 * h) * 65 + 2 * w + 1];
        float cc = xs[(2 * h + 1) * 65 + 2 * w], dd = xs[(2 * h + 1) * 65 + 2 * w + 1];
        wt[0][h * 33 + w] = 0.5f * (a + bb + cc + dd);
        wt[1][h * 33 + w] = 0.5f * (a + bb - cc - dd);
        wt[2][h * 33 + w] = 0.5f * (a - bb + cc - dd);
        wt[3][h * 33 + w] = 0.5f * (a - bb - cc + dd);
    }
    __syncthreads();
    float wk[4][9], tb[4];
#pragma unroll
    for (int k = 0; k < 4; ++k) {
        int ch = c * 4 + k;
        float sc = wav_scale[ch];
#pragma unroll
        for (int j = 0; j < 9; ++j) wk[k][j] = wav_w[ch * 9 + j] * sc;
        tb[k] = wav_b[ch] * sc;
    }
    float* upp = up + ((size_t)b * CG + c) * HW;
    for (int i = threadIdx.x; i < 1024; i += 256) {
        int h = i >> 5, w = i & 31;
        float tg[4];
#pragma unroll
        for (int k = 0; k < 4; ++k) {
            float s = tb[k];
#pragma unroll
            for (int dy = -1; dy <= 1; ++dy) {
                int hh = h + dy;
                if (hh < 0 || hh >= 32) continue;
#pragma unroll
                for (int dx = -1; dx <= 1; ++dx) {
                    int wx = w + dx;
                    if (wx < 0 || wx >= 32) continue;
                    s = fmaf(wt[k][hh * 33 + wx], wk[k][(dy + 1) * 3 + (dx + 1)], s);
                }
            }
            tg[k] = s;
        }
        float u00 = 0.5f * (tg[0] - tg[1] - tg[2] + tg[3]);
        float u01 = 0.5f * (tg[0] - tg[1] + tg[2] - tg[3]);
        float u10 = 0.5f * (tg[0] + tg[1] - tg[2] - tg[3]);
        float u11 = 0.5f * (tg[0] + tg[1] + tg[2] + tg[3]);
        upp[(2 * h) * 64 + 2 * w]         = u00;
        upp[(2 * h) * 64 + 2 * w + 1]     = u01;
        upp[(2 * h + 1) * 64 + 2 * w]     = u10;
        upp[(2 * h + 1) * 64 + 2 * w + 1] = u11;
    }
}

// ---------------------------------------------------------------------------
// SS2D input projection: register-blocked GEMM. Block = (b, 2 h-rows).
// ---------------------------------------------------------------------------
__global__ __launch_bounds__(256) void k_inproj(const float* __restrict__ x,
                                                const float* __restrict__ in_w,
                                                float* __restrict__ xi,
                                                float* __restrict__ z) {
    int h0 = blockIdx.x * 2;
    int b  = blockIdx.y;
    __shared__ float xs[32 * 128];
    __shared__ float wt[32 * 128];
    int tid = threadIdx.x;

    float acc[8][8];
#pragma unroll
    for (int i = 0; i < 8; ++i)
#pragma unroll
        for (int j = 0; j < 8; ++j) acc[i][j] = 0.f;

    int o0 = (tid >> 4) * 8;
    int p0 = (tid & 15) * 8;

    for (int ko = 0; ko < 64; ko += 32) {
        if (ko) __syncthreads();
        {
            int s = tid;
#pragma unroll
            for (int it = 0; it < 4; ++it, s += 256) {
                int c = s >> 5, p4 = (s & 31) * 4;
                float4 v = *(const float4*)(x + ((size_t)b * DIM + ko + c) * HW + h0 * 64 + p4);
                *(float4*)(xs + c * 128 + p4) = v;
            }
        }
        {
            int s = tid;
#pragma unroll
            for (int it = 0; it < 4; ++it, s += 256) {
                int o = s >> 3, c0 = (s & 7) * 4;
                float4 v = *(const float4*)(in_w + o * 64 + ko + c0);
                wt[(c0 + 0) * 128 + o] = v.x;
                wt[(c0 + 1) * 128 + o] = v.y;
                wt[(c0 + 2) * 128 + o] = v.z;
                wt[(c0 + 3) * 128 + o] = v.w;
            }
        }
        __syncthreads();
#pragma unroll 4
        for (int c = 0; c < 32; ++c) {
            float xv[8], wv[8];
            *(float4*)(xv)     = *(const float4*)(xs + c * 128 + p0);
            *(float4*)(xv + 4) = *(const float4*)(xs + c * 128 + p0 + 4);
            *(float4*)(wv)     = *(const float4*)(wt + c * 128 + o0);
            *(float4*)(wv + 4) = *(const float4*)(wt + c * 128 + o0 + 4);
#pragma unroll
            for (int i = 0; i < 8; ++i)
#pragma unroll
                for (int j = 0; j < 8; ++j)
                    acc[i][j] = fmaf(wv[i], xv[j], acc[i][j]);
        }
    }

#pragma unroll
    for (int i = 0; i < 8; ++i) {
        int o = o0 + i;
        float* dst = (o < 64) ? (xi + ((size_t)b * 64 + o) * HW + h0 * 64)
                              : (z + ((size_t)b * 64 + (o - 64)) * HW + h0 * 64);
        *(float4*)(dst + p0)     = make_float4(acc[i][0], acc[i][1], acc[i][2], acc[i][3]);
        *(float4*)(dst + p0 + 4) = make_float4(acc[i][4], acc[i][5], acc[i][6], acc[i][7]);
    }
}

// ---------------------------------------------------------------------------
// Fused dwconv3x3+silu -> xc, and 6-way projections (both dirs) -> proj.
// Block = (b, 2 h-rows). Two 32-channel halves: stage xi rows h0-1..h0+2 in
// LDS (guard cols), compute xc (depthwise, complete per half), store xc,
// accumulate projections across halves (c ascending 0..63).
// ---------------------------------------------------------------------------
__global__ __launch_bounds__(256) void k_convproj(const float* __restrict__ xi,
                                                  const float* __restrict__ cw,
                                                  const float* __restrict__ cb,
                                                  const float* __restrict__ xpw,
                                                  float* __restrict__ xc,
                                                  float4* __restrict__ proj4,
                                                  float2* __restrict__ projBC) {
    int h0 = blockIdx.x * 2;
    int b  = blockIdx.y;
    int tid = threadIdx.x;

    __shared__ float xs[32 * 264];       // [cl][r 0..3][66], data at w+1
    __shared__ float xcs[32 * 130];      // [cl][px 0..127]

    // proj thread role: dir = tid>>7 (wave-uniform), px = tid&127
    int dir = tid >> 7;
    int px  = tid & 127;
    float acc0 = 0.f, acc1 = 0.f, acc2 = 0.f, acc3 = 0.f, acc4 = 0.f, acc5 = 0.f;

    // conv thread role
    int cl_c = tid >> 3;                 // 0..31
    int p0_c = (tid & 7) * 16;           // 16 px in one row
    int row_c = p0_c >> 6;
    int wb_c  = p0_c & 63;

    for (int ch0 = 0; ch0 < 64; ch0 += 32) {
        if (ch0) __syncthreads();        // protect xcs reads of prev half
        // ---- stage xi rows h0-1 .. h0+2 for 32 channels ----
        {
            int s = tid;
#pragma unroll
            for (int it = 0; it < 8; ++it, s += 256) {
                int c = s >> 6;                  // 0..31
                int rem = s & 63;
                int r = rem >> 4, w4 = (rem & 15) * 4;
                int gh = h0 - 1 + r;
                float4 v = make_float4(0.f, 0.f, 0.f, 0.f);
                if (gh >= 0 && gh < 64)
                    v = *(const float4*)(xi + ((size_t)b * 64 + ch0 + c) * HW + gh * 64 + w4);
                float* dp = xs + c * 264 + r * 66 + 1 + w4;
                dp[0] = v.x; dp[1] = v.y; dp[2] = v.z; dp[3] = v.w;
            }
            if (tid < 128) {
                int cl = tid >> 2, r = tid & 3;
                xs[cl * 264 + r * 66 + 0]  = 0.f;
                xs[cl * 264 + r * 66 + 65] = 0.f;
            }
        }
        __syncthreads();

        // ---- depthwise conv 3x3 + silu -> xcs ----
        {
            float wk[9];
#pragma unroll
            for (int j = 0; j < 9; ++j) wk[j] = cw[(ch0 + cl_c) * 9 + j];
            float bias = cb[ch0 + cl_c];
            float accr[16];
#pragma unroll
            for (int k = 0; k < 16; ++k) accr[k] = bias;
#pragma unroll
            for (int dy = 0; dy < 3; ++dy) {
                const float* rp = xs + cl_c * 264 + (row_c + dy) * 66 + wb_c;
                float r[18];
#pragma unroll
                for (int q = 0; q < 18; ++q) r[q] = rp[q];
#pragma unroll
                for (int k = 0; k < 16; ++k)
#pragma unroll
                    for (int dx = 0; dx < 3; ++dx)
                        accr[k] = fmaf(r[k + dx], wk[dy * 3 + dx], accr[k]);
            }
#pragma unroll
            for (int k = 0; k < 16; ++k)
                xcs[cl_c * 130 + p0_c + k] = silu_f(accr[k]);
        }
        __syncthreads();

        // ---- store xc to global (coalesced) ----
        {
            int s = tid;
#pragma unroll
            for (int it = 0; it < 4; ++it, s += 256) {
                int c = s >> 5, pq = (s & 31) * 4;
                const float* sp = xcs + c * 130 + pq;
                *(float4*)(xc + ((size_t)b * 64 + ch0 + c) * HW + h0 * 64 + pq) =
                    make_float4(sp[0], sp[1], sp[2], sp[3]);
            }
        }
        // ---- accumulate projections over this half's channels ----
        {
            const float* wp = xpw + dir * 6 * 64 + ch0;
#pragma unroll 8
            for (int c = 0; c < 32; ++c) {
                float xv = xcs[c * 130 + px];
                acc0 = fmaf(xv, wp[0 * 64 + c], acc0);
                acc1 = fmaf(xv, wp[1 * 64 + c], acc1);
                acc2 = fmaf(xv, wp[2 * 64 + c], acc2);
                acc3 = fmaf(xv, wp[3 * 64 + c], acc3);
                acc4 = fmaf(xv, wp[4 * 64 + c], acc4);
                acc5 = fmaf(xv, wp[5 * 64 + c], acc5);
            }
        }
    }

    // ---- store projections ----
    int h = h0 + (px >> 6), w = px & 63;
    int l = (dir == 0) ? (h * 64 + w) : (w * 64 + h);
    size_t base = ((size_t)dir * NB + b) * HW + l;
    proj4[base]  = make_float4(acc0, acc1, acc2, acc3);
    projBC[base] = make_float2(acc4, acc5);
}

// ---------------------------------------------------------------------------
// Selective scan (N=1), chunk-parallel + LDS ownership transpose.
// ---------------------------------------------------------------------------
__global__ __launch_bounds__(256) void k_scan(const float* __restrict__ xc,
                                              const float4* __restrict__ proj4,
                                              const float2* __restrict__ projBC,
                                              const float* __restrict__ dt_w,
                                              const float* __restrict__ dt_b,
                                              const float* __restrict__ A_log,
                                              const float* __restrict__ Dp,
                                              float* __restrict__ y0,
                                              float* __restrict__ y1) {
    int wave = threadIdx.x >> 6;
    int lane = threadIdx.x & 63;
    int wid = blockIdx.x;
    int b = wid >> 7;
    int rem = wid & 127;
    int dir = rem >> 6;
    int d = rem & 63;
    int pd = dir * 64 + d;

    float4 wv = *(const float4*)(dt_w + pd * 4);
    float db = dt_b[pd];
    float A = -__expf(A_log[pd]);
    float Dv = Dp[pd];
    const float4* p4 = proj4 + ((size_t)dir * NB + b) * HW;
    const float2* pBC = projBC + ((size_t)dir * NB + b) * HW;
    const float* uplane = xc + ((size_t)b * 64 + d) * HW;
    float* yp = ((dir == 0) ? y0 : y1) + ((size_t)b * 64 + d) * HW;

    __shared__ float ut[64 * 65];
    __shared__ float al[4][1088];
    __shared__ float bl[4][1088];
    __shared__ float aggA[4], aggB[4];

    const float4* up4 = (const float4*)uplane;
#pragma unroll
    for (int q = 0; q < 4; ++q) {
        int s = q * 256 + threadIdx.x;
        float4 v = up4[s];
        int r = s >> 4, c0 = (s & 15) * 4;
        float* p = ut + r * 65 + c0;
        p[0] = v.x; p[1] = v.y; p[2] = v.z; p[3] = v.w;
    }
    __syncthreads();

    int ch = wave;
    float* a_my = al[wave];
    float* b_my = bl[wave];

#pragma unroll
    for (int j = 0; j < 16; ++j) {
        int el = j * 64 + lane;
        int e  = ch * 1024 + el;
        float4 t4 = p4[e];
        float2 t2 = pBC[e];
        float u = (dir == 0) ? ut[(ch * 16 + j) * 65 + lane]
                             : ut[lane * 65 + (ch * 16 + j)];
        float pre = fmaf(t4.x, wv.x, fmaf(t4.y, wv.y,
                    fmaf(t4.z, wv.z, fmaf(t4.w, wv.w, db))));
        float delta = softplus_fast(pre);
        float aj = __expf(delta * A);
        float bj = delta * t2.x * u;
        int idx = (el >> 4) * 17 + (el & 15);
        a_my[idx] = aj;
        b_my[idx] = bj;
    }
    __builtin_amdgcn_wave_barrier();

    float a[16], bb[16];
#pragma unroll
    for (int j = 0; j < 16; ++j) {
        a[j]  = a_my[lane * 17 + j];
        bb[j] = b_my[lane * 17 + j];
    }
    float As = 1.f, Bs = 0.f;
#pragma unroll
    for (int j = 0; j < 16; ++j) { Bs = fmaf(a[j], Bs, bb[j]); As *= a[j]; }
    float Ai = As, Bi = Bs;
#pragma unroll
    for (int off = 1; off < 64; off <<= 1) {
        float ap = __shfl_up(Ai, (unsigned)off, 64);
        float bp = __shfl_up(Bi, (unsigned)off, 64);
        if (lane >= off) { Bi = fmaf(Ai, bp, Bi); Ai *= ap; }
    }
    if (lane == 63) { aggA[wave] = Ai; aggB[wave] = Bi; }
    __syncthreads();
    float carry = 0.f;
    for (int k = 0; k < wave; ++k) carry = fmaf(aggA[k], carry, aggB[k]);
    float ap1 = __shfl_up(Ai, 1, 64);
    float bp1 = __shfl_up(Bi, 1, 64);
    float h = (lane == 0) ? carry : fmaf(ap1, carry, bp1);
#pragma unroll
    for (int j = 0; j < 16; ++j) {
        h = fmaf(a[j], h, bb[j]);
        a_my[lane * 17 + j] = h;
    }
    __builtin_amdgcn_wave_barrier();

    if (dir == 0) {
#pragma unroll
        for (int j = 0; j < 16; ++j) {
            int el = j * 64 + lane;
            int e  = ch * 1024 + el;
            float hv = a_my[(el >> 4) * 17 + (el & 15)];
            float cmv = pBC[e].y;
            float u = ut[(ch * 16 + j) * 65 + lane];
            yp[e] = fmaf(hv, cmv, Dv * u);
        }
    } else {
#pragma unroll
        for (int j = 0; j < 16; ++j) {
            int el = j * 64 + lane;
            int e  = ch * 1024 + el;
            float hv = a_my[(el >> 4) * 17 + (el & 15)];
            float cmv = pBC[e].y;
            int w = ch * 16 + j;
            float u = ut[lane * 65 + w];
            ut[lane * 65 + w] = fmaf(hv, cmv, Dv * u);
        }
        __syncthreads();
#pragma unroll
        for (int q = 0; q < 4; ++q) {
            int s = q * 256 + threadIdx.x;
            int r = s >> 4, c0 = (s & 15) * 4;
            const float* p = ut + r * 65 + c0;
            ((float4*)yp)[s] = make_float4(p[0], p[1], p[2], p[3]);
        }
    }
}

// ---------------------------------------------------------------------------
// Final: register-blocked. Block = (b, 2 h-rows). Thread tile 8o x 4px.
// ---------------------------------------------------------------------------
__global__ __launch_bounds__(256) void k_final(const float* __restrict__ y0,
                                               const float* __restrict__ y1,
                                               const float* __restrict__ z,
                                               const float* __restrict__ ow,
                                               const float* __restrict__ base_scale,
                                               const float* __restrict__ up,
                                               float* __restrict__ out) {
    int h0 = blockIdx.x * 2;
    int b  = blockIdx.y;
    __shared__ float yv[32 * 128];
    __shared__ float wt[32 * 64];
    int tid = threadIdx.x;

    float acc[8][4];
#pragma unroll
    for (int i = 0; i < 8; ++i)
#pragma unroll
        for (int j = 0; j < 4; ++j) acc[i][j] = 0.f;

    int o0 = (tid >> 5) * 8;
    int p0 = (tid & 31) * 4;

    for (int ko = 0; ko < 64; ko += 32) {
        if (ko) __syncthreads();
        {
            int s = tid;
#pragma unroll
            for (int it = 0; it < 4; ++it, s += 256) {
                int c = s >> 5, p4 = (s & 31) * 4;
                size_t idx = ((size_t)b * 64 + ko + c) * HW + h0 * 64 + p4;
                float4 a  = *(const float4*)(y0 + idx);
                float4 bb = *(const float4*)(y1 + idx);
                float4 zz = *(const float4*)(z + idx);
                float4 r;
                r.x = (a.x + bb.x) * silu_f(zz.x);
                r.y = (a.y + bb.y) * silu_f(zz.y);
                r.z = (a.z + bb.z) * silu_f(zz.z);
                r.w = (a.w + bb.w) * silu_f(zz.w);
                *(float4*)(yv + c * 128 + p4) = r;
            }
        }
        {
            int s = tid;
#pragma unroll
            for (int it = 0; it < 2; ++it, s += 256) {
                int o = s >> 3, c0 = (s & 7) * 4;
                float4 v = *(const float4*)(ow + o * 64 + ko + c0);
                wt[(c0 + 0) * 64 + o] = v.x;
                wt[(c0 + 1) * 64 + o] = v.y;
                wt[(c0 + 2) * 64 + o] = v.z;
                wt[(c0 + 3) * 64 + o] = v.w;
            }
        }
        __syncthreads();
#pragma unroll 4
        for (int c = 0; c < 32; ++c) {
            float wv[8], xv[4];
            *(float4*)(wv)     = *(const float4*)(wt + c * 64 + o0);
            *(float4*)(wv + 4) = *(const float4*)(wt + c * 64 + o0 + 4);
            *(float4*)(xv)     = *(const float4*)(yv + c * 128 + p0);
#pragma unroll
            for (int i = 0; i < 8; ++i)
#pragma unroll
                for (int j = 0; j < 4; ++j)
                    acc[i][j] = fmaf(wv[i], xv[j], acc[i][j]);
        }
    }

#pragma unroll
    for (int i = 0; i < 8; ++i) {
        int o = o0 + i;
        float bs = base_scale[o];
        float4 u = *(const float4*)(up + ((size_t)b * 64 + o) * HW + h0 * 64 + p0);
        float4 r = make_float4(fmaf(bs, acc[i][0], u.x),
                               fmaf(bs, acc[i][1], u.y),
                               fmaf(bs, acc[i][2], u.z),
                               fmaf(bs, acc[i][3], u.w));
        *(float4*)(out + ((size_t)b * DIM + o) * HW + h0 * 64 + p0) = r;
    }
}

// ---------------------------------------------------------------------------
extern "C" void kernel_launch(void* const* d_in, const int* in_sizes, int n_in,
                              void* d_out, int out_size, void* d_ws, size_t ws_size,
                              hipStream_t stream) {
    (void)in_sizes; (void)n_in; (void)out_size; (void)ws_size;
    const float* x = (const float*)d_in[0];
    float* out = (float*)d_out;
    float* ws = (float*)d_ws;

    const size_t IMG = (size_t)NB * 64 * HW;   // 4,194,304 floats
    float* buf_xi   = ws;                      // reused as y0 after consumption
    float* buf_z    = ws + IMG;
    float* buf_xc   = ws + 2 * IMG;
    float* buf_up   = ws + 3 * IMG;
    float* buf_y1   = ws + 4 * IMG;
    float* buf_p4   = ws + 5 * IMG;            // float4[2*16*4096]
    float* buf_pBC  = buf_p4 + (size_t)4 * 2 * NB * HW;
    float* buf_mean = buf_pBC + (size_t)2 * 2 * NB * HW;
    float* buf_w3   = buf_mean + 1024;
    float* buf_w5   = buf_w3 + 16 * 64 * 9;
    float* buf_w7   = buf_w5 + 16 * 64 * 25;

    // ---- local branch ----
    k_mean<<<1024, 256, 0, stream>>>(x, buf_mean);
    k_weff_all<<<16, 64, 0, stream>>>(buf_mean,
        (const float*)d_in[1],  (const float*)d_in[2],  (const float*)d_in[3],
        (const float*)d_in[8],  (const float*)d_in[9],  (const float*)d_in[10],
        (const float*)d_in[15], (const float*)d_in[16], (const float*)d_in[17],
        buf_w3, buf_w5, buf_w7);
    k_local<<<dim3(4, 64, 16), 256, 0, stream>>>(x, buf_w3, buf_w5, buf_w7,
        (const float*)d_in[4],  (const float*)d_in[5],  (const float*)d_in[6],  (const float*)d_in[7],
        (const float*)d_in[11], (const float*)d_in[12], (const float*)d_in[13], (const float*)d_in[14],
        (const float*)d_in[18], (const float*)d_in[19], (const float*)d_in[20], (const float*)d_in[21],
        out);

    // ---- wavelet branch ----
    k_up<<<dim3(64, 16), 256, 0, stream>>>(x, (const float*)d_in[22],
        (const float*)d_in[23], (const float*)d_in[24], buf_up);

    // ---- ss2d ----
    k_inproj<<<dim3(32, 16), 256, 0, stream>>>(x, (const float*)d_in[26], buf_xi, buf_z);
    k_convproj<<<dim3(32, 16), 256, 0, stream>>>(buf_xi, (const float*)d_in[27],
        (const float*)d_in[28], (const float*)d_in[29],
        buf_xc, (float4*)buf_p4, (float2*)buf_pBC);
    k_scan<<<2048, 256, 0, stream>>>(buf_xc, (const float4*)buf_p4, (const float2*)buf_pBC,
        (const float*)d_in[30], (const float*)d_in[31],
        (const float*)d_in[32], (const float*)d_in[33],
        buf_xi /* y0 (xi is dead now) */, buf_y1);
    k_final<<<dim3(32, 16), 256, 0, stream>>>(buf_xi, buf_y1, buf_z,
        (const float*)d_in[34], (const float*)d_in[25], buf_up, out);
}

// Round 9
// 138.489 us; speedup vs baseline: 1.6975x; 1.0620x over previous
//
#include <hip/hip_runtime.h>
#include <math.h>

// Problem constants
static constexpr int NB   = 16;    // batch
static constexpr int DIM  = 256;   // total channels
static constexpr int CG   = 64;    // global-branch channels
static constexpr int HH   = 64;
static constexpr int WW   = 64;
static constexpr int HW   = HH * WW;   // 4096

// mish(x) = x*tanh(softplus(x)) = x*(t^2+2t)/(t^2+2t+2), t=e^x.
__device__ __forceinline__ float mish_fast(float x) {
    float t = __expf(fminf(x, 20.f));
    float p = __builtin_fmaf(t, t, t + t);         // t^2 + 2t
    return x * p * __builtin_amdgcn_rcpf(p + 2.f);
}
__device__ __forceinline__ float silu_f(float x) {
    return x * __builtin_amdgcn_rcpf(1.f + __expf(-x));
}
// softplus via hw exp/log: max(x,0) + log(1 + e^-|x|). Error vs log1pf < 2 ulp.
__device__ __forceinline__ float softplus_fast(float x) {
    return fmaxf(x, 0.f) + __logf(1.f + __expf(-fabsf(x)));
}

// ---------------------------------------------------------------------------
// All three expert-mixes in one launch. Block per b, 64 threads.
// ---------------------------------------------------------------------------
__global__ void k_weff_all(const float* __restrict__ mean,
                           const float* __restrict__ ew3, const float* __restrict__ gw3,
                           const float* __restrict__ g13,
                           const float* __restrict__ ew5, const float* __restrict__ gw5,
                           const float* __restrict__ g15,
                           const float* __restrict__ ew7, const float* __restrict__ gw7,
                           const float* __restrict__ g17,
                           float* __restrict__ w3o, float* __restrict__ w5o,
                           float* __restrict__ w7o) {
    int b = blockIdx.x;
    int c = threadIdx.x;                 // 64 threads
    __shared__ float m[64];
    __shared__ float g[4];
    m[c] = mean[b * 64 + c];
    __syncthreads();
    const float rs = rsqrtf(1.f + 1e-5f);

#define WEFF_SECT(GW, EW, G1, OUT, K2)                                        \
    {                                                                         \
        if (c < 4) {                                                          \
            float l = 0.f;                                                    \
            for (int cc = 0; cc < 64; ++cc) l += m[cc] * GW[c * 64 + cc];     \
            g[c] = l;                                                         \
        }                                                                     \
        __syncthreads();                                                      \
        if (c == 0) {                                                         \
            float mx = fmaxf(fmaxf(g[0], g[1]), fmaxf(g[2], g[3]));           \
            float e0 = expf(g[0] - mx), e1 = expf(g[1] - mx);                 \
            float e2 = expf(g[2] - mx), e3 = expf(g[3] - mx);                 \
            float inv = 1.f / (e0 + e1 + e2 + e3);                            \
            g[0] = e0 * inv; g[1] = e1 * inv; g[2] = e2 * inv; g[3] = e3 * inv;\
        }                                                                     \
        __syncthreads();                                                      \
        float g1s = G1[c] * rs;                                               \
        for (int kk = 0; kk < K2; ++kk) {                                     \
            float w = 0.f;                                                    \
            for (int e = 0; e < 4; ++e) w += g[e] * EW[(e * 64 + c) * K2 + kk];\
            OUT[(b * 64 + c) * K2 + kk] = w * g1s;                            \
        }                                                                     \
        __syncthreads();                                                      \
    }

    WEFF_SECT(gw3, ew3, g13, w3o, 9)
    WEFF_SECT(gw5, ew5, g15, w5o, 25)
    WEFF_SECT(gw7, ew7, g17, w7o, 49)
#undef WEFF_SECT
}

// ---------------------------------------------------------------------------
// Local branch conv: register-blocked, 4-wide strips, b128 row loads.
// Fused: each block also copies 512 float4 of the x[:,128:256] passthrough.
// ---------------------------------------------------------------------------
__global__ __launch_bounds__(256) void k_local(
    const float* __restrict__ x,
    const float* __restrict__ w3, const float* __restrict__ w5, const float* __restrict__ w7,
    const float* __restrict__ b1_0, const float* __restrict__ pw0,
    const float* __restrict__ g2_0, const float* __restrict__ b2_0,
    const float* __restrict__ b1_1, const float* __restrict__ pw1,
    const float* __restrict__ g2_1, const float* __restrict__ b2_1,
    const float* __restrict__ b1_2, const float* __restrict__ pw2,
    const float* __restrict__ g2_2, const float* __restrict__ b2_2,
    float* __restrict__ out) {
    int tile = blockIdx.x;
    int c = blockIdx.y, b = blockIdx.z;
    int oy = (tile >> 1) * 32, ox = (tile & 1) * 32;
    __shared__ float t[38 * 40];
    const float* xp = x + ((size_t)b * DIM + 64 + c) * HW;
    for (int i = threadIdx.x; i < 38 * 38; i += 256) {
        int r = i / 38, cc = i % 38;
        int yy = r - 3 + oy, xx = cc - 3 + ox;
        t[r * 40 + cc] = (yy >= 0 && yy < 64 && xx >= 0 && xx < 64) ? xp[yy * 64 + xx] : 0.f;
    }
    // fused passthrough copy (independent of LDS/barrier)
    {
        int bl = tile + 4 * c + 256 * b;             // 0..4095
        const float4* x4 = (const float4*)x;
        float4* o4 = (float4*)out;
        int base = bl * 512;
#pragma unroll
        for (int it = 0; it < 2; ++it) {
            int idx = base + it * 256 + threadIdx.x;
            int bb = idx >> 17;
            int r  = idx & 131071;
            int gi = bb * 262144 + 131072 + r;
            o4[gi] = x4[gi];
        }
    }
    const float* w3p = w3 + (b * 64 + c) * 9;
    const float* w5p = w5 + (b * 64 + c) * 25;
    const float* w7p = w7 + (b * 64 + c) * 49;
    float W3r[9], W5r[25], W7r[49];
#pragma unroll
    for (int j = 0; j < 9; ++j)  W3r[j] = w3p[j];
#pragma unroll
    for (int j = 0; j < 25; ++j) W5r[j] = w5p[j];
#pragma unroll
    for (int j = 0; j < 49; ++j) W7r[j] = w7p[j];
    __syncthreads();

    const float rs = rsqrtf(1.f + 1e-5f);
    float bb1a = b1_0[c], bb1b = b1_1[c], bb1c = b1_2[c];
    float ssa = pw0[c] * g2_0[c] * rs, ssb = pw1[c] * g2_1[c] * rs, ssc = pw2[c] * g2_2[c] * rs;
    float bb2a = b2_0[c], bb2b = b2_1[c], bb2c = b2_2[c];

    int y  = threadIdx.x >> 3;
    int x0 = (threadIdx.x & 7) * 4;

    float a3[4] = {0.f, 0.f, 0.f, 0.f};
    float a5[4] = {0.f, 0.f, 0.f, 0.f};
    float a7[4] = {0.f, 0.f, 0.f, 0.f};

#pragma unroll
    for (int dy = 0; dy < 7; ++dy) {
        const float4* rp = (const float4*)(t + (y + dy) * 40 + x0);
        float4 q0 = rp[0], q1 = rp[1], q2 = rp[2];
        float r[12] = {q0.x, q0.y, q0.z, q0.w, q1.x, q1.y, q1.z, q1.w,
                       q2.x, q2.y, q2.z, q2.w};
#pragma unroll
        for (int k = 0; k < 4; ++k)
#pragma unroll
            for (int dx = 0; dx < 7; ++dx)
                a7[k] = fmaf(r[k + dx], W7r[dy * 7 + dx], a7[k]);
        if (dy >= 1 && dy <= 5) {
            int ey = dy - 1;
#pragma unroll
            for (int k = 0; k < 4; ++k)
#pragma unroll
                for (int dx = 0; dx < 5; ++dx)
                    a5[k] = fmaf(r[k + 1 + dx], W5r[ey * 5 + dx], a5[k]);
        }
        if (dy >= 2 && dy <= 4) {
            int ey = dy - 2;
#pragma unroll
            for (int k = 0; k < 4; ++k)
#pragma unroll
                for (int dx = 0; dx < 3; ++dx)
                    a3[k] = fmaf(r[k + 2 + dx], W3r[ey * 3 + dx], a3[k]);
        }
    }

    float4 res;
    float* rr = (float*)&res;
#pragma unroll
    for (int k = 0; k < 4; ++k) {
        rr[k] = mish_fast(a3[k] + bb1a) * ssa + bb2a
              + mish_fast(a5[k] + bb1b) * ssb + bb2b
              + mish_fast(a7[k] + bb1c) * ssc + bb2c;
    }
    float* op = out + ((size_t)b * DIM + 64 + c) * HW;
    *(float4*)(op + (oy + y) * 64 + ox + x0) = res;
}

// ---------------------------------------------------------------------------
// Fused wavelet (Haar dec -> dw3x3 conv -> Haar rec) + channel mean of the
// corresponding local-branch plane (b, 64+c). One block per (b,c).
// Mean sum order identical to the old k_mean (stride-256 partials + tree).
// ---------------------------------------------------------------------------
__global__ __launch_bounds__(256) void k_up(const float* __restrict__ x,
                                            const float* __restrict__ wav_w,
                                            const float* __restrict__ wav_b,
                                            const float* __restrict__ wav_scale,
                                            float* __restrict__ up,
                                            float* __restrict__ mean) {
    int c = blockIdx.x, b = blockIdx.y;
    __shared__ float xs[64 * 65];
    __shared__ float wt[4][32 * 33];
    __shared__ float red[256];
    const float* xp = x + ((size_t)b * DIM + c) * HW;
    for (int i = threadIdx.x; i < HW; i += 256) xs[(i >> 6) * 65 + (i & 63)] = xp[i];
    // mean of plane (b, 64+c)
    {
        const float* lp = x + ((size_t)b * DIM + 64 + c) * HW;
        float s = 0.f;
        for (int i = threadIdx.x; i < HW; i += 256) s += lp[i];
        red[threadIdx.x] = s;
        __syncthreads();                 // also orders xs for the wt stage
        for (int o = 128; o > 0; o >>= 1) {
            if (threadIdx.x < o) red[threadIdx.x] += red[threadIdx.x + o];
            __syncthreads();
        }
        if (threadIdx.x == 0) mean[b * 64 + c] = red[0] * (1.f / HW);
    }
    for (int i = threadIdx.x; i < 1024; i += 256) {
        int h = i >> 5, w = i & 31;
        float a  = xs[(2 * h) * 65 + 2 * w],     bb = xs[(2 * h) * 65 + 2 * w + 1];
        float cc = xs[(2 * h + 1) * 65 + 2 * w], dd = xs[(2 * h + 1) * 65 + 2 * w + 1];
        wt[0][h * 33 + w] = 0.5f * (a + bb + cc + dd);
        wt[1][h * 33 + w] = 0.5f * (a + bb - cc - dd);
        wt[2][h * 33 + w] = 0.5f * (a - bb + cc - dd);
        wt[3][h * 33 + w] = 0.5f * (a - bb - cc + dd);
    }
    __syncthreads();
    float wk[4][9], tb[4];
#pragma unroll
    for (int k = 0; k < 4; ++k) {
        int ch = c * 4 + k;
        float sc = wav_scale[ch];
#pragma unroll
        for (int j = 0; j < 9; ++j) wk[k][j] = wav_w[ch * 9 + j] * sc;
        tb[k] = wav_b[ch] * sc;
    }
    float* upp = up + ((size_t)b * CG + c) * HW;
    for (int i = threadIdx.x; i < 1024; i += 256) {
        int h = i >> 5, w = i & 31;
        float tg[4];
#pragma unroll
        for (int k = 0; k < 4; ++k) {
            float s = tb[k];
#pragma unroll
            for (int dy = -1; dy <= 1; ++dy) {
                int hh = h + dy;
                if (hh < 0 || hh >= 32) continue;
#pragma unroll
                for (int dx = -1; dx <= 1; ++dx) {
                    int wx = w + dx;
                    if (wx < 0 || wx >= 32) continue;
                    s = fmaf(wt[k][hh * 33 + wx], wk[k][(dy + 1) * 3 + (dx + 1)], s);
                }
            }
            tg[k] = s;
        }
        float u00 = 0.5f * (tg[0] - tg[1] - tg[2] + tg[3]);
        float u01 = 0.5f * (tg[0] - tg[1] + tg[2] - tg[3]);
        float u10 = 0.5f * (tg[0] + tg[1] - tg[2] - tg[3]);
        float u11 = 0.5f * (tg[0] + tg[1] + tg[2] + tg[3]);
        upp[(2 * h) * 64 + 2 * w]         = u00;
        upp[(2 * h) * 64 + 2 * w + 1]     = u01;
        upp[(2 * h + 1) * 64 + 2 * w]     = u10;
        upp[(2 * h + 1) * 64 + 2 * w + 1] = u11;
    }
}

// ---------------------------------------------------------------------------
// SS2D input projection: register-blocked GEMM. Block = (b, 2 h-rows).
// ---------------------------------------------------------------------------
__global__ __launch_bounds__(256) void k_inproj(const float* __restrict__ x,
                                                const float* __restrict__ in_w,
                                                float* __restrict__ xi,
                                                float* __restrict__ z) {
    int h0 = blockIdx.x * 2;
    int b  = blockIdx.y;
    __shared__ float xs[32 * 128];
    __shared__ float wt[32 * 128];
    int tid = threadIdx.x;

    float acc[8][8];
#pragma unroll
    for (int i = 0; i < 8; ++i)
#pragma unroll
        for (int j = 0; j < 8; ++j) acc[i][j] = 0.f;

    int o0 = (tid >> 4) * 8;
    int p0 = (tid & 15) * 8;

    for (int ko = 0; ko < 64; ko += 32) {
        if (ko) __syncthreads();
        {
            int s = tid;
#pragma unroll
            for (int it = 0; it < 4; ++it, s += 256) {
                int c = s >> 5, p4 = (s & 31) * 4;
                float4 v = *(const float4*)(x + ((size_t)b * DIM + ko + c) * HW + h0 * 64 + p4);
                *(float4*)(xs + c * 128 + p4) = v;
            }
        }
        {
            int s = tid;
#pragma unroll
            for (int it = 0; it < 4; ++it, s += 256) {
                int o = s >> 3, c0 = (s & 7) * 4;
                float4 v = *(const float4*)(in_w + o * 64 + ko + c0);
                wt[(c0 + 0) * 128 + o] = v.x;
                wt[(c0 + 1) * 128 + o] = v.y;
                wt[(c0 + 2) * 128 + o] = v.z;
                wt[(c0 + 3) * 128 + o] = v.w;
            }
        }
        __syncthreads();
#pragma unroll 4
        for (int c = 0; c < 32; ++c) {
            float xv[8], wv[8];
            *(float4*)(xv)     = *(const float4*)(xs + c * 128 + p0);
            *(float4*)(xv + 4) = *(const float4*)(xs + c * 128 + p0 + 4);
            *(float4*)(wv)     = *(const float4*)(wt + c * 128 + o0);
            *(float4*)(wv + 4) = *(const float4*)(wt + c * 128 + o0 + 4);
#pragma unroll
            for (int i = 0; i < 8; ++i)
#pragma unroll
                for (int j = 0; j < 8; ++j)
                    acc[i][j] = fmaf(wv[i], xv[j], acc[i][j]);
        }
    }

#pragma unroll
    for (int i = 0; i < 8; ++i) {
        int o = o0 + i;
        float* dst = (o < 64) ? (xi + ((size_t)b * 64 + o) * HW + h0 * 64)
                              : (z + ((size_t)b * 64 + (o - 64)) * HW + h0 * 64);
        *(float4*)(dst + p0)     = make_float4(acc[i][0], acc[i][1], acc[i][2], acc[i][3]);
        *(float4*)(dst + p0 + 4) = make_float4(acc[i][4], acc[i][5], acc[i][6], acc[i][7]);
    }
}

// ---------------------------------------------------------------------------
// Fused dwconv3x3+silu -> xc, and 6-way projections (both dirs) -> proj.
// Block = (b, 2 h-rows).
// ---------------------------------------------------------------------------
__global__ __launch_bounds__(256) void k_convproj(const float* __restrict__ xi,
                                                  const float* __restrict__ cw,
                                                  const float* __restrict__ cb,
                                                  const float* __restrict__ xpw,
                                                  float* __restrict__ xc,
                                                  float4* __restrict__ proj4,
                                                  float2* __restrict__ projBC) {
    int h0 = blockIdx.x * 2;
    int b  = blockIdx.y;
    int tid = threadIdx.x;

    __shared__ float xs[32 * 264];       // [cl][r 0..3][66], data at w+1
    __shared__ float xcs[32 * 130];      // [cl][px 0..127]

    int dir = tid >> 7;
    int px  = tid & 127;
    float acc0 = 0.f, acc1 = 0.f, acc2 = 0.f, acc3 = 0.f, acc4 = 0.f, acc5 = 0.f;

    int cl_c = tid >> 3;
    int p0_c = (tid & 7) * 16;
    int row_c = p0_c >> 6;
    int wb_c  = p0_c & 63;

    for (int ch0 = 0; ch0 < 64; ch0 += 32) {
        if (ch0) __syncthreads();
        {
            int s = tid;
#pragma unroll
            for (int it = 0; it < 8; ++it, s += 256) {
                int c = s >> 6;
                int rem = s & 63;
                int r = rem >> 4, w4 = (rem & 15) * 4;
                int gh = h0 - 1 + r;
                float4 v = make_float4(0.f, 0.f, 0.f, 0.f);
                if (gh >= 0 && gh < 64)
                    v = *(const float4*)(xi + ((size_t)b * 64 + ch0 + c) * HW + gh * 64 + w4);
                float* dp = xs + c * 264 + r * 66 + 1 + w4;
                dp[0] = v.x; dp[1] = v.y; dp[2] = v.z; dp[3] = v.w;
            }
            if (tid < 128) {
                int cl = tid >> 2, r = tid & 3;
                xs[cl * 264 + r * 66 + 0]  = 0.f;
                xs[cl * 264 + r * 66 + 65] = 0.f;
            }
        }
        __syncthreads();

        {
            float wk[9];
#pragma unroll
            for (int j = 0; j < 9; ++j) wk[j] = cw[(ch0 + cl_c) * 9 + j];
            float bias = cb[ch0 + cl_c];
            float accr[16];
#pragma unroll
            for (int k = 0; k < 16; ++k) accr[k] = bias;
#pragma unroll
            for (int dy = 0; dy < 3; ++dy) {
                const float* rp = xs + cl_c * 264 + (row_c + dy) * 66 + wb_c;
                float r[18];
#pragma unroll
                for (int q = 0; q < 18; ++q) r[q] = rp[q];
#pragma unroll
                for (int k = 0; k < 16; ++k)
#pragma unroll
                    for (int dx = 0; dx < 3; ++dx)
                        accr[k] = fmaf(r[k + dx], wk[dy * 3 + dx], accr[k]);
            }
#pragma unroll
            for (int k = 0; k < 16; ++k)
                xcs[cl_c * 130 + p0_c + k] = silu_f(accr[k]);
        }
        __syncthreads();

        {
            int s = tid;
#pragma unroll
            for (int it = 0; it < 4; ++it, s += 256) {
                int c = s >> 5, pq = (s & 31) * 4;
                const float* sp = xcs + c * 130 + pq;
                *(float4*)(xc + ((size_t)b * 64 + ch0 + c) * HW + h0 * 64 + pq) =
                    make_float4(sp[0], sp[1], sp[2], sp[3]);
            }
        }
        {
            const float* wp = xpw + dir * 6 * 64 + ch0;
#pragma unroll 8
            for (int c = 0; c < 32; ++c) {
                float xv = xcs[c * 130 + px];
                acc0 = fmaf(xv, wp[0 * 64 + c], acc0);
                acc1 = fmaf(xv, wp[1 * 64 + c], acc1);
                acc2 = fmaf(xv, wp[2 * 64 + c], acc2);
                acc3 = fmaf(xv, wp[3 * 64 + c], acc3);
                acc4 = fmaf(xv, wp[4 * 64 + c], acc4);
                acc5 = fmaf(xv, wp[5 * 64 + c], acc5);
            }
        }
    }

    int h = h0 + (px >> 6), w = px & 63;
    int l = (dir == 0) ? (h * 64 + w) : (w * 64 + h);
    size_t base = ((size_t)dir * NB + b) * HW + l;
    proj4[base]  = make_float4(acc0, acc1, acc2, acc3);
    projBC[base] = make_float2(acc4, acc5);
}

// ---------------------------------------------------------------------------
// Selective scan v3: BOTH directions per block. Block per (b,d) plane,
// wave = chunk of 1024. dir0's y stays in registers; dir1's y goes into the
// shared u-plane tile (in place); output yz = (y0+y1)*silu(z) directly.
// Carry-chain and per-element math identical to v2 (bit-exact).
// ---------------------------------------------------------------------------
__global__ __launch_bounds__(256) void k_scan2(const float* __restrict__ xc,
                                               const float4* __restrict__ proj4,
                                               const float2* __restrict__ projBC,
                                               const float* __restrict__ dt_w,
                                               const float* __restrict__ dt_b,
                                               const float* __restrict__ A_log,
                                               const float* __restrict__ Dp,
                                               const float* __restrict__ z,
                                               float* __restrict__ yz) {
    int wave = threadIdx.x >> 6;
    int lane = threadIdx.x & 63;
    int wid = blockIdx.x;                // b*64 + d
    int b = wid >> 6;
    int d = wid & 63;

    __shared__ float ut[64 * 65];        // u plane; dir1 y overwrites in place
    __shared__ float al[4][1088];        // per-wave (a)/(h), padded seg*17+pos
    __shared__ float bl[4][1088];        // per-wave (b)
    __shared__ float aggA[4], aggB[4];

    const float* uplane = xc + ((size_t)b * 64 + d) * HW;
    const float4* up4 = (const float4*)uplane;
#pragma unroll
    for (int q = 0; q < 4; ++q) {
        int s = q * 256 + threadIdx.x;
        float4 v = up4[s];
        int r = s >> 4, c0 = (s & 15) * 4;
        float* p = ut + r * 65 + c0;
        p[0] = v.x; p[1] = v.y; p[2] = v.z; p[3] = v.w;
    }
    __syncthreads();

    int ch = wave;
    float* a_my = al[wave];
    float* b_my = bl[wave];
    float y0r[16];

    // ================= DIR 0 =================
    {
        float4 wv = *(const float4*)(dt_w + d * 4);
        float db = dt_b[d];
        float A = -__expf(A_log[d]);
        float Dv = Dp[d];
        const float4* p4 = proj4 + (size_t)b * HW;
        const float2* pBC = projBC + (size_t)b * HW;

        float uv[16], cm[16];
#pragma unroll
        for (int j = 0; j < 16; ++j) {
            int el = j * 64 + lane;
            int e  = ch * 1024 + el;
            float4 t4 = p4[e];
            float2 t2 = pBC[e];
            float u = ut[(ch * 16 + j) * 65 + lane];
            uv[j] = u; cm[j] = t2.y;
            float pre = fmaf(t4.x, wv.x, fmaf(t4.y, wv.y,
                        fmaf(t4.z, wv.z, fmaf(t4.w, wv.w, db))));
            float delta = softplus_fast(pre);
            float aj = __expf(delta * A);
            float bj = delta * t2.x * u;
            int idx = (el >> 4) * 17 + (el & 15);
            a_my[idx] = aj;
            b_my[idx] = bj;
        }
        __builtin_amdgcn_wave_barrier();

        float a[16], bb[16];
#pragma unroll
        for (int j = 0; j < 16; ++j) {
            a[j]  = a_my[lane * 17 + j];
            bb[j] = b_my[lane * 17 + j];
        }
        float As = 1.f, Bs = 0.f;
#pragma unroll
        for (int j = 0; j < 16; ++j) { Bs = fmaf(a[j], Bs, bb[j]); As *= a[j]; }
        float Ai = As, Bi = Bs;
#pragma unroll
        for (int off = 1; off < 64; off <<= 1) {
            float ap = __shfl_up(Ai, (unsigned)off, 64);
            float bp = __shfl_up(Bi, (unsigned)off, 64);
            if (lane >= off) { Bi = fmaf(Ai, bp, Bi); Ai *= ap; }
        }
        if (lane == 63) { aggA[wave] = Ai; aggB[wave] = Bi; }
        __syncthreads();
        float carry = 0.f;
        for (int k = 0; k < wave; ++k) carry = fmaf(aggA[k], carry, aggB[k]);
        float ap1 = __shfl_up(Ai, 1, 64);
        float bp1 = __shfl_up(Bi, 1, 64);
        float h = (lane == 0) ? carry : fmaf(ap1, carry, bp1);
#pragma unroll
        for (int j = 0; j < 16; ++j) {
            h = fmaf(a[j], h, bb[j]);
            a_my[lane * 17 + j] = h;
        }
        __builtin_amdgcn_wave_barrier();
#pragma unroll
        for (int j = 0; j < 16; ++j) {
            int el = j * 64 + lane;
            float hv = a_my[(el >> 4) * 17 + (el & 15)];
            y0r[j] = fmaf(hv, cm[j], Dv * uv[j]);
        }
    }
    __syncthreads();                     // fence agg + al/bl reuse across dirs

    // ================= DIR 1 =================
    {
        int pd = 64 + d;
        float4 wv = *(const float4*)(dt_w + pd * 4);
        float db = dt_b[pd];
        float A = -__expf(A_log[pd]);
        float Dv = Dp[pd];
        const float4* p4 = proj4 + ((size_t)NB + b) * HW;
        const float2* pBC = projBC + ((size_t)NB + b) * HW;

        float uv[16], cm[16];
#pragma unroll
        for (int j = 0; j < 16; ++j) {
            int el = j * 64 + lane;
            int e  = ch * 1024 + el;
            float4 t4 = p4[e];
            float2 t2 = pBC[e];
            float u = ut[lane * 65 + (ch * 16 + j)];
            uv[j] = u; cm[j] = t2.y;
            float pre = fmaf(t4.x, wv.x, fmaf(t4.y, wv.y,
                        fmaf(t4.z, wv.z, fmaf(t4.w, wv.w, db))));
            float delta = softplus_fast(pre);
            float aj = __expf(delta * A);
            float bj = delta * t2.x * u;
            int idx = (el >> 4) * 17 + (el & 15);
            a_my[idx] = aj;
            b_my[idx] = bj;
        }
        __builtin_amdgcn_wave_barrier();

        float a[16], bb[16];
#pragma unroll
        for (int j = 0; j < 16; ++j) {
            a[j]  = a_my[lane * 17 + j];
            bb[j] = b_my[lane * 17 + j];
        }
        float As = 1.f, Bs = 0.f;
#pragma unroll
        for (int j = 0; j < 16; ++j) { Bs = fmaf(a[j], Bs, bb[j]); As *= a[j]; }
        float Ai = As, Bi = Bs;
#pragma unroll
        for (int off = 1; off < 64; off <<= 1) {
            float ap = __shfl_up(Ai, (unsigned)off, 64);
            float bp = __shfl_up(Bi, (unsigned)off, 64);
            if (lane >= off) { Bi = fmaf(Ai, bp, Bi); Ai *= ap; }
        }
        if (lane == 63) { aggA[wave] = Ai; aggB[wave] = Bi; }
        __syncthreads();
        float carry = 0.f;
        for (int k = 0; k < wave; ++k) carry = fmaf(aggA[k], carry, aggB[k]);
        float ap1 = __shfl_up(Ai, 1, 64);
        float bp1 = __shfl_up(Bi, 1, 64);
        float h = (lane == 0) ? carry : fmaf(ap1, carry, bp1);
#pragma unroll
        for (int j = 0; j < 16; ++j) {
            h = fmaf(a[j], h, bb[j]);
            a_my[lane * 17 + j] = h;
        }
        __builtin_amdgcn_wave_barrier();
        // y1 into ut in place (spatial h=lane, w=ch*16+j)
#pragma unroll
        for (int j = 0; j < 16; ++j) {
            int el = j * 64 + lane;
            float hv = a_my[(el >> 4) * 17 + (el & 15)];
            ut[lane * 65 + (ch * 16 + j)] = fmaf(hv, cm[j], Dv * uv[j]);
        }
    }
    __syncthreads();

    // ---- combine: yz = (y0 + y1) * silu(z), coalesced ----
    const float* zp = z + ((size_t)b * 64 + d) * HW;
    float* yp = yz + ((size_t)b * 64 + d) * HW;
#pragma unroll
    for (int j = 0; j < 16; ++j) {
        int e = ch * 1024 + j * 64 + lane;
        float y1v = ut[(ch * 16 + j) * 65 + lane];
        float zz = zp[e];
        yp[e] = (y0r[j] + y1v) * silu_f(zz);
    }
}

// ---------------------------------------------------------------------------
// Final: register-blocked GEMM over pre-gated yz. Block = (b, 2 h-rows).
// ---------------------------------------------------------------------------
__global__ __launch_bounds__(256) void k_final(const float* __restrict__ yz,
                                               const float* __restrict__ ow,
                                               const float* __restrict__ base_scale,
                                               const float* __restrict__ up,
                                               float* __restrict__ out) {
    int h0 = blockIdx.x * 2;
    int b  = blockIdx.y;
    __shared__ float yv[32 * 128];
    __shared__ float wt[32 * 64];
    int tid = threadIdx.x;

    float acc[8][4];
#pragma unroll
    for (int i = 0; i < 8; ++i)
#pragma unroll
        for (int j = 0; j < 4; ++j) acc[i][j] = 0.f;

    int o0 = (tid >> 5) * 8;
    int p0 = (tid & 31) * 4;

    for (int ko = 0; ko < 64; ko += 32) {
        if (ko) __syncthreads();
        {
            int s = tid;
#pragma unroll
            for (int it = 0; it < 4; ++it, s += 256) {
                int c = s >> 5, p4 = (s & 31) * 4;
                size_t idx = ((size_t)b * 64 + ko + c) * HW + h0 * 64 + p4;
                *(float4*)(yv + c * 128 + p4) = *(const float4*)(yz + idx);
            }
        }
        {
            int s = tid;
#pragma unroll
            for (int it = 0; it < 2; ++it, s += 256) {
                int o = s >> 3, c0 = (s & 7) * 4;
                float4 v = *(const float4*)(ow + o * 64 + ko + c0);
                wt[(c0 + 0) * 64 + o] = v.x;
                wt[(c0 + 1) * 64 + o] = v.y;
                wt[(c0 + 2) * 64 + o] = v.z;
                wt[(c0 + 3) * 64 + o] = v.w;
            }
        }
        __syncthreads();
#pragma unroll 4
        for (int c = 0; c < 32; ++c) {
            float wv[8], xv[4];
            *(float4*)(wv)     = *(const float4*)(wt + c * 64 + o0);
            *(float4*)(wv + 4) = *(const float4*)(wt + c * 64 + o0 + 4);
            *(float4*)(xv)     = *(const float4*)(yv + c * 128 + p0);
#pragma unroll
            for (int i = 0; i < 8; ++i)
#pragma unroll
                for (int j = 0; j < 4; ++j)
                    acc[i][j] = fmaf(wv[i], xv[j], acc[i][j]);
        }
    }

#pragma unroll
    for (int i = 0; i < 8; ++i) {
        int o = o0 + i;
        float bs = base_scale[o];
        float4 u = *(const float4*)(up + ((size_t)b * 64 + o) * HW + h0 * 64 + p0);
        float4 r = make_float4(fmaf(bs, acc[i][0], u.x),
                               fmaf(bs, acc[i][1], u.y),
                               fmaf(bs, acc[i][2], u.z),
                               fmaf(bs, acc[i][3], u.w));
        *(float4*)(out + ((size_t)b * DIM + o) * HW + h0 * 64 + p0) = r;
    }
}

// ---------------------------------------------------------------------------
extern "C" void kernel_launch(void* const* d_in, const int* in_sizes, int n_in,
                              void* d_out, int out_size, void* d_ws, size_t ws_size,
                              hipStream_t stream) {
    (void)in_sizes; (void)n_in; (void)out_size; (void)ws_size;
    const float* x = (const float*)d_in[0];
    float* out = (float*)d_out;
    float* ws = (float*)d_ws;

    const size_t IMG = (size_t)NB * 64 * HW;   // 4,194,304 floats
    float* buf_xi   = ws;                      // xi, later reused as yz
    float* buf_z    = ws + IMG;
    float* buf_xc   = ws + 2 * IMG;
    float* buf_up   = ws + 3 * IMG;
    float* buf_p4   = ws + 4 * IMG;            // float4[2*16*4096]
    float* buf_pBC  = buf_p4 + (size_t)4 * 2 * NB * HW;
    float* buf_mean = buf_pBC + (size_t)2 * 2 * NB * HW;
    float* buf_w3   = buf_mean + 1024;
    float* buf_w5   = buf_w3 + 16 * 64 * 9;
    float* buf_w7   = buf_w5 + 16 * 64 * 25;

    // ---- wavelet branch + channel means (fused) ----
    k_up<<<dim3(64, 16), 256, 0, stream>>>(x, (const float*)d_in[22],
        (const float*)d_in[23], (const float*)d_in[24], buf_up, buf_mean);

    // ---- local branch ----
    k_weff_all<<<16, 64, 0, stream>>>(buf_mean,
        (const float*)d_in[1],  (const float*)d_in[2],  (const float*)d_in[3],
        (const float*)d_in[8],  (const float*)d_in[9],  (const float*)d_in[10],
        (const float*)d_in[15], (const float*)d_in[16], (const float*)d_in[17],
        buf_w3, buf_w5, buf_w7);
    k_local<<<dim3(4, 64, 16), 256, 0, stream>>>(x, buf_w3, buf_w5, buf_w7,
        (const float*)d_in[4],  (const float*)d_in[5],  (const float*)d_in[6],  (const float*)d_in[7],
        (const float*)d_in[11], (const float*)d_in[12], (const float*)d_in[13], (const float*)d_in[14],
        (const float*)d_in[18], (const float*)d_in[19], (const float*)d_in[20], (const float*)d_in[21],
        out);

    // ---- ss2d ----
    k_inproj<<<dim3(32, 16), 256, 0, stream>>>(x, (const float*)d_in[26], buf_xi, buf_z);
    k_convproj<<<dim3(32, 16), 256, 0, stream>>>(buf_xi, (const float*)d_in[27],
        (const float*)d_in[28], (const float*)d_in[29],
        buf_xc, (float4*)buf_p4, (float2*)buf_pBC);
    k_scan2<<<1024, 256, 0, stream>>>(buf_xc, (const float4*)buf_p4, (const float2*)buf_pBC,
        (const float*)d_in[30], (const float*)d_in[31],
        (const float*)d_in[32], (const float*)d_in[33],
        buf_z, buf_xi /* yz (xi is dead now) */);
    k_final<<<dim3(32, 16), 256, 0, stream>>>(buf_xi,
        (const float*)d_in[34], (const float*)d_in[25], buf_up, out);
}

// Round 10
// 126.411 us; speedup vs baseline: 1.8597x; 1.0955x over previous
//
#include <hip/hip_runtime.h>
#include <math.h>

// Problem constants
static constexpr int NB   = 16;    // batch
static constexpr int DIM  = 256;   // total channels
static constexpr int CG   = 64;    // global-branch channels
static constexpr int HH   = 64;
static constexpr int WW   = 64;
static constexpr int HW   = HH * WW;   // 4096

// mish(x) = x*tanh(softplus(x)) = x*(t^2+2t)/(t^2+2t+2), t=e^x.
__device__ __forceinline__ float mish_fast(float x) {
    float t = __expf(fminf(x, 20.f));
    float p = __builtin_fmaf(t, t, t + t);         // t^2 + 2t
    return x * p * __builtin_amdgcn_rcpf(p + 2.f);
}
__device__ __forceinline__ float silu_f(float x) {
    return x * __builtin_amdgcn_rcpf(1.f + __expf(-x));
}
__device__ __forceinline__ float softplus_fast(float x) {
    return fmaxf(x, 0.f) + __logf(1.f + __expf(-fabsf(x)));
}

// ===========================================================================
// STAGE 1: role A (blocks 0..1023)   = wavelet up + channel mean
//          role D (blocks 1024..1535) = ss2d input projection GEMM
// Both roles read only x; outputs disjoint.
// ===========================================================================
__global__ __launch_bounds__(256) void k_stage1(
    const float* __restrict__ x,
    const float* __restrict__ wav_w, const float* __restrict__ wav_b,
    const float* __restrict__ wav_scale,
    float* __restrict__ up, float* __restrict__ mean,
    const float* __restrict__ in_w,
    float* __restrict__ xi, float* __restrict__ z) {
    __shared__ float smem[8640];
    int bid = blockIdx.x;
    int tid = threadIdx.x;

    if (bid < 1024) {
        // ---------------- role A: k_up + mean ----------------
        int c = bid & 63, b = bid >> 6;
        float* xs  = smem;                 // 64*65 = 4160
        float* wtb = smem + 4160;          // 4 * 1056
        float* red = smem + 8384;          // 256
        const float* xp = x + ((size_t)b * DIM + c) * HW;
        for (int i = tid; i < HW; i += 256) xs[(i >> 6) * 65 + (i & 63)] = xp[i];
        // mean of plane (b, 64+c) — identical order to original k_mean
        {
            const float* lp = x + ((size_t)b * DIM + 64 + c) * HW;
            float s = 0.f;
            for (int i = tid; i < HW; i += 256) s += lp[i];
            red[tid] = s;
            __syncthreads();               // also orders xs
            for (int o = 128; o > 0; o >>= 1) {
                if (tid < o) red[tid] += red[tid + o];
                __syncthreads();
            }
            if (tid == 0) mean[b * 64 + c] = red[0] * (1.f / HW);
        }
        for (int i = tid; i < 1024; i += 256) {
            int h = i >> 5, w = i & 31;
            float a  = xs[(2 * h) * 65 + 2 * w],     bb = xs[(2 * h) * 65 + 2 * w + 1];
            float cc = xs[(2 * h + 1) * 65 + 2 * w], dd = xs[(2 * h + 1) * 65 + 2 * w + 1];
            wtb[0 * 1056 + h * 33 + w] = 0.5f * (a + bb + cc + dd);
            wtb[1 * 1056 + h * 33 + w] = 0.5f * (a + bb - cc - dd);
            wtb[2 * 1056 + h * 33 + w] = 0.5f * (a - bb + cc - dd);
            wtb[3 * 1056 + h * 33 + w] = 0.5f * (a - bb - cc + dd);
        }
        __syncthreads();
        float wk[4][9], tb[4];
#pragma unroll
        for (int k = 0; k < 4; ++k) {
            int ch = c * 4 + k;
            float sc = wav_scale[ch];
#pragma unroll
            for (int j = 0; j < 9; ++j) wk[k][j] = wav_w[ch * 9 + j] * sc;
            tb[k] = wav_b[ch] * sc;
        }
        float* upp = up + ((size_t)b * CG + c) * HW;
        for (int i = tid; i < 1024; i += 256) {
            int h = i >> 5, w = i & 31;
            float tg[4];
#pragma unroll
            for (int k = 0; k < 4; ++k) {
                float s = tb[k];
#pragma unroll
                for (int dy = -1; dy <= 1; ++dy) {
                    int hh = h + dy;
                    if (hh < 0 || hh >= 32) continue;
#pragma unroll
                    for (int dx = -1; dx <= 1; ++dx) {
                        int wx = w + dx;
                        if (wx < 0 || wx >= 32) continue;
                        s = fmaf(wtb[k * 1056 + hh * 33 + wx], wk[k][(dy + 1) * 3 + (dx + 1)], s);
                    }
                }
                tg[k] = s;
            }
            float u00 = 0.5f * (tg[0] - tg[1] - tg[2] + tg[3]);
            float u01 = 0.5f * (tg[0] - tg[1] + tg[2] - tg[3]);
            float u10 = 0.5f * (tg[0] + tg[1] - tg[2] - tg[3]);
            float u11 = 0.5f * (tg[0] + tg[1] + tg[2] + tg[3]);
            upp[(2 * h) * 64 + 2 * w]         = u00;
            upp[(2 * h) * 64 + 2 * w + 1]     = u01;
            upp[(2 * h + 1) * 64 + 2 * w]     = u10;
            upp[(2 * h + 1) * 64 + 2 * w + 1] = u11;
        }
    } else {
        // ---------------- role D: k_inproj ----------------
        int id2 = bid - 1024;
        int h0 = (id2 & 31) * 2;
        int b  = id2 >> 5;
        float* xs = smem;                  // 32*128
        float* wt = smem + 4096;           // 32*128

        float acc[8][8];
#pragma unroll
        for (int i = 0; i < 8; ++i)
#pragma unroll
            for (int j = 0; j < 8; ++j) acc[i][j] = 0.f;

        int o0 = (tid >> 4) * 8;
        int p0 = (tid & 15) * 8;

        for (int ko = 0; ko < 64; ko += 32) {
            if (ko) __syncthreads();
            {
                int s = tid;
#pragma unroll
                for (int it = 0; it < 4; ++it, s += 256) {
                    int c = s >> 5, p4 = (s & 31) * 4;
                    float4 v = *(const float4*)(x + ((size_t)b * DIM + ko + c) * HW + h0 * 64 + p4);
                    *(float4*)(xs + c * 128 + p4) = v;
                }
            }
            {
                int s = tid;
#pragma unroll
                for (int it = 0; it < 4; ++it, s += 256) {
                    int o = s >> 3, c0 = (s & 7) * 4;
                    float4 v = *(const float4*)(in_w + o * 64 + ko + c0);
                    wt[(c0 + 0) * 128 + o] = v.x;
                    wt[(c0 + 1) * 128 + o] = v.y;
                    wt[(c0 + 2) * 128 + o] = v.z;
                    wt[(c0 + 3) * 128 + o] = v.w;
                }
            }
            __syncthreads();
#pragma unroll 4
            for (int c = 0; c < 32; ++c) {
                float xv[8], wv[8];
                *(float4*)(xv)     = *(const float4*)(xs + c * 128 + p0);
                *(float4*)(xv + 4) = *(const float4*)(xs + c * 128 + p0 + 4);
                *(float4*)(wv)     = *(const float4*)(wt + c * 128 + o0);
                *(float4*)(wv + 4) = *(const float4*)(wt + c * 128 + o0 + 4);
#pragma unroll
                for (int i = 0; i < 8; ++i)
#pragma unroll
                    for (int j = 0; j < 8; ++j)
                        acc[i][j] = fmaf(wv[i], xv[j], acc[i][j]);
            }
        }

#pragma unroll
        for (int i = 0; i < 8; ++i) {
            int o = o0 + i;
            float* dst = (o < 64) ? (xi + ((size_t)b * 64 + o) * HW + h0 * 64)
                                  : (z + ((size_t)b * 64 + (o - 64)) * HW + h0 * 64);
            *(float4*)(dst + p0)     = make_float4(acc[i][0], acc[i][1], acc[i][2], acc[i][3]);
            *(float4*)(dst + p0 + 4) = make_float4(acc[i][4], acc[i][5], acc[i][6], acc[i][7]);
        }
    }
}

// ===========================================================================
// STAGE 2: role E (blocks 0..511)   = fused dwconv+silu -> xc, projections
//          role B (blocks 512..527) = all three expert-mixes
// ===========================================================================
__global__ __launch_bounds__(256) void k_stage2(
    const float* __restrict__ xi,
    const float* __restrict__ cw, const float* __restrict__ cb,
    const float* __restrict__ xpw,
    float* __restrict__ xc, float4* __restrict__ proj4, float2* __restrict__ projBC,
    const float* __restrict__ mean,
    const float* __restrict__ ew3, const float* __restrict__ gw3, const float* __restrict__ g13,
    const float* __restrict__ ew5, const float* __restrict__ gw5, const float* __restrict__ g15,
    const float* __restrict__ ew7, const float* __restrict__ gw7, const float* __restrict__ g17,
    float* __restrict__ w3o, float* __restrict__ w5o, float* __restrict__ w7o) {
    __shared__ float smem[12608];
    int bid = blockIdx.x;
    int tid = threadIdx.x;

    if (bid < 512) {
        // ---------------- role E: k_convproj ----------------
        int h0 = (bid & 31) * 2;
        int b  = bid >> 5;
        float* xs  = smem;                 // 32*264 = 8448
        float* xcs = smem + 8448;          // 32*130 = 4160

        int dir = tid >> 7;
        int px  = tid & 127;
        float acc0 = 0.f, acc1 = 0.f, acc2 = 0.f, acc3 = 0.f, acc4 = 0.f, acc5 = 0.f;

        int cl_c = tid >> 3;
        int p0_c = (tid & 7) * 16;
        int row_c = p0_c >> 6;
        int wb_c  = p0_c & 63;

        for (int ch0 = 0; ch0 < 64; ch0 += 32) {
            if (ch0) __syncthreads();
            {
                int s = tid;
#pragma unroll
                for (int it = 0; it < 8; ++it, s += 256) {
                    int c = s >> 6;
                    int rem = s & 63;
                    int r = rem >> 4, w4 = (rem & 15) * 4;
                    int gh = h0 - 1 + r;
                    float4 v = make_float4(0.f, 0.f, 0.f, 0.f);
                    if (gh >= 0 && gh < 64)
                        v = *(const float4*)(xi + ((size_t)b * 64 + ch0 + c) * HW + gh * 64 + w4);
                    float* dp = xs + c * 264 + r * 66 + 1 + w4;
                    dp[0] = v.x; dp[1] = v.y; dp[2] = v.z; dp[3] = v.w;
                }
                if (tid < 128) {
                    int cl = tid >> 2, r = tid & 3;
                    xs[cl * 264 + r * 66 + 0]  = 0.f;
                    xs[cl * 264 + r * 66 + 65] = 0.f;
                }
            }
            __syncthreads();

            {
                float wk[9];
#pragma unroll
                for (int j = 0; j < 9; ++j) wk[j] = cw[(ch0 + cl_c) * 9 + j];
                float bias = cb[ch0 + cl_c];
                float accr[16];
#pragma unroll
                for (int k = 0; k < 16; ++k) accr[k] = bias;
#pragma unroll
                for (int dy = 0; dy < 3; ++dy) {
                    const float* rp = xs + cl_c * 264 + (row_c + dy) * 66 + wb_c;
                    float r[18];
#pragma unroll
                    for (int q = 0; q < 18; ++q) r[q] = rp[q];
#pragma unroll
                    for (int k = 0; k < 16; ++k)
#pragma unroll
                        for (int dx = 0; dx < 3; ++dx)
                            accr[k] = fmaf(r[k + dx], wk[dy * 3 + dx], accr[k]);
                }
#pragma unroll
                for (int k = 0; k < 16; ++k)
                    xcs[cl_c * 130 + p0_c + k] = silu_f(accr[k]);
            }
            __syncthreads();

            {
                int s = tid;
#pragma unroll
                for (int it = 0; it < 4; ++it, s += 256) {
                    int c = s >> 5, pq = (s & 31) * 4;
                    const float* sp = xcs + c * 130 + pq;
                    *(float4*)(xc + ((size_t)b * 64 + ch0 + c) * HW + h0 * 64 + pq) =
                        make_float4(sp[0], sp[1], sp[2], sp[3]);
                }
            }
            {
                const float* wp = xpw + dir * 6 * 64 + ch0;
#pragma unroll 8
                for (int c = 0; c < 32; ++c) {
                    float xv = xcs[c * 130 + px];
                    acc0 = fmaf(xv, wp[0 * 64 + c], acc0);
                    acc1 = fmaf(xv, wp[1 * 64 + c], acc1);
                    acc2 = fmaf(xv, wp[2 * 64 + c], acc2);
                    acc3 = fmaf(xv, wp[3 * 64 + c], acc3);
                    acc4 = fmaf(xv, wp[4 * 64 + c], acc4);
                    acc5 = fmaf(xv, wp[5 * 64 + c], acc5);
                }
            }
        }

        int h = h0 + (px >> 6), w = px & 63;
        int l = (dir == 0) ? (h * 64 + w) : (w * 64 + h);
        size_t base = ((size_t)dir * NB + b) * HW + l;
        proj4[base]  = make_float4(acc0, acc1, acc2, acc3);
        projBC[base] = make_float2(acc4, acc5);
    } else {
        // ---------------- role B: k_weff_all (256 threads, 64 active) ----------------
        int b = bid - 512;
        int c = tid;
        float* m = smem;        // 64
        float* g = smem + 64;   // 4
        if (c < 64) m[c] = mean[b * 64 + c];
        __syncthreads();
        const float rs = rsqrtf(1.f + 1e-5f);

#define WEFF_SECT(GW, EW, G1, OUT, K2)                                        \
        {                                                                     \
            if (c < 4) {                                                      \
                float l = 0.f;                                                \
                for (int cc = 0; cc < 64; ++cc) l += m[cc] * GW[c * 64 + cc]; \
                g[c] = l;                                                     \
            }                                                                 \
            __syncthreads();                                                  \
            if (c == 0) {                                                     \
                float mx = fmaxf(fmaxf(g[0], g[1]), fmaxf(g[2], g[3]));       \
                float e0 = expf(g[0] - mx), e1 = expf(g[1] - mx);             \
                float e2 = expf(g[2] - mx), e3 = expf(g[3] - mx);             \
                float inv = 1.f / (e0 + e1 + e2 + e3);                        \
                g[0] = e0 * inv; g[1] = e1 * inv; g[2] = e2 * inv; g[3] = e3 * inv; \
            }                                                                 \
            __syncthreads();                                                  \
            if (c < 64) {                                                     \
                float g1s = G1[c] * rs;                                       \
                for (int kk = 0; kk < K2; ++kk) {                             \
                    float w = 0.f;                                            \
                    for (int e = 0; e < 4; ++e) w += g[e] * EW[(e * 64 + c) * K2 + kk]; \
                    OUT[(b * 64 + c) * K2 + kk] = w * g1s;                    \
                }                                                             \
            }                                                                 \
            __syncthreads();                                                  \
        }

        WEFF_SECT(gw3, ew3, g13, w3o, 9)
        WEFF_SECT(gw5, ew5, g15, w5o, 25)
        WEFF_SECT(gw7, ew7, g17, w7o, 49)
#undef WEFF_SECT
    }
}

// ===========================================================================
// STAGE 3: selective scan, both directions per block (unchanged from v3).
// ===========================================================================
__global__ __launch_bounds__(256) void k_scan2(const float* __restrict__ xc,
                                               const float4* __restrict__ proj4,
                                               const float2* __restrict__ projBC,
                                               const float* __restrict__ dt_w,
                                               const float* __restrict__ dt_b,
                                               const float* __restrict__ A_log,
                                               const float* __restrict__ Dp,
                                               const float* __restrict__ z,
                                               float* __restrict__ yz) {
    int wave = threadIdx.x >> 6;
    int lane = threadIdx.x & 63;
    int wid = blockIdx.x;                // b*64 + d
    int b = wid >> 6;
    int d = wid & 63;

    __shared__ float ut[64 * 65];
    __shared__ float al[4][1088];
    __shared__ float bl[4][1088];
    __shared__ float aggA[4], aggB[4];

    const float* uplane = xc + ((size_t)b * 64 + d) * HW;
    const float4* up4 = (const float4*)uplane;
#pragma unroll
    for (int q = 0; q < 4; ++q) {
        int s = q * 256 + threadIdx.x;
        float4 v = up4[s];
        int r = s >> 4, c0 = (s & 15) * 4;
        float* p = ut + r * 65 + c0;
        p[0] = v.x; p[1] = v.y; p[2] = v.z; p[3] = v.w;
    }
    __syncthreads();

    int ch = wave;
    float* a_my = al[wave];
    float* b_my = bl[wave];
    float y0r[16];

    // ================= DIR 0 =================
    {
        float4 wv = *(const float4*)(dt_w + d * 4);
        float db = dt_b[d];
        float A = -__expf(A_log[d]);
        float Dv = Dp[d];
        const float4* p4 = proj4 + (size_t)b * HW;
        const float2* pBC = projBC + (size_t)b * HW;

        float uv[16], cm[16];
#pragma unroll
        for (int j = 0; j < 16; ++j) {
            int el = j * 64 + lane;
            int e  = ch * 1024 + el;
            float4 t4 = p4[e];
            float2 t2 = pBC[e];
            float u = ut[(ch * 16 + j) * 65 + lane];
            uv[j] = u; cm[j] = t2.y;
            float pre = fmaf(t4.x, wv.x, fmaf(t4.y, wv.y,
                        fmaf(t4.z, wv.z, fmaf(t4.w, wv.w, db))));
            float delta = softplus_fast(pre);
            float aj = __expf(delta * A);
            float bj = delta * t2.x * u;
            int idx = (el >> 4) * 17 + (el & 15);
            a_my[idx] = aj;
            b_my[idx] = bj;
        }
        __builtin_amdgcn_wave_barrier();

        float a[16], bb[16];
#pragma unroll
        for (int j = 0; j < 16; ++j) {
            a[j]  = a_my[lane * 17 + j];
            bb[j] = b_my[lane * 17 + j];
        }
        float As = 1.f, Bs = 0.f;
#pragma unroll
        for (int j = 0; j < 16; ++j) { Bs = fmaf(a[j], Bs, bb[j]); As *= a[j]; }
        float Ai = As, Bi = Bs;
#pragma unroll
        for (int off = 1; off < 64; off <<= 1) {
            float ap = __shfl_up(Ai, (unsigned)off, 64);
            float bp = __shfl_up(Bi, (unsigned)off, 64);
            if (lane >= off) { Bi = fmaf(Ai, bp, Bi); Ai *= ap; }
        }
        if (lane == 63) { aggA[wave] = Ai; aggB[wave] = Bi; }
        __syncthreads();
        float carry = 0.f;
        for (int k = 0; k < wave; ++k) carry = fmaf(aggA[k], carry, aggB[k]);
        float ap1 = __shfl_up(Ai, 1, 64);
        float bp1 = __shfl_up(Bi, 1, 64);
        float h = (lane == 0) ? carry : fmaf(ap1, carry, bp1);
#pragma unroll
        for (int j = 0; j < 16; ++j) {
            h = fmaf(a[j], h, bb[j]);
            a_my[lane * 17 + j] = h;
        }
        __builtin_amdgcn_wave_barrier();
#pragma unroll
        for (int j = 0; j < 16; ++j) {
            int el = j * 64 + lane;
            float hv = a_my[(el >> 4) * 17 + (el & 15)];
            y0r[j] = fmaf(hv, cm[j], Dv * uv[j]);
        }
    }
    __syncthreads();

    // ================= DIR 1 =================
    {
        int pd = 64 + d;
        float4 wv = *(const float4*)(dt_w + pd * 4);
        float db = dt_b[pd];
        float A = -__expf(A_log[pd]);
        float Dv = Dp[pd];
        const float4* p4 = proj4 + ((size_t)NB + b) * HW;
        const float2* pBC = projBC + ((size_t)NB + b) * HW;

        float uv[16], cm[16];
#pragma unroll
        for (int j = 0; j < 16; ++j) {
            int el = j * 64 + lane;
            int e  = ch * 1024 + el;
            float4 t4 = p4[e];
            float2 t2 = pBC[e];
            float u = ut[lane * 65 + (ch * 16 + j)];
            uv[j] = u; cm[j] = t2.y;
            float pre = fmaf(t4.x, wv.x, fmaf(t4.y, wv.y,
                        fmaf(t4.z, wv.z, fmaf(t4.w, wv.w, db))));
            float delta = softplus_fast(pre);
            float aj = __expf(delta * A);
            float bj = delta * t2.x * u;
            int idx = (el >> 4) * 17 + (el & 15);
            a_my[idx] = aj;
            b_my[idx] = bj;
        }
        __builtin_amdgcn_wave_barrier();

        float a[16], bb[16];
#pragma unroll
        for (int j = 0; j < 16; ++j) {
            a[j]  = a_my[lane * 17 + j];
            bb[j] = b_my[lane * 17 + j];
        }
        float As = 1.f, Bs = 0.f;
#pragma unroll
        for (int j = 0; j < 16; ++j) { Bs = fmaf(a[j], Bs, bb[j]); As *= a[j]; }
        float Ai = As, Bi = Bs;
#pragma unroll
        for (int off = 1; off < 64; off <<= 1) {
            float ap = __shfl_up(Ai, (unsigned)off, 64);
            float bp = __shfl_up(Bi, (unsigned)off, 64);
            if (lane >= off) { Bi = fmaf(Ai, bp, Bi); Ai *= ap; }
        }
        if (lane == 63) { aggA[wave] = Ai; aggB[wave] = Bi; }
        __syncthreads();
        float carry = 0.f;
        for (int k = 0; k < wave; ++k) carry = fmaf(aggA[k], carry, aggB[k]);
        float ap1 = __shfl_up(Ai, 1, 64);
        float bp1 = __shfl_up(Bi, 1, 64);
        float h = (lane == 0) ? carry : fmaf(ap1, carry, bp1);
#pragma unroll
        for (int j = 0; j < 16; ++j) {
            h = fmaf(a[j], h, bb[j]);
            a_my[lane * 17 + j] = h;
        }
        __builtin_amdgcn_wave_barrier();
#pragma unroll
        for (int j = 0; j < 16; ++j) {
            int el = j * 64 + lane;
            float hv = a_my[(el >> 4) * 17 + (el & 15)];
            ut[lane * 65 + (ch * 16 + j)] = fmaf(hv, cm[j], Dv * uv[j]);
        }
    }
    __syncthreads();

    const float* zp = z + ((size_t)b * 64 + d) * HW;
    float* yp = yz + ((size_t)b * 64 + d) * HW;
#pragma unroll
    for (int j = 0; j < 16; ++j) {
        int e = ch * 1024 + j * 64 + lane;
        float y1v = ut[(ch * 16 + j) * 65 + lane];
        float zz = zp[e];
        yp[e] = (y0r[j] + y1v) * silu_f(zz);
    }
}

// ===========================================================================
// STAGE 4: role C (blocks 0..4095)    = local conv + passthrough copy
//          role G (blocks 4096..4607) = final GEMM + up add
// Disjoint out channel ranges: C -> [64:256], G -> [0:64].
// ===========================================================================
__global__ __launch_bounds__(256) void k_stage4(
    const float* __restrict__ x,
    const float* __restrict__ w3, const float* __restrict__ w5, const float* __restrict__ w7,
    const float* __restrict__ b1_0, const float* __restrict__ pw0,
    const float* __restrict__ g2_0, const float* __restrict__ b2_0,
    const float* __restrict__ b1_1, const float* __restrict__ pw1,
    const float* __restrict__ g2_1, const float* __restrict__ b2_1,
    const float* __restrict__ b1_2, const float* __restrict__ pw2,
    const float* __restrict__ g2_2, const float* __restrict__ b2_2,
    const float* __restrict__ yz, const float* __restrict__ ow,
    const float* __restrict__ base_scale, const float* __restrict__ up,
    float* __restrict__ out) {
    __shared__ float smem[6144];
    int bid = blockIdx.x;
    int tid = threadIdx.x;

    if (bid < 4096) {
        // ---------------- role C: k_local + passthrough ----------------
        int tile = bid & 3;
        int c = (bid >> 2) & 63;
        int b = bid >> 8;
        int oy = (tile >> 1) * 32, ox = (tile & 1) * 32;
        float* t = smem;                   // 38*40 = 1520
        const float* xp = x + ((size_t)b * DIM + 64 + c) * HW;
        for (int i = tid; i < 38 * 38; i += 256) {
            int r = i / 38, cc = i % 38;
            int yy = r - 3 + oy, xx = cc - 3 + ox;
            t[r * 40 + cc] = (yy >= 0 && yy < 64 && xx >= 0 && xx < 64) ? xp[yy * 64 + xx] : 0.f;
        }
        // fused passthrough copy
        {
            const float4* x4 = (const float4*)x;
            float4* o4 = (float4*)out;
            int base = bid * 512;
#pragma unroll
            for (int it = 0; it < 2; ++it) {
                int idx = base + it * 256 + tid;
                int bb = idx >> 17;
                int r  = idx & 131071;
                int gi = bb * 262144 + 131072 + r;
                o4[gi] = x4[gi];
            }
        }
        const float* w3p = w3 + (b * 64 + c) * 9;
        const float* w5p = w5 + (b * 64 + c) * 25;
        const float* w7p = w7 + (b * 64 + c) * 49;
        float W3r[9], W5r[25], W7r[49];
#pragma unroll
        for (int j = 0; j < 9; ++j)  W3r[j] = w3p[j];
#pragma unroll
        for (int j = 0; j < 25; ++j) W5r[j] = w5p[j];
#pragma unroll
        for (int j = 0; j < 49; ++j) W7r[j] = w7p[j];
        __syncthreads();

        const float rs = rsqrtf(1.f + 1e-5f);
        float bb1a = b1_0[c], bb1b = b1_1[c], bb1c = b1_2[c];
        float ssa = pw0[c] * g2_0[c] * rs, ssb = pw1[c] * g2_1[c] * rs, ssc = pw2[c] * g2_2[c] * rs;
        float bb2a = b2_0[c], bb2b = b2_1[c], bb2c = b2_2[c];

        int y  = tid >> 3;
        int x0 = (tid & 7) * 4;

        float a3[4] = {0.f, 0.f, 0.f, 0.f};
        float a5[4] = {0.f, 0.f, 0.f, 0.f};
        float a7[4] = {0.f, 0.f, 0.f, 0.f};

#pragma unroll
        for (int dy = 0; dy < 7; ++dy) {
            const float4* rp = (const float4*)(t + (y + dy) * 40 + x0);
            float4 q0 = rp[0], q1 = rp[1], q2 = rp[2];
            float r[12] = {q0.x, q0.y, q0.z, q0.w, q1.x, q1.y, q1.z, q1.w,
                           q2.x, q2.y, q2.z, q2.w};
#pragma unroll
            for (int k = 0; k < 4; ++k)
#pragma unroll
                for (int dx = 0; dx < 7; ++dx)
                    a7[k] = fmaf(r[k + dx], W7r[dy * 7 + dx], a7[k]);
            if (dy >= 1 && dy <= 5) {
                int ey = dy - 1;
#pragma unroll
                for (int k = 0; k < 4; ++k)
#pragma unroll
                    for (int dx = 0; dx < 5; ++dx)
                        a5[k] = fmaf(r[k + 1 + dx], W5r[ey * 5 + dx], a5[k]);
            }
            if (dy >= 2 && dy <= 4) {
                int ey = dy - 2;
#pragma unroll
                for (int k = 0; k < 4; ++k)
#pragma unroll
                    for (int dx = 0; dx < 3; ++dx)
                        a3[k] = fmaf(r[k + 2 + dx], W3r[ey * 3 + dx], a3[k]);
            }
        }

        float4 res;
        float* rr = (float*)&res;
#pragma unroll
        for (int k = 0; k < 4; ++k) {
            rr[k] = mish_fast(a3[k] + bb1a) * ssa + bb2a
                  + mish_fast(a5[k] + bb1b) * ssb + bb2b
                  + mish_fast(a7[k] + bb1c) * ssc + bb2c;
        }
        float* op = out + ((size_t)b * DIM + 64 + c) * HW;
        *(float4*)(op + (oy + y) * 64 + ox + x0) = res;
    } else {
        // ---------------- role G: k_final ----------------
        int id2 = bid - 4096;
        int h0 = (id2 & 31) * 2;
        int b  = id2 >> 5;
        float* yv = smem;                  // 32*128 = 4096
        float* wt = smem + 4096;           // 32*64 = 2048

        float acc[8][4];
#pragma unroll
        for (int i = 0; i < 8; ++i)
#pragma unroll
            for (int j = 0; j < 4; ++j) acc[i][j] = 0.f;

        int o0 = (tid >> 5) * 8;
        int p0 = (tid & 31) * 4;

        for (int ko = 0; ko < 64; ko += 32) {
            if (ko) __syncthreads();
            {
                int s = tid;
#pragma unroll
                for (int it = 0; it < 4; ++it, s += 256) {
                    int c = s >> 5, p4 = (s & 31) * 4;
                    size_t idx = ((size_t)b * 64 + ko + c) * HW + h0 * 64 + p4;
                    *(float4*)(yv + c * 128 + p4) = *(const float4*)(yz + idx);
                }
            }
            {
                int s = tid;
#pragma unroll
                for (int it = 0; it < 2; ++it, s += 256) {
                    int o = s >> 3, c0 = (s & 7) * 4;
                    float4 v = *(const float4*)(ow + o * 64 + ko + c0);
                    wt[(c0 + 0) * 64 + o] = v.x;
                    wt[(c0 + 1) * 64 + o] = v.y;
                    wt[(c0 + 2) * 64 + o] = v.z;
                    wt[(c0 + 3) * 64 + o] = v.w;
                }
            }
            __syncthreads();
#pragma unroll 4
            for (int c = 0; c < 32; ++c) {
                float wv[8], xv[4];
                *(float4*)(wv)     = *(const float4*)(wt + c * 64 + o0);
                *(float4*)(wv + 4) = *(const float4*)(wt + c * 64 + o0 + 4);
                *(float4*)(xv)     = *(const float4*)(yv + c * 128 + p0);
#pragma unroll
                for (int i = 0; i < 8; ++i)
#pragma unroll
                    for (int j = 0; j < 4; ++j)
                        acc[i][j] = fmaf(wv[i], xv[j], acc[i][j]);
            }
        }

#pragma unroll
        for (int i = 0; i < 8; ++i) {
            int o = o0 + i;
            float bs = base_scale[o];
            float4 u = *(const float4*)(up + ((size_t)b * 64 + o) * HW + h0 * 64 + p0);
            float4 r = make_float4(fmaf(bs, acc[i][0], u.x),
                                   fmaf(bs, acc[i][1], u.y),
                                   fmaf(bs, acc[i][2], u.z),
                                   fmaf(bs, acc[i][3], u.w));
            *(float4*)(out + ((size_t)b * DIM + o) * HW + h0 * 64 + p0) = r;
        }
    }
}

// ---------------------------------------------------------------------------
extern "C" void kernel_launch(void* const* d_in, const int* in_sizes, int n_in,
                              void* d_out, int out_size, void* d_ws, size_t ws_size,
                              hipStream_t stream) {
    (void)in_sizes; (void)n_in; (void)out_size; (void)ws_size;
    const float* x = (const float*)d_in[0];
    float* out = (float*)d_out;
    float* ws = (float*)d_ws;

    const size_t IMG = (size_t)NB * 64 * HW;   // 4,194,304 floats
    float* buf_xi   = ws;                      // xi, later reused as yz
    float* buf_z    = ws + IMG;
    float* buf_xc   = ws + 2 * IMG;
    float* buf_up   = ws + 3 * IMG;
    float* buf_p4   = ws + 4 * IMG;            // float4[2*16*4096]
    float* buf_pBC  = buf_p4 + (size_t)4 * 2 * NB * HW;
    float* buf_mean = buf_pBC + (size_t)2 * 2 * NB * HW;
    float* buf_w3   = buf_mean + 1024;
    float* buf_w5   = buf_w3 + 16 * 64 * 9;
    float* buf_w7   = buf_w5 + 16 * 64 * 25;

    // stage1: wavelet-up + mean (A) || input projection (D)
    k_stage1<<<1536, 256, 0, stream>>>(x,
        (const float*)d_in[22], (const float*)d_in[23], (const float*)d_in[24],
        buf_up, buf_mean,
        (const float*)d_in[26], buf_xi, buf_z);

    // stage2: dwconv+proj (E) || expert-mix weights (B)
    k_stage2<<<528, 256, 0, stream>>>(buf_xi,
        (const float*)d_in[27], (const float*)d_in[28], (const float*)d_in[29],
        buf_xc, (float4*)buf_p4, (float2*)buf_pBC,
        buf_mean,
        (const float*)d_in[1],  (const float*)d_in[2],  (const float*)d_in[3],
        (const float*)d_in[8],  (const float*)d_in[9],  (const float*)d_in[10],
        (const float*)d_in[15], (const float*)d_in[16], (const float*)d_in[17],
        buf_w3, buf_w5, buf_w7);

    // stage3: dual-direction selective scan -> yz (xi is dead, reuse)
    k_scan2<<<1024, 256, 0, stream>>>(buf_xc, (const float4*)buf_p4, (const float2*)buf_pBC,
        (const float*)d_in[30], (const float*)d_in[31],
        (const float*)d_in[32], (const float*)d_in[33],
        buf_z, buf_xi);

    // stage4: local conv + passthrough (C) || final GEMM (G)
    k_stage4<<<4608, 256, 0, stream>>>(x, buf_w3, buf_w5, buf_w7,
        (const float*)d_in[4],  (const float*)d_in[5],  (const float*)d_in[6],  (const float*)d_in[7],
        (const float*)d_in[11], (const float*)d_in[12], (const float*)d_in[13], (const float*)d_in[14],
        (const float*)d_in[18], (const float*)d_in[19], (const float*)d_in[20], (const float*)d_in[21],
        buf_xi, (const float*)d_in[34], (const float*)d_in[25], buf_up, out);
}

// Round 11
// 119.676 us; speedup vs baseline: 1.9643x; 1.0563x over previous
//
#include <hip/hip_runtime.h>
#include <math.h>

// Problem constants
static constexpr int NB   = 16;    // batch
static constexpr int DIM  = 256;   // total channels
static constexpr int CG   = 64;    // global-branch channels
static constexpr int HH   = 64;
static constexpr int WW   = 64;
static constexpr int HW   = HH * WW;   // 4096

// mish(x) = x*tanh(softplus(x)) = x*(t^2+2t)/(t^2+2t+2), t=e^x.
__device__ __forceinline__ float mish_fast(float x) {
    float t = __expf(fminf(x, 20.f));
    float p = __builtin_fmaf(t, t, t + t);         // t^2 + 2t
    return x * p * __builtin_amdgcn_rcpf(p + 2.f);
}
__device__ __forceinline__ float silu_f(float x) {
    return x * __builtin_amdgcn_rcpf(1.f + __expf(-x));
}
__device__ __forceinline__ float softplus_fast(float x) {
    return fmaxf(x, 0.f) + __logf(1.f + __expf(-fabsf(x)));
}

// ===========================================================================
// STAGE 1 (roles interleaved: bid%3==2 -> D, else A)
//   role A = wavelet up (register-direct Haar dec) + channel mean
//   role D = ss2d input projection GEMM
// ===========================================================================
__global__ __launch_bounds__(256) void k_stage1(
    const float* __restrict__ x,
    const float* __restrict__ wav_w, const float* __restrict__ wav_b,
    const float* __restrict__ wav_scale,
    float* __restrict__ up, float* __restrict__ mean,
    const float* __restrict__ in_w,
    float* __restrict__ xi, float* __restrict__ z) {
    __shared__ float smem[8192];
    int bid = blockIdx.x;
    int tid = threadIdx.x;

    if (bid % 3 != 2) {
        // ---------------- role A: wavelet + mean ----------------
        int aid = (bid / 3) * 2 + (bid % 3);   // 0..1023
        int c = aid & 63, b = aid >> 6;
        float* wtb = smem;                 // 4 planes * (32*34) = 4352
        float* red = smem + 4352;          // 256
        const float* xp = x + ((size_t)b * DIM + c) * HW;

        // mean of plane (b, 64+c), float4 loads
        {
            const float4* lp4 = (const float4*)(x + ((size_t)b * DIM + 64 + c) * HW);
            float s = 0.f;
            for (int i = tid; i < 1024; i += 256) {
                float4 v = lp4[i];
                s += (v.x + v.y) + (v.z + v.w);
            }
            red[tid] = s;
            __syncthreads();
            for (int o = 128; o > 0; o >>= 1) {
                if (tid < o) red[tid] += red[tid + o];
                __syncthreads();
            }
            if (tid == 0) mean[b * 64 + c] = red[0] * (1.f / HW);
        }

        // register-direct Haar dec: each pair p covers quads (h,2w2),(h,2w2+1)
#pragma unroll
        for (int it = 0; it < 2; ++it) {
            int p = tid + it * 256;        // 0..511
            int h = p >> 4, w2 = p & 15;
            float4 top = *(const float4*)(xp + (2 * h) * 64 + 4 * w2);
            float4 bot = *(const float4*)(xp + (2 * h + 1) * 64 + 4 * w2);
            float a0 = top.x, b0 = top.y, c0q = bot.x, d0 = bot.y;
            float a1 = top.z, b1 = top.w, c1q = bot.z, d1 = bot.w;
            int base0 = h * 34 + 2 * w2;
            *(float2*)(wtb + 0 * 1088 + base0) =
                make_float2(0.5f * (a0 + b0 + c0q + d0), 0.5f * (a1 + b1 + c1q + d1));
            *(float2*)(wtb + 1 * 1088 + base0) =
                make_float2(0.5f * (a0 + b0 - c0q - d0), 0.5f * (a1 + b1 - c1q - d1));
            *(float2*)(wtb + 2 * 1088 + base0) =
                make_float2(0.5f * (a0 - b0 + c0q - d0), 0.5f * (a1 - b1 + c1q - d1));
            *(float2*)(wtb + 3 * 1088 + base0) =
                make_float2(0.5f * (a0 - b0 - c0q + d0), 0.5f * (a1 - b1 - c1q + d1));
        }
        __syncthreads();

        float wk[4][9], tb[4];
#pragma unroll
        for (int k = 0; k < 4; ++k) {
            int ch = c * 4 + k;
            float sc = wav_scale[ch];
#pragma unroll
            for (int j = 0; j < 9; ++j) wk[k][j] = wav_w[ch * 9 + j] * sc;
            tb[k] = wav_b[ch] * sc;
        }
        float* upp = up + ((size_t)b * CG + c) * HW;
        for (int i = tid; i < 1024; i += 256) {
            int h = i >> 5, w = i & 31;
            float tg[4];
#pragma unroll
            for (int k = 0; k < 4; ++k) {
                float s = tb[k];
#pragma unroll
                for (int dy = -1; dy <= 1; ++dy) {
                    int hh = h + dy;
                    if (hh < 0 || hh >= 32) continue;
#pragma unroll
                    for (int dx = -1; dx <= 1; ++dx) {
                        int wx = w + dx;
                        if (wx < 0 || wx >= 32) continue;
                        s = fmaf(wtb[k * 1088 + hh * 34 + wx], wk[k][(dy + 1) * 3 + (dx + 1)], s);
                    }
                }
                tg[k] = s;
            }
            float u00 = 0.5f * (tg[0] - tg[1] - tg[2] + tg[3]);
            float u01 = 0.5f * (tg[0] - tg[1] + tg[2] - tg[3]);
            float u10 = 0.5f * (tg[0] + tg[1] - tg[2] - tg[3]);
            float u11 = 0.5f * (tg[0] + tg[1] + tg[2] + tg[3]);
            *(float2*)(upp + (2 * h) * 64 + 2 * w)     = make_float2(u00, u01);
            *(float2*)(upp + (2 * h + 1) * 64 + 2 * w) = make_float2(u10, u11);
        }
    } else {
        // ---------------- role D: k_inproj ----------------
        int id2 = bid / 3;                 // 0..511
        int h0 = (id2 & 31) * 2;
        int b  = id2 >> 5;
        float* xs = smem;                  // 32*128
        float* wt = smem + 4096;           // 32*128

        float acc[8][8];
#pragma unroll
        for (int i = 0; i < 8; ++i)
#pragma unroll
            for (int j = 0; j < 8; ++j) acc[i][j] = 0.f;

        int o0 = (tid >> 4) * 8;
        int p0 = (tid & 15) * 8;

        for (int ko = 0; ko < 64; ko += 32) {
            if (ko) __syncthreads();
            {
                int s = tid;
#pragma unroll
                for (int it = 0; it < 4; ++it, s += 256) {
                    int c = s >> 5, p4 = (s & 31) * 4;
                    float4 v = *(const float4*)(x + ((size_t)b * DIM + ko + c) * HW + h0 * 64 + p4);
                    *(float4*)(xs + c * 128 + p4) = v;
                }
            }
            {
                int s = tid;
#pragma unroll
                for (int it = 0; it < 4; ++it, s += 256) {
                    int o = s >> 3, c0 = (s & 7) * 4;
                    float4 v = *(const float4*)(in_w + o * 64 + ko + c0);
                    wt[(c0 + 0) * 128 + o] = v.x;
                    wt[(c0 + 1) * 128 + o] = v.y;
                    wt[(c0 + 2) * 128 + o] = v.z;
                    wt[(c0 + 3) * 128 + o] = v.w;
                }
            }
            __syncthreads();
#pragma unroll 4
            for (int c = 0; c < 32; ++c) {
                float xv[8], wv[8];
                *(float4*)(xv)     = *(const float4*)(xs + c * 128 + p0);
                *(float4*)(xv + 4) = *(const float4*)(xs + c * 128 + p0 + 4);
                *(float4*)(wv)     = *(const float4*)(wt + c * 128 + o0);
                *(float4*)(wv + 4) = *(const float4*)(wt + c * 128 + o0 + 4);
#pragma unroll
                for (int i = 0; i < 8; ++i)
#pragma unroll
                    for (int j = 0; j < 8; ++j)
                        acc[i][j] = fmaf(wv[i], xv[j], acc[i][j]);
            }
        }

#pragma unroll
        for (int i = 0; i < 8; ++i) {
            int o = o0 + i;
            float* dst = (o < 64) ? (xi + ((size_t)b * 64 + o) * HW + h0 * 64)
                                  : (z + ((size_t)b * 64 + (o - 64)) * HW + h0 * 64);
            *(float4*)(dst + p0)     = make_float4(acc[i][0], acc[i][1], acc[i][2], acc[i][3]);
            *(float4*)(dst + p0 + 4) = make_float4(acc[i][4], acc[i][5], acc[i][6], acc[i][7]);
        }
    }
}

// ===========================================================================
// STAGE 2: role E (blocks 0..511) = fused dwconv+silu -> xc, projections
//          role B (blocks 512..527) = all three expert-mixes
// ===========================================================================
__global__ __launch_bounds__(256) void k_stage2(
    const float* __restrict__ xi,
    const float* __restrict__ cw, const float* __restrict__ cb,
    const float* __restrict__ xpw,
    float* __restrict__ xc, float4* __restrict__ proj4, float2* __restrict__ projBC,
    const float* __restrict__ mean,
    const float* __restrict__ ew3, const float* __restrict__ gw3, const float* __restrict__ g13,
    const float* __restrict__ ew5, const float* __restrict__ gw5, const float* __restrict__ g15,
    const float* __restrict__ ew7, const float* __restrict__ gw7, const float* __restrict__ g17,
    float* __restrict__ w3o, float* __restrict__ w5o, float* __restrict__ w7o) {
    __shared__ float smem[12608];
    int bid = blockIdx.x;
    int tid = threadIdx.x;

    if (bid < 512) {
        // ---------------- role E: k_convproj ----------------
        int h0 = (bid & 31) * 2;
        int b  = bid >> 5;
        float* xs  = smem;                 // 32*264 = 8448
        float* xcs = smem + 8448;          // 32*130 = 4160

        int dir = tid >> 7;
        int px  = tid & 127;
        float acc0 = 0.f, acc1 = 0.f, acc2 = 0.f, acc3 = 0.f, acc4 = 0.f, acc5 = 0.f;

        int cl_c = tid >> 3;
        int p0_c = (tid & 7) * 16;
        int row_c = p0_c >> 6;
        int wb_c  = p0_c & 63;

        for (int ch0 = 0; ch0 < 64; ch0 += 32) {
            if (ch0) __syncthreads();
            {
                int s = tid;
#pragma unroll
                for (int it = 0; it < 8; ++it, s += 256) {
                    int c = s >> 6;
                    int rem = s & 63;
                    int r = rem >> 4, w4 = (rem & 15) * 4;
                    int gh = h0 - 1 + r;
                    float4 v = make_float4(0.f, 0.f, 0.f, 0.f);
                    if (gh >= 0 && gh < 64)
                        v = *(const float4*)(xi + ((size_t)b * 64 + ch0 + c) * HW + gh * 64 + w4);
                    float* dp = xs + c * 264 + r * 66 + 1 + w4;
                    dp[0] = v.x; dp[1] = v.y; dp[2] = v.z; dp[3] = v.w;
                }
                if (tid < 128) {
                    int cl = tid >> 2, r = tid & 3;
                    xs[cl * 264 + r * 66 + 0]  = 0.f;
                    xs[cl * 264 + r * 66 + 65] = 0.f;
                }
            }
            __syncthreads();

            {
                float wk[9];
#pragma unroll
                for (int j = 0; j < 9; ++j) wk[j] = cw[(ch0 + cl_c) * 9 + j];
                float bias = cb[ch0 + cl_c];
                float accr[16];
#pragma unroll
                for (int k = 0; k < 16; ++k) accr[k] = bias;
#pragma unroll
                for (int dy = 0; dy < 3; ++dy) {
                    const float* rp = xs + cl_c * 264 + (row_c + dy) * 66 + wb_c;
                    float r[18];
#pragma unroll
                    for (int q = 0; q < 18; ++q) r[q] = rp[q];
#pragma unroll
                    for (int k = 0; k < 16; ++k)
#pragma unroll
                        for (int dx = 0; dx < 3; ++dx)
                            accr[k] = fmaf(r[k + dx], wk[dy * 3 + dx], accr[k]);
                }
#pragma unroll
                for (int k = 0; k < 16; ++k)
                    xcs[cl_c * 130 + p0_c + k] = silu_f(accr[k]);
            }
            __syncthreads();

            {
                int s = tid;
#pragma unroll
                for (int it = 0; it < 4; ++it, s += 256) {
                    int c = s >> 5, pq = (s & 31) * 4;
                    const float* sp = xcs + c * 130 + pq;
                    *(float4*)(xc + ((size_t)b * 64 + ch0 + c) * HW + h0 * 64 + pq) =
                        make_float4(sp[0], sp[1], sp[2], sp[3]);
                }
            }
            {
                const float* wp = xpw + dir * 6 * 64 + ch0;
#pragma unroll 8
                for (int c = 0; c < 32; ++c) {
                    float xv = xcs[c * 130 + px];
                    acc0 = fmaf(xv, wp[0 * 64 + c], acc0);
                    acc1 = fmaf(xv, wp[1 * 64 + c], acc1);
                    acc2 = fmaf(xv, wp[2 * 64 + c], acc2);
                    acc3 = fmaf(xv, wp[3 * 64 + c], acc3);
                    acc4 = fmaf(xv, wp[4 * 64 + c], acc4);
                    acc5 = fmaf(xv, wp[5 * 64 + c], acc5);
                }
            }
        }

        int h = h0 + (px >> 6), w = px & 63;
        int l = (dir == 0) ? (h * 64 + w) : (w * 64 + h);
        size_t base = ((size_t)dir * NB + b) * HW + l;
        proj4[base]  = make_float4(acc0, acc1, acc2, acc3);
        projBC[base] = make_float2(acc4, acc5);
    } else {
        // ---------------- role B: k_weff_all ----------------
        int b = bid - 512;
        int c = tid;
        float* m = smem;
        float* g = smem + 64;
        if (c < 64) m[c] = mean[b * 64 + c];
        __syncthreads();
        const float rs = rsqrtf(1.f + 1e-5f);

#define WEFF_SECT(GW, EW, G1, OUT, K2)                                        \
        {                                                                     \
            if (c < 4) {                                                      \
                float l = 0.f;                                                \
                for (int cc = 0; cc < 64; ++cc) l += m[cc] * GW[c * 64 + cc]; \
                g[c] = l;                                                     \
            }                                                                 \
            __syncthreads();                                                  \
            if (c == 0) {                                                     \
                float mx = fmaxf(fmaxf(g[0], g[1]), fmaxf(g[2], g[3]));       \
                float e0 = expf(g[0] - mx), e1 = expf(g[1] - mx);             \
                float e2 = expf(g[2] - mx), e3 = expf(g[3] - mx);             \
                float inv = 1.f / (e0 + e1 + e2 + e3);                        \
                g[0] = e0 * inv; g[1] = e1 * inv; g[2] = e2 * inv; g[3] = e3 * inv; \
            }                                                                 \
            __syncthreads();                                                  \
            if (c < 64) {                                                     \
                float g1s = G1[c] * rs;                                       \
                for (int kk = 0; kk < K2; ++kk) {                             \
                    float w = 0.f;                                            \
                    for (int e = 0; e < 4; ++e) w += g[e] * EW[(e * 64 + c) * K2 + kk]; \
                    OUT[(b * 64 + c) * K2 + kk] = w * g1s;                    \
                }                                                             \
            }                                                                 \
            __syncthreads();                                                  \
        }

        WEFF_SECT(gw3, ew3, g13, w3o, 9)
        WEFF_SECT(gw5, ew5, g15, w5o, 25)
        WEFF_SECT(gw7, ew7, g17, w7o, 49)
#undef WEFF_SECT
    }
}

// ===========================================================================
// STAGE 3: selective scan, both directions per block (unchanged).
// ===========================================================================
__global__ __launch_bounds__(256) void k_scan2(const float* __restrict__ xc,
                                               const float4* __restrict__ proj4,
                                               const float2* __restrict__ projBC,
                                               const float* __restrict__ dt_w,
                                               const float* __restrict__ dt_b,
                                               const float* __restrict__ A_log,
                                               const float* __restrict__ Dp,
                                               const float* __restrict__ z,
                                               float* __restrict__ yz) {
    int wave = threadIdx.x >> 6;
    int lane = threadIdx.x & 63;
    int wid = blockIdx.x;                // b*64 + d
    int b = wid >> 6;
    int d = wid & 63;

    __shared__ float ut[64 * 65];
    __shared__ float al[4][1088];
    __shared__ float bl[4][1088];
    __shared__ float aggA[4], aggB[4];

    const float* uplane = xc + ((size_t)b * 64 + d) * HW;
    const float4* up4 = (const float4*)uplane;
#pragma unroll
    for (int q = 0; q < 4; ++q) {
        int s = q * 256 + threadIdx.x;
        float4 v = up4[s];
        int r = s >> 4, c0 = (s & 15) * 4;
        float* p = ut + r * 65 + c0;
        p[0] = v.x; p[1] = v.y; p[2] = v.z; p[3] = v.w;
    }
    __syncthreads();

    int ch = wave;
    float* a_my = al[wave];
    float* b_my = bl[wave];
    float y0r[16];

    // ================= DIR 0 =================
    {
        float4 wv = *(const float4*)(dt_w + d * 4);
        float db = dt_b[d];
        float A = -__expf(A_log[d]);
        float Dv = Dp[d];
        const float4* p4 = proj4 + (size_t)b * HW;
        const float2* pBC = projBC + (size_t)b * HW;

        float uv[16], cm[16];
#pragma unroll
        for (int j = 0; j < 16; ++j) {
            int el = j * 64 + lane;
            int e  = ch * 1024 + el;
            float4 t4 = p4[e];
            float2 t2 = pBC[e];
            float u = ut[(ch * 16 + j) * 65 + lane];
            uv[j] = u; cm[j] = t2.y;
            float pre = fmaf(t4.x, wv.x, fmaf(t4.y, wv.y,
                        fmaf(t4.z, wv.z, fmaf(t4.w, wv.w, db))));
            float delta = softplus_fast(pre);
            float aj = __expf(delta * A);
            float bj = delta * t2.x * u;
            int idx = (el >> 4) * 17 + (el & 15);
            a_my[idx] = aj;
            b_my[idx] = bj;
        }
        __builtin_amdgcn_wave_barrier();

        float a[16], bb[16];
#pragma unroll
        for (int j = 0; j < 16; ++j) {
            a[j]  = a_my[lane * 17 + j];
            bb[j] = b_my[lane * 17 + j];
        }
        float As = 1.f, Bs = 0.f;
#pragma unroll
        for (int j = 0; j < 16; ++j) { Bs = fmaf(a[j], Bs, bb[j]); As *= a[j]; }
        float Ai = As, Bi = Bs;
#pragma unroll
        for (int off = 1; off < 64; off <<= 1) {
            float ap = __shfl_up(Ai, (unsigned)off, 64);
            float bp = __shfl_up(Bi, (unsigned)off, 64);
            if (lane >= off) { Bi = fmaf(Ai, bp, Bi); Ai *= ap; }
        }
        if (lane == 63) { aggA[wave] = Ai; aggB[wave] = Bi; }
        __syncthreads();
        float carry = 0.f;
        for (int k = 0; k < wave; ++k) carry = fmaf(aggA[k], carry, aggB[k]);
        float ap1 = __shfl_up(Ai, 1, 64);
        float bp1 = __shfl_up(Bi, 1, 64);
        float h = (lane == 0) ? carry : fmaf(ap1, carry, bp1);
#pragma unroll
        for (int j = 0; j < 16; ++j) {
            h = fmaf(a[j], h, bb[j]);
            a_my[lane * 17 + j] = h;
        }
        __builtin_amdgcn_wave_barrier();
#pragma unroll
        for (int j = 0; j < 16; ++j) {
            int el = j * 64 + lane;
            float hv = a_my[(el >> 4) * 17 + (el & 15)];
            y0r[j] = fmaf(hv, cm[j], Dv * uv[j]);
        }
    }
    __syncthreads();

    // ================= DIR 1 =================
    {
        int pd = 64 + d;
        float4 wv = *(const float4*)(dt_w + pd * 4);
        float db = dt_b[pd];
        float A = -__expf(A_log[pd]);
        float Dv = Dp[pd];
        const float4* p4 = proj4 + ((size_t)NB + b) * HW;
        const float2* pBC = projBC + ((size_t)NB + b) * HW;

        float uv[16], cm[16];
#pragma unroll
        for (int j = 0; j < 16; ++j) {
            int el = j * 64 + lane;
            int e  = ch * 1024 + el;
            float4 t4 = p4[e];
            float2 t2 = pBC[e];
            float u = ut[lane * 65 + (ch * 16 + j)];
            uv[j] = u; cm[j] = t2.y;
            float pre = fmaf(t4.x, wv.x, fmaf(t4.y, wv.y,
                        fmaf(t4.z, wv.z, fmaf(t4.w, wv.w, db))));
            float delta = softplus_fast(pre);
            float aj = __expf(delta * A);
            float bj = delta * t2.x * u;
            int idx = (el >> 4) * 17 + (el & 15);
            a_my[idx] = aj;
            b_my[idx] = bj;
        }
        __builtin_amdgcn_wave_barrier();

        float a[16], bb[16];
#pragma unroll
        for (int j = 0; j < 16; ++j) {
            a[j]  = a_my[lane * 17 + j];
            bb[j] = b_my[lane * 17 + j];
        }
        float As = 1.f, Bs = 0.f;
#pragma unroll
        for (int j = 0; j < 16; ++j) { Bs = fmaf(a[j], Bs, bb[j]); As *= a[j]; }
        float Ai = As, Bi = Bs;
#pragma unroll
        for (int off = 1; off < 64; off <<= 1) {
            float ap = __shfl_up(Ai, (unsigned)off, 64);
            float bp = __shfl_up(Bi, (unsigned)off, 64);
            if (lane >= off) { Bi = fmaf(Ai, bp, Bi); Ai *= ap; }
        }
        if (lane == 63) { aggA[wave] = Ai; aggB[wave] = Bi; }
        __syncthreads();
        float carry = 0.f;
        for (int k = 0; k < wave; ++k) carry = fmaf(aggA[k], carry, aggB[k]);
        float ap1 = __shfl_up(Ai, 1, 64);
        float bp1 = __shfl_up(Bi, 1, 64);
        float h = (lane == 0) ? carry : fmaf(ap1, carry, bp1);
#pragma unroll
        for (int j = 0; j < 16; ++j) {
            h = fmaf(a[j], h, bb[j]);
            a_my[lane * 17 + j] = h;
        }
        __builtin_amdgcn_wave_barrier();
#pragma unroll
        for (int j = 0; j < 16; ++j) {
            int el = j * 64 + lane;
            float hv = a_my[(el >> 4) * 17 + (el & 15)];
            ut[lane * 65 + (ch * 16 + j)] = fmaf(hv, cm[j], Dv * uv[j]);
        }
    }
    __syncthreads();

    const float* zp = z + ((size_t)b * 64 + d) * HW;
    float* yp = yz + ((size_t)b * 64 + d) * HW;
#pragma unroll
    for (int j = 0; j < 16; ++j) {
        int e = ch * 1024 + j * 64 + lane;
        float y1v = ut[(ch * 16 + j) * 65 + lane];
        float zz = zp[e];
        yp[e] = (y0r[j] + y1v) * silu_f(zz);
    }
}

// ===========================================================================
// STAGE 4 (roles interleaved: bid%9==8 -> G, else C)
//   role C = local conv + passthrough copy  (out channels [64:256])
//   role G = final GEMM + up add            (out channels [0:64])
// ===========================================================================
__global__ __launch_bounds__(256) void k_stage4(
    const float* __restrict__ x,
    const float* __restrict__ w3, const float* __restrict__ w5, const float* __restrict__ w7,
    const float* __restrict__ b1_0, const float* __restrict__ pw0,
    const float* __restrict__ g2_0, const float* __restrict__ b2_0,
    const float* __restrict__ b1_1, const float* __restrict__ pw1,
    const float* __restrict__ g2_1, const float* __restrict__ b2_1,
    const float* __restrict__ b1_2, const float* __restrict__ pw2,
    const float* __restrict__ g2_2, const float* __restrict__ b2_2,
    const float* __restrict__ yz, const float* __restrict__ ow,
    const float* __restrict__ base_scale, const float* __restrict__ up,
    float* __restrict__ out) {
    __shared__ float smem[6144];
    int bid = blockIdx.x;
    int tid = threadIdx.x;

    if (bid % 9 != 8) {
        // ---------------- role C: k_local + passthrough ----------------
        int cidx = (bid / 9) * 8 + (bid % 9);   // 0..4095
        int tile = cidx & 3;
        int c = (cidx >> 2) & 63;
        int b = cidx >> 8;
        int oy = (tile >> 1) * 32, ox = (tile & 1) * 32;
        float* t = smem;                   // 38*40 = 1520
        const float* xp = x + ((size_t)b * DIM + 64 + c) * HW;
        for (int i = tid; i < 38 * 38; i += 256) {
            int r = i / 38, cc = i % 38;
            int yy = r - 3 + oy, xx = cc - 3 + ox;
            t[r * 40 + cc] = (yy >= 0 && yy < 64 && xx >= 0 && xx < 64) ? xp[yy * 64 + xx] : 0.f;
        }
        // fused passthrough copy
        {
            const float4* x4 = (const float4*)x;
            float4* o4 = (float4*)out;
            int base = cidx * 512;
#pragma unroll
            for (int it = 0; it < 2; ++it) {
                int idx = base + it * 256 + tid;
                int bb = idx >> 17;
                int r  = idx & 131071;
                int gi = bb * 262144 + 131072 + r;
                o4[gi] = x4[gi];
            }
        }
        const float* w3p = w3 + (b * 64 + c) * 9;
        const float* w5p = w5 + (b * 64 + c) * 25;
        const float* w7p = w7 + (b * 64 + c) * 49;
        float W3r[9], W5r[25], W7r[49];
#pragma unroll
        for (int j = 0; j < 9; ++j)  W3r[j] = w3p[j];
#pragma unroll
        for (int j = 0; j < 25; ++j) W5r[j] = w5p[j];
#pragma unroll
        for (int j = 0; j < 49; ++j) W7r[j] = w7p[j];
        __syncthreads();

        const float rs = rsqrtf(1.f + 1e-5f);
        float bb1a = b1_0[c], bb1b = b1_1[c], bb1c = b1_2[c];
        float ssa = pw0[c] * g2_0[c] * rs, ssb = pw1[c] * g2_1[c] * rs, ssc = pw2[c] * g2_2[c] * rs;
        float bb2a = b2_0[c], bb2b = b2_1[c], bb2c = b2_2[c];

        int y  = tid >> 3;
        int x0 = (tid & 7) * 4;

        float a3[4] = {0.f, 0.f, 0.f, 0.f};
        float a5[4] = {0.f, 0.f, 0.f, 0.f};
        float a7[4] = {0.f, 0.f, 0.f, 0.f};

#pragma unroll
        for (int dy = 0; dy < 7; ++dy) {
            const float4* rp = (const float4*)(t + (y + dy) * 40 + x0);
            float4 q0 = rp[0], q1 = rp[1], q2 = rp[2];
            float r[12] = {q0.x, q0.y, q0.z, q0.w, q1.x, q1.y, q1.z, q1.w,
                           q2.x, q2.y, q2.z, q2.w};
#pragma unroll
            for (int k = 0; k < 4; ++k)
#pragma unroll
                for (int dx = 0; dx < 7; ++dx)
                    a7[k] = fmaf(r[k + dx], W7r[dy * 7 + dx], a7[k]);
            if (dy >= 1 && dy <= 5) {
                int ey = dy - 1;
#pragma unroll
                for (int k = 0; k < 4; ++k)
#pragma unroll
                    for (int dx = 0; dx < 5; ++dx)
                        a5[k] = fmaf(r[k + 1 + dx], W5r[ey * 5 + dx], a5[k]);
            }
            if (dy >= 2 && dy <= 4) {
                int ey = dy - 2;
#pragma unroll
                for (int k = 0; k < 4; ++k)
#pragma unroll
                    for (int dx = 0; dx < 3; ++dx)
                        a3[k] = fmaf(r[k + 2 + dx], W3r[ey * 3 + dx], a3[k]);
            }
        }

        float4 res;
        float* rr = (float*)&res;
#pragma unroll
        for (int k = 0; k < 4; ++k) {
            rr[k] = mish_fast(a3[k] + bb1a) * ssa + bb2a
                  + mish_fast(a5[k] + bb1b) * ssb + bb2b
                  + mish_fast(a7[k] + bb1c) * ssc + bb2c;
        }
        float* op = out + ((size_t)b * DIM + 64 + c) * HW;
        *(float4*)(op + (oy + y) * 64 + ox + x0) = res;
    } else {
        // ---------------- role G: k_final ----------------
        int id2 = bid / 9;                 // 0..511
        int h0 = (id2 & 31) * 2;
        int b  = id2 >> 5;
        float* yv = smem;                  // 32*128 = 4096
        float* wt = smem + 4096;           // 32*64 = 2048

        float acc[8][4];
#pragma unroll
        for (int i = 0; i < 8; ++i)
#pragma unroll
            for (int j = 0; j < 4; ++j) acc[i][j] = 0.f;

        int o0 = (tid >> 5) * 8;
        int p0 = (tid & 31) * 4;

        for (int ko = 0; ko < 64; ko += 32) {
            if (ko) __syncthreads();
            {
                int s = tid;
#pragma unroll
                for (int it = 0; it < 4; ++it, s += 256) {
                    int c = s >> 5, p4 = (s & 31) * 4;
                    size_t idx = ((size_t)b * 64 + ko + c) * HW + h0 * 64 + p4;
                    *(float4*)(yv + c * 128 + p4) = *(const float4*)(yz + idx);
                }
            }
            {
                int s = tid;
#pragma unroll
                for (int it = 0; it < 2; ++it, s += 256) {
                    int o = s >> 3, c0 = (s & 7) * 4;
                    float4 v = *(const float4*)(ow + o * 64 + ko + c0);
                    wt[(c0 + 0) * 64 + o] = v.x;
                    wt[(c0 + 1) * 64 + o] = v.y;
                    wt[(c0 + 2) * 64 + o] = v.z;
                    wt[(c0 + 3) * 64 + o] = v.w;
                }
            }
            __syncthreads();
#pragma unroll 4
            for (int c = 0; c < 32; ++c) {
                float wv[8], xv[4];
                *(float4*)(wv)     = *(const float4*)(wt + c * 64 + o0);
                *(float4*)(wv + 4) = *(const float4*)(wt + c * 64 + o0 + 4);
                *(float4*)(xv)     = *(const float4*)(yv + c * 128 + p0);
#pragma unroll
                for (int i = 0; i < 8; ++i)
#pragma unroll
                    for (int j = 0; j < 4; ++j)
                        acc[i][j] = fmaf(wv[i], xv[j], acc[i][j]);
            }
        }

#pragma unroll
        for (int i = 0; i < 8; ++i) {
            int o = o0 + i;
            float bs = base_scale[o];
            float4 u = *(const float4*)(up + ((size_t)b * 64 + o) * HW + h0 * 64 + p0);
            float4 r = make_float4(fmaf(bs, acc[i][0], u.x),
                                   fmaf(bs, acc[i][1], u.y),
                                   fmaf(bs, acc[i][2], u.z),
                                   fmaf(bs, acc[i][3], u.w));
            *(float4*)(out + ((size_t)b * DIM + o) * HW + h0 * 64 + p0) = r;
        }
    }
}

// ---------------------------------------------------------------------------
extern "C" void kernel_launch(void* const* d_in, const int* in_sizes, int n_in,
                              void* d_out, int out_size, void* d_ws, size_t ws_size,
                              hipStream_t stream) {
    (void)in_sizes; (void)n_in; (void)out_size; (void)ws_size;
    const float* x = (const float*)d_in[0];
    float* out = (float*)d_out;
    float* ws = (float*)d_ws;

    const size_t IMG = (size_t)NB * 64 * HW;   // 4,194,304 floats
    float* buf_xi   = ws;                      // xi, later reused as yz
    float* buf_z    = ws + IMG;
    float* buf_xc   = ws + 2 * IMG;
    float* buf_up   = ws + 3 * IMG;
    float* buf_p4   = ws + 4 * IMG;            // float4[2*16*4096]
    float* buf_pBC  = buf_p4 + (size_t)4 * 2 * NB * HW;
    float* buf_mean = buf_pBC + (size_t)2 * 2 * NB * HW;
    float* buf_w3   = buf_mean + 1024;
    float* buf_w5   = buf_w3 + 16 * 64 * 9;
    float* buf_w7   = buf_w5 + 16 * 64 * 25;

    // stage1: wavelet-up + mean (A) || input projection (D), interleaved
    k_stage1<<<1536, 256, 0, stream>>>(x,
        (const float*)d_in[22], (const float*)d_in[23], (const float*)d_in[24],
        buf_up, buf_mean,
        (const float*)d_in[26], buf_xi, buf_z);

    // stage2: dwconv+proj (E) || expert-mix weights (B)
    k_stage2<<<528, 256, 0, stream>>>(buf_xi,
        (const float*)d_in[27], (const float*)d_in[28], (const float*)d_in[29],
        buf_xc, (float4*)buf_p4, (float2*)buf_pBC,
        buf_mean,
        (const float*)d_in[1],  (const float*)d_in[2],  (const float*)d_in[3],
        (const float*)d_in[8],  (const float*)d_in[9],  (const float*)d_in[10],
        (const float*)d_in[15], (const float*)d_in[16], (const float*)d_in[17],
        buf_w3, buf_w5, buf_w7);

    // stage3: dual-direction selective scan -> yz (xi is dead, reuse)
    k_scan2<<<1024, 256, 0, stream>>>(buf_xc, (const float4*)buf_p4, (const float2*)buf_pBC,
        (const float*)d_in[30], (const float*)d_in[31],
        (const float*)d_in[32], (const float*)d_in[33],
        buf_z, buf_xi);

    // stage4: local conv + passthrough (C) || final GEMM (G), interleaved
    k_stage4<<<4608, 256, 0, stream>>>(x, buf_w3, buf_w5, buf_w7,
        (const float*)d_in[4],  (const float*)d_in[5],  (const float*)d_in[6],  (const float*)d_in[7],
        (const float*)d_in[11], (const float*)d_in[12], (const float*)d_in[13], (const float*)d_in[14],
        (const float*)d_in[18], (const float*)d_in[19], (const float*)d_in[20], (const float*)d_in[21],
        buf_xi, (const float*)d_in[34], (const float*)d_in[25], buf_up, out);
}